// Round 2
// baseline (1579.881 us; speedup 1.0000x reference)
//
#include <hip/hip_runtime.h>
#include <hip/hip_bf16.h>
#include <math.h>

#define NPOS 4900
#define NG1  708
#define NG2  4192
#define INF  512
#define OUTF 256
#define JBP  4928       // B'/Vt padded j extent (rows >= 4900 zeroed)
#define NJT  154        // JBP/32 j-tiles
#define LDS_KS 36       // k2: ushort k-stride (32 + 4 pad)
#define PCH   2508800   // k2 partial chunk stride in floats (512*4900)

typedef __attribute__((ext_vector_type(8))) short short8;
typedef __attribute__((ext_vector_type(16))) float f32x16;

// ---------------------------------------------------------------------------
// K0: rp = r @ Wr + br  (4x256); store S[0]=rp[ridx], S[1]=rp[2], S[2]=rp[3]
// ---------------------------------------------------------------------------
__global__ __launch_bounds__(256) void k0_rp(
    const float* __restrict__ r, const float* __restrict__ Wr,
    const float* __restrict__ br, const int* __restrict__ flagp,
    float* __restrict__ S)
{
    __shared__ float rsh[1024];
    int t = threadIdx.x;
    for (int i = t; i < 1024; i += 256) rsh[i] = r[i];
    __syncthreads();
    float a0 = 0.f, a1 = 0.f, a2 = 0.f, a3 = 0.f;
    for (int c = 0; c < 256; ++c) {
        float w = Wr[c * 256 + t];
        a0 += rsh[c] * w;
        a1 += rsh[256 + c] * w;
        a2 += rsh[512 + c] * w;
        a3 += rsh[768 + c] * w;
    }
    float b = br[t];
    a0 += b; a1 += b; a2 += b; a3 += b;
    int ridx = (flagp[0] != 0) ? 1 : 0;
    S[t]         = ridx ? a1 : a0;
    S[256 + t]   = a2;
    S[512 + t]   = a3;
}

// ---------------------------------------------------------------------------
// K1: fused projections hQ/hK/hV/H = feature @ {Wq,Wk,Wv,Ww} + bias
// ---------------------------------------------------------------------------
__global__ __launch_bounds__(256) void k1_proj(
    const float* __restrict__ feat,
    const float* __restrict__ Wq, const float* __restrict__ bq,
    const float* __restrict__ Wk, const float* __restrict__ bk,
    const float* __restrict__ Wv, const float* __restrict__ bv,
    const float* __restrict__ Ww, const float* __restrict__ bw,
    float* __restrict__ hQ, float* __restrict__ hK,
    float* __restrict__ hV, float* __restrict__ Hb)
{
    __shared__ float AT[16][68];    // [k][m]
    __shared__ float Bs[16][132];   // [k][n]
    int t = threadIdx.x;
    int mat = blockIdx.x >> 1;
    int n0  = (blockIdx.x & 1) * 128;
    int m0  = blockIdx.y * 64;
    const float* W; const float* bias; float* dst;
    switch (mat) {
        case 0:  W = Wq; bias = bq; dst = hQ; break;
        case 1:  W = Wk; bias = bk; dst = hK; break;
        case 2:  W = Wv; bias = bv; dst = hV; break;
        default: W = Ww; bias = bw; dst = Hb; break;
    }
    float acc[4][8];
#pragma unroll
    for (int i = 0; i < 4; ++i)
#pragma unroll
        for (int j = 0; j < 8; ++j) acc[i][j] = 0.f;
    int mg = (t >> 4) * 4, jg = (t & 15) * 8;
    int am = t & 63, ak = (t >> 6) * 4;
    int bkk = t >> 4, bn = (t & 15) * 8;
    for (int k0 = 0; k0 < INF; k0 += 16) {
        __syncthreads();
        {
            int row = m0 + am;
            float4 v = make_float4(0.f, 0.f, 0.f, 0.f);
            if (row < NPOS) v = *(const float4*)(feat + (size_t)row * INF + k0 + ak);
            AT[ak + 0][am] = v.x; AT[ak + 1][am] = v.y;
            AT[ak + 2][am] = v.z; AT[ak + 3][am] = v.w;
        }
        {
            const float* p = W + (size_t)(k0 + bkk) * OUTF + n0 + bn;
            float4 u0 = *(const float4*)p;
            float4 u1 = *(const float4*)(p + 4);
            *(float4*)&Bs[bkk][bn]     = u0;
            *(float4*)&Bs[bkk][bn + 4] = u1;
        }
        __syncthreads();
#pragma unroll
        for (int kk = 0; kk < 16; ++kk) {
            float4 a  = *(const float4*)&AT[kk][mg];
            float4 b0 = *(const float4*)&Bs[kk][jg];
            float4 b1 = *(const float4*)&Bs[kk][jg + 4];
            float av[4] = {a.x, a.y, a.z, a.w};
            float bv_[8] = {b0.x, b0.y, b0.z, b0.w, b1.x, b1.y, b1.z, b1.w};
#pragma unroll
            for (int i = 0; i < 4; ++i)
#pragma unroll
                for (int j = 0; j < 8; ++j) acc[i][j] += av[i] * bv_[j];
        }
    }
#pragma unroll
    for (int i = 0; i < 4; ++i) {
        int row = m0 + mg + i;
        if (row < NPOS) {
#pragma unroll
            for (int j = 0; j < 8; ++j) {
                int n = n0 + jg + j;
                dst[(size_t)row * OUTF + n] = acc[i][j] + bias[n];
            }
        }
    }
}

// ---------------------------------------------------------------------------
// split helpers (truncation split: x = hi(bf16) + lo(bf16), rel err ~2^-16)
// ---------------------------------------------------------------------------
__device__ __forceinline__ void split2(float x0, float x1,
                                       unsigned& hi, unsigned& lo)
{
    unsigned u0 = __float_as_uint(x0), u1 = __float_as_uint(x1);
    unsigned h0 = u0 & 0xFFFF0000u,   h1 = u1 & 0xFFFF0000u;
    float r0 = x0 - __uint_as_float(h0);
    float r1 = x1 - __uint_as_float(h1);
    hi = (h0 >> 16) | h1;
    lo = (__float_as_uint(r0) >> 16) | (__float_as_uint(r1) & 0xFFFF0000u);
}

__device__ __forceinline__ void split1(float x, unsigned short& hi, unsigned short& lo)
{
    unsigned u = __float_as_uint(x);
    unsigned h = u & 0xFFFF0000u;
    float r = x - __uint_as_float(h);
    hi = (unsigned short)(h >> 16);
    lo = (unsigned short)(__float_as_uint(r) >> 16);
}

__device__ __forceinline__ short8 ldfrag(const unsigned short* base, int row, int kuo)
{
    const unsigned long long* p =
        (const unsigned long long*)(base + row * LDS_KS + kuo);
    union { unsigned long long q[2]; short8 s; } u;
    u.q[0] = p[0];
    u.q[1] = p[1];
    return u.s;
}

__device__ __forceinline__ short8 g16(const unsigned short* p)
{
    union { uint4 q; short8 s; } u;
    u.q = *(const uint4*)p;
    return u.s;
}

// ---------------------------------------------------------------------------
// K2 (MFMA split-bf16, K-SPLIT): fp32 partials of
//   Bc[part][(h*2+g)*64+dd][j] = sum_k hK~*adj
// chunk 0 -> part0 [0,708); chunks 1..3 -> part1 thirds.
// ---------------------------------------------------------------------------
__global__ __launch_bounds__(256) void k2_mfma(
    const float* __restrict__ hK, const float* __restrict__ adj,
    const float* __restrict__ S,
    float* __restrict__ P0, float* __restrict__ P1)
{
    __shared__ unsigned short sAh[128 * LDS_KS];
    __shared__ unsigned short sAl[128 * LDS_KS];
    __shared__ unsigned short sBh[64 * LDS_KS];
    __shared__ unsigned short sBl[64 * LDS_KS];

    int t = threadIdx.x;
    int j0 = blockIdx.x * 64;
    int h  = blockIdx.y;
    int chunk = blockIdx.z;
    int part = (chunk == 0) ? 0 : 1;
    int kbeg = (chunk <= 1) ? 0 : (chunk - 1) * 1408;
    int kend = (chunk == 0) ? NG1 : ((chunk == 3) ? NG2 : chunk * 1408);
    int L = part ? NG2 : NG1;
    const float* kflat = hK + (part ? (size_t)NG1 * OUTF : 0);
    int rowoff = part ? NG1 : 0;
    float* Pout = chunk ? (P1 + (size_t)(chunk - 1) * PCH) : P0;

    int dd = t & 63;
    int kg = t >> 6;
    int jcol = j0 + dd;

    float sc[2][4];
#pragma unroll
    for (int g = 0; g < 2; ++g)
#pragma unroll
        for (int c = 0; c < 4; ++c)
            sc[g][c] = 0.5f * S[(g + part) * 256 + c * 64 + dd];

    f32x16 acc0, acc1;
#pragma unroll
    for (int i = 0; i < 16; ++i) { acc0[i] = 0.f; acc1[i] = 0.f; }

    int lane = t & 63;
    int half = lane >> 5;
    int ml = lane & 31;
    int arow = kg * 32 + ml;

    unsigned* uAh = (unsigned*)sAh;
    unsigned* uAl = (unsigned*)sAl;
    unsigned* uBh = (unsigned*)sBh;
    unsigned* uBl = (unsigned*)sBl;

    int ks0 = kbeg >> 5;
    int ks1 = (kend + 31) >> 5;
    for (int ks = ks0; ks < ks1; ++ks) {
        int k0 = ks * 32;
        float xa[8], xb[8];
#pragma unroll
        for (int i = 0; i < 8; ++i) {
            int kv = k0 + kg * 8 + i;
            bool okk = (kv < kend);
            xa[i] = okk ? kflat[(size_t)(h * L + kv) * 64 + dd] : 0.f;
            xb[i] = (okk && jcol < NPOS)
                        ? adj[(size_t)(rowoff + kv) * NPOS + jcol] : 0.f;
        }
        unsigned hA0[4], lA0[4], hA1[4], lA1[4], hB[4], lB[4];
#pragma unroll
        for (int i = 0; i < 8; i += 2) {
            float a0 = xa[i] * sc[0][i & 3];
            float a1 = xa[i + 1] * sc[0][(i + 1) & 3];
            split2(a0, a1, hA0[i >> 1], lA0[i >> 1]);
            float c0 = xa[i] * sc[1][i & 3];
            float c1 = xa[i + 1] * sc[1][(i + 1) & 3];
            split2(c0, c1, hA1[i >> 1], lA1[i >> 1]);
            split2(xb[i], xb[i + 1], hB[i >> 1], lB[i >> 1]);
        }
        __syncthreads();
        {
            int b0 = dd * 18 + kg * 4;
            int b1 = (64 + dd) * 18 + kg * 4;
            *(uint2*)(uAh + b0)     = make_uint2(hA0[0], hA0[1]);
            *(uint2*)(uAh + b0 + 2) = make_uint2(hA0[2], hA0[3]);
            *(uint2*)(uAl + b0)     = make_uint2(lA0[0], lA0[1]);
            *(uint2*)(uAl + b0 + 2) = make_uint2(lA0[2], lA0[3]);
            *(uint2*)(uAh + b1)     = make_uint2(hA1[0], hA1[1]);
            *(uint2*)(uAh + b1 + 2) = make_uint2(hA1[2], hA1[3]);
            *(uint2*)(uAl + b1)     = make_uint2(lA1[0], lA1[1]);
            *(uint2*)(uAl + b1 + 2) = make_uint2(lA1[2], lA1[3]);
            *(uint2*)(uBh + b0)     = make_uint2(hB[0], hB[1]);
            *(uint2*)(uBh + b0 + 2) = make_uint2(hB[2], hB[3]);
            *(uint2*)(uBl + b0)     = make_uint2(lB[0], lB[1]);
            *(uint2*)(uBl + b0 + 2) = make_uint2(lB[2], lB[3]);
        }
        __syncthreads();
#pragma unroll
        for (int kq = 0; kq < 2; ++kq) {
            int kuo = kq * 16 + half * 8;
            short8 aH = ldfrag(sAh, arow, kuo);
            short8 aL = ldfrag(sAl, arow, kuo);
            short8 b0H = ldfrag(sBh, ml, kuo);
            short8 b0L = ldfrag(sBl, ml, kuo);
            short8 b1H = ldfrag(sBh, 32 + ml, kuo);
            short8 b1L = ldfrag(sBl, 32 + ml, kuo);
            acc0 = __builtin_amdgcn_mfma_f32_32x32x16_bf16(aH, b0H, acc0, 0, 0, 0);
            acc0 = __builtin_amdgcn_mfma_f32_32x32x16_bf16(aH, b0L, acc0, 0, 0, 0);
            acc0 = __builtin_amdgcn_mfma_f32_32x32x16_bf16(aL, b0H, acc0, 0, 0, 0);
            acc1 = __builtin_amdgcn_mfma_f32_32x32x16_bf16(aH, b1H, acc1, 0, 0, 0);
            acc1 = __builtin_amdgcn_mfma_f32_32x32x16_bf16(aH, b1L, acc1, 0, 0, 0);
            acc1 = __builtin_amdgcn_mfma_f32_32x32x16_bf16(aL, b1H, acc1, 0, 0, 0);
        }
    }

    int col0 = j0 + ml;
    int col1 = j0 + 32 + ml;
#pragma unroll
    for (int reg = 0; reg < 16; ++reg) {
        int m = kg * 32 + (reg & 3) + 8 * (reg >> 2) + 4 * half;
        int g = m >> 6, ddm = m & 63;
        size_t rb = (size_t)((h * 2 + g) * 64 + ddm) * NPOS;
        Pout[rb + col0] = acc0[reg];
        if (col1 < NPOS) Pout[rb + col1] = acc1[reg];
    }
}

// ---------------------------------------------------------------------------
// K2R: reduce part1 chunks + split-bf16 + transpose to B' planes
//   Bhi/Blo[(g*4+h)][j][k], k = part*64+dd.  Rows j in [4900,4928) zeroed.
// ---------------------------------------------------------------------------
__global__ __launch_bounds__(256) void k2_reduce(
    const float* __restrict__ P0, const float* __restrict__ P1,
    unsigned short* __restrict__ Bhi, unsigned short* __restrict__ Blo)
{
    int t = threadIdx.x;
    int j = blockIdx.x * 256 + t;
    if (j >= JBP) return;
    int p = blockIdx.y;               // plane = g*4+h
    int g = p >> 2, h = p & 3;
    int kg = blockIdx.z;              // 16 k-values each
    int k0 = kg * 16;
    int rowb = (h * 2 + g) * 64;

    unsigned short hi[16], lo[16];
    if (j < NPOS) {
        if (k0 < 64) {
#pragma unroll
            for (int i = 0; i < 16; ++i) {
                float v = P0[(size_t)(rowb + k0 + i) * NPOS + j];
                split1(v, hi[i], lo[i]);
            }
        } else {
#pragma unroll
            for (int i = 0; i < 16; ++i) {
                size_t off = (size_t)(rowb + (k0 - 64) + i) * NPOS + j;
                float v = P1[off] + P1[off + PCH] + P1[off + 2 * (size_t)PCH];
                split1(v, hi[i], lo[i]);
            }
        }
    } else {
#pragma unroll
        for (int i = 0; i < 16; ++i) { hi[i] = 0; lo[i] = 0; }
    }
    size_t base = ((size_t)p * JBP + j) * 128 + k0;
    union { unsigned short us[16]; uint4 v[2]; } uh, ul;
#pragma unroll
    for (int i = 0; i < 16; ++i) { uh.us[i] = hi[i]; ul.us[i] = lo[i]; }
    *(uint4*)(Bhi + base)     = uh.v[0];
    *(uint4*)(Bhi + base + 8) = uh.v[1];
    *(uint4*)(Blo + base)     = ul.v[0];
    *(uint4*)(Blo + base + 8) = ul.v[1];
}

// ---------------------------------------------------------------------------
// QSPLIT: Q~ = hQ (head-reshaped) * S, split-bf16, k-contiguous rows.
// Row layout: g0: h*768 + ql (pad 768); g1: 3072 + h*4224 + ql (pad 4224).
// Pad rows (ql >= Lg) zeroed. 19968 rows x 128 k.
// ---------------------------------------------------------------------------
__global__ __launch_bounds__(256) void qsplit(
    const float* __restrict__ hQ, const float* __restrict__ S,
    unsigned short* __restrict__ Qh, unsigned short* __restrict__ Ql)
{
    int t = threadIdx.x;
    int row = blockIdx.x * 2 + (t >> 7);
    int k = t & 127;
    int g, h, ql, Lg, vbase;
    if (row < 3072) { g = 0; h = row / 768; ql = row - h * 768; Lg = NG1; vbase = 0; }
    else {
        int rr = row - 3072;
        g = 1; h = rr / 4224; ql = rr - h * 4224; Lg = NG2; vbase = NG1 * OUTF;
    }
    int d = k & 63, p = k >> 6;
    float v = 0.f;
    if (ql < Lg)
        v = hQ[vbase + (size_t)(h * Lg + ql) * 64 + d] *
            S[(g + p) * 256 + (ql & 3) * 64 + d];
    unsigned short hi, lo;
    split1(v, hi, lo);
    Qh[(size_t)row * 128 + k] = hi;
    Ql[(size_t)row * 128 + k] = lo;
}

// ---------------------------------------------------------------------------
// VTSPLIT: Vt[h][d][j] (hi/lo bf16, j-contiguous, j padded to JBP with zeros)
// from hV head-view hV[(h*4900 + j)*64 + d].
// ---------------------------------------------------------------------------
__global__ __launch_bounds__(256) void vtsplit(
    const float* __restrict__ hV,
    unsigned short* __restrict__ VtH, unsigned short* __restrict__ VtL)
{
    __shared__ float ls[128 * 65];
    int t = threadIdx.x;
    int j0 = blockIdx.x * 128;
    int h  = blockIdx.y;
#pragma unroll
    for (int i = 0; i < 32; ++i) {
        int idx = t + i * 256;
        int j = idx >> 6, d = idx & 63;
        float v = 0.f;
        int jg = j0 + j;
        if (jg < NPOS) v = hV[(size_t)(h * NPOS + jg) * 64 + d];
        ls[j * 65 + d] = v;
    }
    __syncthreads();
    int d = t >> 2, jseg = (t & 3) * 32;
#pragma unroll
    for (int i = 0; i < 32; ++i) {
        int j = jseg + i;
        int jg = j0 + j;
        if (jg < JBP) {
            unsigned short hi, lo;
            split1(ls[j * 65 + d], hi, lo);
            VtH[(size_t)(h * 64 + d) * JBP + jg] = hi;
            VtL[(size_t)(h * 64 + d) * JBP + jg] = lo;
        }
    }
}

// ---------------------------------------------------------------------------
// K3F: fused logits -> head-softmax -> PV.  Grid (39 pos-tiles, 13 j-chunks),
// 4 waves/block, each wave owns 32 pos, all 4 heads, loops j-tiles of chunk.
// QK swapped (A=B' j-rows, B=Q~ pos-cols) -> D[j regs][pos lanes]; per-lane
// softmax across heads; alpha reshuffled reg-j -> elem-j via shfl_xor(32);
// split-bf16 PV MFMA (A=alpha, B=Vt); atomicAdd epilogue into mpart.
// ---------------------------------------------------------------------------
__global__ __launch_bounds__(256, 2) void k3f_attn(
    const unsigned short* __restrict__ Qh, const unsigned short* __restrict__ Ql,
    const unsigned short* __restrict__ Bhi, const unsigned short* __restrict__ Blo,
    const unsigned short* __restrict__ VtH, const unsigned short* __restrict__ VtL,
    float* __restrict__ mpart)
{
    int t = threadIdx.x;
    int w = t >> 6;
    int lane = t & 63;
    int half = lane >> 5, ml = lane & 31;
    int x = blockIdx.x;
    int chunk = blockIdx.y;
    int g = (x < 6) ? 0 : 1;
    int tile = g ? (x - 6) : x;
    int Lg = g ? NG2 : NG1;
    int posbase = g ? NG1 : 0;
    int q0 = tile * 128 + w * 32;
    int qbase = g ? 3072 : 0;
    int hstr = g ? 4224 : 768;

    f32x16 pv[4][2];
#pragma unroll
    for (int h = 0; h < 4; ++h)
#pragma unroll
        for (int n = 0; n < 2; ++n)
#pragma unroll
            for (int r = 0; r < 16; ++r) pv[h][n][r] = 0.f;

    int jt0 = chunk * 12;
    int jt1 = jt0 + 12; if (jt1 > NJT) jt1 = NJT;

    for (int jt = jt0; jt < jt1; ++jt) {
        int j0 = jt * 32;
        f32x16 qk[4];
        // ---- QK^T (swapped) for 4 heads ----
#pragma unroll
        for (int h = 0; h < 4; ++h) {
#pragma unroll
            for (int r = 0; r < 16; ++r) qk[h][r] = 0.f;
            const unsigned short* bhp = Bhi + ((size_t)(g * 4 + h) * JBP + j0 + ml) * 128;
            const unsigned short* blp = Blo + ((size_t)(g * 4 + h) * JBP + j0 + ml) * 128;
            const unsigned short* qhp = Qh + (size_t)(qbase + h * hstr + q0 + ml) * 128;
            const unsigned short* qlp = Ql + (size_t)(qbase + h * hstr + q0 + ml) * 128;
#pragma unroll
            for (int kc = 0; kc < 8; ++kc) {
                int ko = kc * 16 + half * 8;
                short8 aH = g16(bhp + ko);
                short8 aL = g16(blp + ko);
                short8 xH = g16(qhp + ko);
                short8 xL = g16(qlp + ko);
                qk[h] = __builtin_amdgcn_mfma_f32_32x32x16_bf16(aH, xH, qk[h], 0, 0, 0);
                qk[h] = __builtin_amdgcn_mfma_f32_32x32x16_bf16(aH, xL, qk[h], 0, 0, 0);
                qk[h] = __builtin_amdgcn_mfma_f32_32x32x16_bf16(aL, xH, qk[h], 0, 0, 0);
            }
        }
        // ---- softmax across heads (per-lane, elementwise) ----
#pragma unroll
        for (int r = 0; r < 16; ++r) {
            float v0 = qk[0][r], v1 = qk[1][r], v2 = qk[2][r], v3 = qk[3][r];
            float mx = fmaxf(fmaxf(v0, v1), fmaxf(v2, v3));
            float e0 = __expf(v0 - mx), e1 = __expf(v1 - mx);
            float e2 = __expf(v2 - mx), e3 = __expf(v3 - mx);
            float inv = 1.0f / (e0 + e1 + e2 + e3);
            qk[0][r] = e0 * inv; qk[1][r] = e1 * inv;
            qk[2][r] = e2 * inv; qk[3][r] = e3 * inv;
        }
        // ---- per head: reg-j -> elem-j exchange, split, PV MFMA ----
#pragma unroll
        for (int h = 0; h < 4; ++h) {
            float e[16];
#pragma unroll
            for (int r = 0; r < 16; ++r) e[r] = qk[h][r];
#pragma unroll
            for (int i = 0; i < 4; ++i) {
                float A = e[i], B = e[4 + i];
                float As = __shfl_xor(A, 32, 64);
                float Bs = __shfl_xor(B, 32, 64);
                e[i]     = half ? Bs : A;   // -> j = 8*half + i
                e[4 + i] = half ? B  : As;  // -> j = 8*half + 4 + i
                float C = e[8 + i], D = e[12 + i];
                float Cs = __shfl_xor(C, 32, 64);
                float Ds = __shfl_xor(D, 32, 64);
                e[8 + i]  = half ? Ds : C;  // -> j = 16 + 8*half + i
                e[12 + i] = half ? D  : Cs; // -> j = 16 + 8*half + 4 + i
            }
            union { unsigned u[4]; short8 s; } pah[2], pal[2];
#pragma unroll
            for (int kq = 0; kq < 2; ++kq)
#pragma unroll
                for (int p2 = 0; p2 < 4; ++p2)
                    split2(e[kq * 8 + 2 * p2], e[kq * 8 + 2 * p2 + 1],
                           pah[kq].u[p2], pal[kq].u[p2]);
#pragma unroll
            for (int kq = 0; kq < 2; ++kq) {
                int jo = j0 + kq * 16 + half * 8;
#pragma unroll
                for (int nt = 0; nt < 2; ++nt) {
                    const unsigned short* vhp = VtH + (size_t)(h * 64 + nt * 32 + ml) * JBP + jo;
                    const unsigned short* vlp = VtL + (size_t)(h * 64 + nt * 32 + ml) * JBP + jo;
                    short8 vH = g16(vhp);
                    short8 vL = g16(vlp);
                    pv[h][nt] = __builtin_amdgcn_mfma_f32_32x32x16_bf16(pah[kq].s, vH, pv[h][nt], 0, 0, 0);
                    pv[h][nt] = __builtin_amdgcn_mfma_f32_32x32x16_bf16(pah[kq].s, vL, pv[h][nt], 0, 0, 0);
                    pv[h][nt] = __builtin_amdgcn_mfma_f32_32x32x16_bf16(pal[kq].s, vH, pv[h][nt], 0, 0, 0);
                }
            }
        }
    }
    // ---- epilogue: atomic accumulate m[pos][h*64+d] ----
#pragma unroll
    for (int h = 0; h < 4; ++h)
#pragma unroll
        for (int nt = 0; nt < 2; ++nt)
#pragma unroll
            for (int r = 0; r < 16; ++r) {
                int pl = (r & 3) + 8 * (r >> 2) + 4 * half;
                int pg = q0 + pl;
                if (pg < Lg)
                    atomicAdd(mpart + (size_t)(posbase + pg) * OUTF + h * 64 + nt * 32 + ml,
                              pv[h][nt][r]);
            }
}

// ---------------------------------------------------------------------------
// E1: m = mpart; relu; ln1; write concat buffer [H | ln1(relu(m))]
// ---------------------------------------------------------------------------
__global__ __launch_bounds__(256) void e1_relu_ln(
    const float* __restrict__ mpart, const float* __restrict__ Hb,
    const float* __restrict__ g1, const float* __restrict__ b1,
    float* __restrict__ cc)
{
    int w = threadIdx.x >> 6, lane = threadIdx.x & 63;
    int row = blockIdx.x * 4 + w;
    int c = lane * 4;
    float4 x0 = *(const float4*)(mpart + (size_t)row * OUTF + c);
    float x[4] = { fmaxf(x0.x, 0.f), fmaxf(x0.y, 0.f),
                   fmaxf(x0.z, 0.f), fmaxf(x0.w, 0.f) };
    float s = x[0] + x[1] + x[2] + x[3];
#pragma unroll
    for (int m = 32; m > 0; m >>= 1) s += __shfl_xor(s, m, 64);
    float mu = s * (1.0f / 256.0f);
    float vs = 0.f;
#pragma unroll
    for (int i = 0; i < 4; ++i) { float d = x[i] - mu; vs += d * d; }
#pragma unroll
    for (int m = 32; m > 0; m >>= 1) vs += __shfl_xor(vs, m, 64);
    float rs = rsqrtf(vs * (1.0f / 256.0f) + 1e-5f);
    float4 y;
    y.x = (x[0] - mu) * rs * g1[c + 0] + b1[c + 0];
    y.y = (x[1] - mu) * rs * g1[c + 1] + b1[c + 1];
    y.z = (x[2] - mu) * rs * g1[c + 2] + b1[c + 2];
    y.w = (x[3] - mu) * rs * g1[c + 3] + b1[c + 3];
    *(float4*)(cc + (size_t)row * INF + OUTF + c) = y;
    float4 hh = *(const float4*)(Hb + (size_t)row * OUTF + c);
    *(float4*)(cc + (size_t)row * INF + c) = hh;
}

// ---------------------------------------------------------------------------
// E2: beta = sigmoid(cc @ Wbeta + bbeta); out = beta*m1 + (1-beta)*H
// ---------------------------------------------------------------------------
__global__ __launch_bounds__(256) void e2_beta(
    const float* __restrict__ cc, const float* __restrict__ Wb,
    const float* __restrict__ bb, float* __restrict__ outb)
{
    __shared__ float AT[16][68];
    __shared__ float Bs[16][132];
    int t = threadIdx.x;
    int n0 = blockIdx.x * 128;
    int m0 = blockIdx.y * 64;
    float acc[4][8];
#pragma unroll
    for (int i = 0; i < 4; ++i)
#pragma unroll
        for (int j = 0; j < 8; ++j) acc[i][j] = 0.f;
    int mg = (t >> 4) * 4, jg = (t & 15) * 8;
    int am = t & 63, ak = (t >> 6) * 4;
    int bkk = t >> 4, bn = (t & 15) * 8;
    for (int k0 = 0; k0 < INF; k0 += 16) {
        __syncthreads();
        {
            int row = m0 + am;
            float4 v = make_float4(0.f, 0.f, 0.f, 0.f);
            if (row < NPOS) v = *(const float4*)(cc + (size_t)row * INF + k0 + ak);
            AT[ak + 0][am] = v.x; AT[ak + 1][am] = v.y;
            AT[ak + 2][am] = v.z; AT[ak + 3][am] = v.w;
        }
        {
            const float* p = Wb + (size_t)(k0 + bkk) * OUTF + n0 + bn;
            float4 u0 = *(const float4*)p;
            float4 u1 = *(const float4*)(p + 4);
            *(float4*)&Bs[bkk][bn]     = u0;
            *(float4*)&Bs[bkk][bn + 4] = u1;
        }
        __syncthreads();
#pragma unroll
        for (int kk = 0; kk < 16; ++kk) {
            float4 a  = *(const float4*)&AT[kk][mg];
            float4 b0 = *(const float4*)&Bs[kk][jg];
            float4 b1 = *(const float4*)&Bs[kk][jg + 4];
            float av[4] = {a.x, a.y, a.z, a.w};
            float bv_[8] = {b0.x, b0.y, b0.z, b0.w, b1.x, b1.y, b1.z, b1.w};
#pragma unroll
            for (int i = 0; i < 4; ++i)
#pragma unroll
                for (int j = 0; j < 8; ++j) acc[i][j] += av[i] * bv_[j];
        }
    }
#pragma unroll
    for (int i = 0; i < 4; ++i) {
        int row = m0 + mg + i;
        if (row < NPOS) {
#pragma unroll
            for (int j = 0; j < 8; ++j) {
                int n = n0 + jg + j;
                float x = acc[i][j] + bb[n];
                float sg = 1.0f / (1.0f + __expf(-x));
                float m1v = cc[(size_t)row * INF + OUTF + n];
                float Hv  = cc[(size_t)row * INF + n];
                outb[(size_t)row * OUTF + n] = sg * m1v + (1.0f - sg) * Hv;
            }
        }
    }
}

// ---------------------------------------------------------------------------
// E3: t = out @ w1 + b1 ; ln2(eps=1e-6) ; tanh -> h2.
// ---------------------------------------------------------------------------
__global__ __launch_bounds__(256) void e3_w1_ln2(
    const float* __restrict__ outb, const float* __restrict__ w1,
    const float* __restrict__ b1v, const float* __restrict__ g2,
    const float* __restrict__ b2v, float* __restrict__ h2o)
{
    __shared__ float As[16][260];
    __shared__ float Bs[16][260];
    __shared__ float red[16][17];
    int t = threadIdx.x;
    int m0 = blockIdx.x * 16;
    {
        int rr = t >> 4, c4 = (t & 15) * 4;
        int row = m0 + rr;
#pragma unroll
        for (int i = 0; i < 4; ++i) {
            int c = c4 + i * 64;
            float4 x = make_float4(0.f, 0.f, 0.f, 0.f);
            if (row < NPOS) x = *(const float4*)(outb + (size_t)row * OUTF + c);
            *(float4*)&As[rr][c] = x;
        }
    }
    int q = t & 15, dg = (t >> 4) * 16;
    float acc[16];
#pragma unroll
    for (int i = 0; i < 16; ++i) acc[i] = 0.f;
    for (int k0 = 0; k0 < 256; k0 += 16) {
        __syncthreads();
        {
            int kk = t >> 4, n16 = (t & 15) * 16;
#pragma unroll
            for (int i = 0; i < 4; ++i) {
                float4 x = *(const float4*)(w1 + (size_t)(k0 + kk) * OUTF + n16 + i * 4);
                *(float4*)&Bs[kk][n16 + i * 4] = x;
            }
        }
        __syncthreads();
#pragma unroll
        for (int kk = 0; kk < 16; ++kk) {
            float a = As[q][k0 + kk];
#pragma unroll
            for (int i = 0; i < 16; i += 4) {
                float4 b = *(const float4*)&Bs[kk][dg + i];
                acc[i + 0] += a * b.x; acc[i + 1] += a * b.y;
                acc[i + 2] += a * b.z; acc[i + 3] += a * b.w;
            }
        }
    }
    float x[16];
#pragma unroll
    for (int i = 0; i < 16; ++i) x[i] = acc[i] + b1v[dg + i];
    float ps = 0.f;
#pragma unroll
    for (int i = 0; i < 16; ++i) ps += x[i];
    __syncthreads();
    red[t >> 4][q] = ps;
    __syncthreads();
    float s = 0.f;
#pragma unroll
    for (int i = 0; i < 16; ++i) s += red[i][q];
    float mu = s * (1.0f / 256.0f);
    float pvv = 0.f;
#pragma unroll
    for (int i = 0; i < 16; ++i) { float d = x[i] - mu; pvv += d * d; }
    __syncthreads();
    red[t >> 4][q] = pvv;
    __syncthreads();
    float v = 0.f;
#pragma unroll
    for (int i = 0; i < 16; ++i) v += red[i][q];
    float rs = rsqrtf(v * (1.0f / 256.0f) + 1e-6f);
    int row = m0 + q;
    if (row < NPOS) {
#pragma unroll
        for (int i = 0; i < 16; ++i) {
            int n = dg + i;
            h2o[(size_t)row * OUTF + n] = tanhf((x[i] - mu) * rs * g2[n] + b2v[n]);
        }
    }
}

// ---------------------------------------------------------------------------
// E4: final = h2 @ w2  (no bias) -> d_out
// ---------------------------------------------------------------------------
__global__ __launch_bounds__(256) void e4_final(
    const float* __restrict__ h2in, const float* __restrict__ w2,
    float* __restrict__ outp)
{
    __shared__ float AT[16][68];
    __shared__ float Bs[16][132];
    int t = threadIdx.x;
    int n0 = blockIdx.x * 128;
    int m0 = blockIdx.y * 64;
    float acc[4][8];
#pragma unroll
    for (int i = 0; i < 4; ++i)
#pragma unroll
        for (int j = 0; j < 8; ++j) acc[i][j] = 0.f;
    int mg = (t >> 4) * 4, jg = (t & 15) * 8;
    int am = t & 63, ak = (t >> 6) * 4;
    int bkk = t >> 4, bn = (t & 15) * 8;
    for (int k0 = 0; k0 < 256; k0 += 16) {
        __syncthreads();
        {
            int row = m0 + am;
            float4 v = make_float4(0.f, 0.f, 0.f, 0.f);
            if (row < NPOS) v = *(const float4*)(h2in + (size_t)row * OUTF + k0 + ak);
            AT[ak + 0][am] = v.x; AT[ak + 1][am] = v.y;
            AT[ak + 2][am] = v.z; AT[ak + 3][am] = v.w;
        }
        {
            const float* p = w2 + (size_t)(k0 + bkk) * OUTF + n0 + bn;
            float4 u0 = *(const float4*)p;
            float4 u1 = *(const float4*)(p + 4);
            *(float4*)&Bs[bkk][bn]     = u0;
            *(float4*)&Bs[bkk][bn + 4] = u1;
        }
        __syncthreads();
#pragma unroll
        for (int kk = 0; kk < 16; ++kk) {
            float4 a  = *(const float4*)&AT[kk][mg];
            float4 b0 = *(const float4*)&Bs[kk][jg];
            float4 b1 = *(const float4*)&Bs[kk][jg + 4];
            float av[4] = {a.x, a.y, a.z, a.w};
            float bv_[8] = {b0.x, b0.y, b0.z, b0.w, b1.x, b1.y, b1.z, b1.w};
#pragma unroll
            for (int i = 0; i < 4; ++i)
#pragma unroll
                for (int j = 0; j < 8; ++j) acc[i][j] += av[i] * bv_[j];
        }
    }
#pragma unroll
    for (int i = 0; i < 4; ++i) {
        int row = m0 + mg + i;
        if (row < NPOS) {
#pragma unroll
            for (int j = 0; j < 8; ++j) {
                outp[(size_t)row * OUTF + n0 + jg + j] = acc[i][j];
            }
        }
    }
}

// ---------------------------------------------------------------------------
extern "C" void kernel_launch(void* const* d_in, const int* in_sizes, int n_in,
                              void* d_out, int out_size, void* d_ws, size_t ws_size,
                              hipStream_t stream)
{
    const float* feature = (const float*)d_in[0];
    const float* adj   = (const float*)d_in[1];
    const float* r     = (const float*)d_in[2];
    const float* Wq    = (const float*)d_in[3];
    const float* bq    = (const float*)d_in[4];
    const float* Wk    = (const float*)d_in[5];
    const float* bk    = (const float*)d_in[6];
    const float* Wv    = (const float*)d_in[7];
    const float* bv    = (const float*)d_in[8];
    const float* Ww    = (const float*)d_in[9];
    const float* bw    = (const float*)d_in[10];
    const float* Wr    = (const float*)d_in[11];
    const float* br    = (const float*)d_in[12];
    const float* Wbeta = (const float*)d_in[13];
    const float* bbeta = (const float*)d_in[14];
    const float* ln1g  = (const float*)d_in[15];
    const float* ln1b  = (const float*)d_in[16];
    const float* w1    = (const float*)d_in[17];
    const float* b1    = (const float*)d_in[18];
    const float* ln2g  = (const float*)d_in[19];
    const float* ln2b  = (const float*)d_in[20];
    const float* w2    = (const float*)d_in[21];
    const int*   flag  = (const int*)d_in[22];
    float* out = (float*)d_out;

    // --- workspace layout (liveness-aliased, peak 75.4 MB at k2_reduce) ---
    // k2 phase:       P0 [0,10.04M), P1 [10.04M,40.14M), hK aliases Bhi slot.
    // k2_reduce:      P0,P1 -> Bhi,Blo (hK dead).
    // qsplit/vtsplit: Qh,Ql,VtH,VtL,mpart carved from dead P0/P1 region.
    // e-chain:        cc/outb/hh2 also in dead P0/P1/Bhi region.
    char* ws = (char*)d_ws;
    float*          P0    = (float*)(ws + 0);
    float*          P1    = (float*)(ws + 10035200);
    unsigned short* Qh    = (unsigned short*)(ws + 0);         // 5,111,808
    unsigned short* Qlo   = (unsigned short*)(ws + 5111808);   // 5,111,808
    unsigned short* VtH   = (unsigned short*)(ws + 10223616);  // 2,523,136
    unsigned short* VtL   = (unsigned short*)(ws + 12746752);  // 2,523,136
    float*          mpart = (float*)(ws + 15269888);           // 5,017,600
    float*          cc    = (float*)(ws + 20287488);           // 10,035,200
    float*          outb  = (float*)(ws + 30322688);           // 5,017,600
    float*          hh2   = (float*)(ws + 35340288);           // 5,017,600
    unsigned short* Bhi   = (unsigned short*)(ws + 40140800);  // 10,092,544
    unsigned short* Blo   = (unsigned short*)(ws + 50233344);  // 10,092,544
    float*          hK    = (float*)(ws + 40140800);           // aliases Bhi (dead first)
    float*          hQ    = (float*)(ws + 60325888);           // 5,017,600
    float*          hV    = (float*)(ws + 65343488);           // 5,017,600
    float*          Hb    = (float*)(ws + 70361088);           // 5,017,600
    float*          S     = (float*)(ws + 75378688);           // 3,072

    k0_rp<<<1, 256, 0, stream>>>(r, Wr, br, flag, S);
    k1_proj<<<dim3(8, 77), 256, 0, stream>>>(feature, Wq, bq, Wk, bk, Wv, bv, Ww, bw,
                                             hQ, hK, hV, Hb);
    k2_mfma<<<dim3(77, 4, 4), 256, 0, stream>>>(hK, adj, S, P0, P1);
    k2_reduce<<<dim3(20, 8, 8), 256, 0, stream>>>(P0, P1, Bhi, Blo);
    qsplit<<<9984, 256, 0, stream>>>(hQ, S, Qh, Qlo);
    vtsplit<<<dim3(39, 4), 256, 0, stream>>>(hV, VtH, VtL);
    hipMemsetAsync(mpart, 0, (size_t)NPOS * OUTF * 4, stream);
    k3f_attn<<<dim3(39, 13), 256, 0, stream>>>(Qh, Qlo, Bhi, Blo, VtH, VtL, mpart);
    e1_relu_ln<<<1225, 256, 0, stream>>>(mpart, Hb, ln1g, ln1b, cc);
    e2_beta<<<dim3(2, 77), 256, 0, stream>>>(cc, Wbeta, bbeta, outb);
    e3_w1_ln2<<<307, 256, 0, stream>>>(outb, w1, b1, ln2g, ln2b, hh2);
    e4_final<<<dim3(2, 77), 256, 0, stream>>>(hh2, w2, out);
}

// Round 3
// 1064.256 us; speedup vs baseline: 1.4845x; 1.4845x over previous
//
#include <hip/hip_runtime.h>
#include <hip/hip_bf16.h>
#include <math.h>

#define NPOS 4900
#define NG1  708
#define NG2  4192
#define INF  512
#define OUTF 256
#define JBP  4928       // B'/Vt padded j extent (rows >= 4900 zeroed)
#define NJT  154        // JBP/32 j-tiles
#define NC   4          // j-chunks (mpart copies)
#define JTT  39         // ceil(154/4)
#define LDS_KS 36       // k2: ushort k-stride (32 + 4 pad)
#define PCH   2508800   // k2 partial chunk stride in floats (512*4900)

typedef __attribute__((ext_vector_type(8))) short short8;
typedef __attribute__((ext_vector_type(16))) float f32x16;

// ---------------------------------------------------------------------------
// K0: rp = r @ Wr + br  (4x256); store S[0]=rp[ridx], S[1]=rp[2], S[2]=rp[3]
// ---------------------------------------------------------------------------
__global__ __launch_bounds__(256) void k0_rp(
    const float* __restrict__ r, const float* __restrict__ Wr,
    const float* __restrict__ br, const int* __restrict__ flagp,
    float* __restrict__ S)
{
    __shared__ float rsh[1024];
    int t = threadIdx.x;
    for (int i = t; i < 1024; i += 256) rsh[i] = r[i];
    __syncthreads();
    float a0 = 0.f, a1 = 0.f, a2 = 0.f, a3 = 0.f;
    for (int c = 0; c < 256; ++c) {
        float w = Wr[c * 256 + t];
        a0 += rsh[c] * w;
        a1 += rsh[256 + c] * w;
        a2 += rsh[512 + c] * w;
        a3 += rsh[768 + c] * w;
    }
    float b = br[t];
    a0 += b; a1 += b; a2 += b; a3 += b;
    int ridx = (flagp[0] != 0) ? 1 : 0;
    S[t]         = ridx ? a1 : a0;
    S[256 + t]   = a2;
    S[512 + t]   = a3;
}

// ---------------------------------------------------------------------------
// K1: fused projections hQ/hK/hV/H = feature @ {Wq,Wk,Wv,Ww} + bias
// ---------------------------------------------------------------------------
__global__ __launch_bounds__(256) void k1_proj(
    const float* __restrict__ feat,
    const float* __restrict__ Wq, const float* __restrict__ bq,
    const float* __restrict__ Wk, const float* __restrict__ bk,
    const float* __restrict__ Wv, const float* __restrict__ bv,
    const float* __restrict__ Ww, const float* __restrict__ bw,
    float* __restrict__ hQ, float* __restrict__ hK,
    float* __restrict__ hV, float* __restrict__ Hb)
{
    __shared__ float AT[16][68];    // [k][m]
    __shared__ float Bs[16][132];   // [k][n]
    int t = threadIdx.x;
    int mat = blockIdx.x >> 1;
    int n0  = (blockIdx.x & 1) * 128;
    int m0  = blockIdx.y * 64;
    const float* W; const float* bias; float* dst;
    switch (mat) {
        case 0:  W = Wq; bias = bq; dst = hQ; break;
        case 1:  W = Wk; bias = bk; dst = hK; break;
        case 2:  W = Wv; bias = bv; dst = hV; break;
        default: W = Ww; bias = bw; dst = Hb; break;
    }
    float acc[4][8];
#pragma unroll
    for (int i = 0; i < 4; ++i)
#pragma unroll
        for (int j = 0; j < 8; ++j) acc[i][j] = 0.f;
    int mg = (t >> 4) * 4, jg = (t & 15) * 8;
    int am = t & 63, ak = (t >> 6) * 4;
    int bkk = t >> 4, bn = (t & 15) * 8;
    for (int k0 = 0; k0 < INF; k0 += 16) {
        __syncthreads();
        {
            int row = m0 + am;
            float4 v = make_float4(0.f, 0.f, 0.f, 0.f);
            if (row < NPOS) v = *(const float4*)(feat + (size_t)row * INF + k0 + ak);
            AT[ak + 0][am] = v.x; AT[ak + 1][am] = v.y;
            AT[ak + 2][am] = v.z; AT[ak + 3][am] = v.w;
        }
        {
            const float* p = W + (size_t)(k0 + bkk) * OUTF + n0 + bn;
            float4 u0 = *(const float4*)p;
            float4 u1 = *(const float4*)(p + 4);
            *(float4*)&Bs[bkk][bn]     = u0;
            *(float4*)&Bs[bkk][bn + 4] = u1;
        }
        __syncthreads();
#pragma unroll
        for (int kk = 0; kk < 16; ++kk) {
            float4 a  = *(const float4*)&AT[kk][mg];
            float4 b0 = *(const float4*)&Bs[kk][jg];
            float4 b1 = *(const float4*)&Bs[kk][jg + 4];
            float av[4] = {a.x, a.y, a.z, a.w};
            float bv_[8] = {b0.x, b0.y, b0.z, b0.w, b1.x, b1.y, b1.z, b1.w};
#pragma unroll
            for (int i = 0; i < 4; ++i)
#pragma unroll
                for (int j = 0; j < 8; ++j) acc[i][j] += av[i] * bv_[j];
        }
    }
#pragma unroll
    for (int i = 0; i < 4; ++i) {
        int row = m0 + mg + i;
        if (row < NPOS) {
#pragma unroll
            for (int j = 0; j < 8; ++j) {
                int n = n0 + jg + j;
                dst[(size_t)row * OUTF + n] = acc[i][j] + bias[n];
            }
        }
    }
}

// ---------------------------------------------------------------------------
// split helpers (truncation split: x = hi(bf16) + lo(bf16), rel err ~2^-16)
// ---------------------------------------------------------------------------
__device__ __forceinline__ void split2(float x0, float x1,
                                       unsigned& hi, unsigned& lo)
{
    unsigned u0 = __float_as_uint(x0), u1 = __float_as_uint(x1);
    unsigned h0 = u0 & 0xFFFF0000u,   h1 = u1 & 0xFFFF0000u;
    float r0 = x0 - __uint_as_float(h0);
    float r1 = x1 - __uint_as_float(h1);
    hi = (h0 >> 16) | h1;
    lo = (__float_as_uint(r0) >> 16) | (__float_as_uint(r1) & 0xFFFF0000u);
}

__device__ __forceinline__ void split1(float x, unsigned short& hi, unsigned short& lo)
{
    unsigned u = __float_as_uint(x);
    unsigned h = u & 0xFFFF0000u;
    float r = x - __uint_as_float(h);
    hi = (unsigned short)(h >> 16);
    lo = (unsigned short)(__float_as_uint(r) >> 16);
}

__device__ __forceinline__ short8 ldfrag(const unsigned short* base, int row, int kuo)
{
    const unsigned long long* p =
        (const unsigned long long*)(base + row * LDS_KS + kuo);
    union { unsigned long long q[2]; short8 s; } u;
    u.q[0] = p[0];
    u.q[1] = p[1];
    return u.s;
}

__device__ __forceinline__ short8 g16(const unsigned short* p)
{
    union { uint4 q; short8 s; } u;
    u.q = *(const uint4*)p;
    return u.s;
}

__device__ __forceinline__ short8 lds16u(const unsigned short* p)
{
    union { unsigned long long q[2]; short8 s; } u;
    u.q[0] = ((const unsigned long long*)p)[0];
    u.q[1] = ((const unsigned long long*)p)[1];
    return u.s;
}

// ---------------------------------------------------------------------------
// K2 (MFMA split-bf16, K-SPLIT): fp32 partials of
//   Bc[part][(h*2+g)*64+dd][j] = sum_k hK~*adj
// chunk 0 -> part0 [0,708); chunks 1..3 -> part1 thirds.
// ---------------------------------------------------------------------------
__global__ __launch_bounds__(256) void k2_mfma(
    const float* __restrict__ hK, const float* __restrict__ adj,
    const float* __restrict__ S,
    float* __restrict__ P0, float* __restrict__ P1)
{
    __shared__ unsigned short sAh[128 * LDS_KS];
    __shared__ unsigned short sAl[128 * LDS_KS];
    __shared__ unsigned short sBh[64 * LDS_KS];
    __shared__ unsigned short sBl[64 * LDS_KS];

    int t = threadIdx.x;
    int j0 = blockIdx.x * 64;
    int h  = blockIdx.y;
    int chunk = blockIdx.z;
    int part = (chunk == 0) ? 0 : 1;
    int kbeg = (chunk <= 1) ? 0 : (chunk - 1) * 1408;
    int kend = (chunk == 0) ? NG1 : ((chunk == 3) ? NG2 : chunk * 1408);
    int L = part ? NG2 : NG1;
    const float* kflat = hK + (part ? (size_t)NG1 * OUTF : 0);
    int rowoff = part ? NG1 : 0;
    float* Pout = chunk ? (P1 + (size_t)(chunk - 1) * PCH) : P0;

    int dd = t & 63;
    int kg = t >> 6;
    int jcol = j0 + dd;

    float sc[2][4];
#pragma unroll
    for (int g = 0; g < 2; ++g)
#pragma unroll
        for (int c = 0; c < 4; ++c)
            sc[g][c] = 0.5f * S[(g + part) * 256 + c * 64 + dd];

    f32x16 acc0, acc1;
#pragma unroll
    for (int i = 0; i < 16; ++i) { acc0[i] = 0.f; acc1[i] = 0.f; }

    int lane = t & 63;
    int half = lane >> 5;
    int ml = lane & 31;
    int arow = kg * 32 + ml;

    unsigned* uAh = (unsigned*)sAh;
    unsigned* uAl = (unsigned*)sAl;
    unsigned* uBh = (unsigned*)sBh;
    unsigned* uBl = (unsigned*)sBl;

    int ks0 = kbeg >> 5;
    int ks1 = (kend + 31) >> 5;
    for (int ks = ks0; ks < ks1; ++ks) {
        int k0 = ks * 32;
        float xa[8], xb[8];
#pragma unroll
        for (int i = 0; i < 8; ++i) {
            int kv = k0 + kg * 8 + i;
            bool okk = (kv < kend);
            xa[i] = okk ? kflat[(size_t)(h * L + kv) * 64 + dd] : 0.f;
            xb[i] = (okk && jcol < NPOS)
                        ? adj[(size_t)(rowoff + kv) * NPOS + jcol] : 0.f;
        }
        unsigned hA0[4], lA0[4], hA1[4], lA1[4], hB[4], lB[4];
#pragma unroll
        for (int i = 0; i < 8; i += 2) {
            float a0 = xa[i] * sc[0][i & 3];
            float a1 = xa[i + 1] * sc[0][(i + 1) & 3];
            split2(a0, a1, hA0[i >> 1], lA0[i >> 1]);
            float c0 = xa[i] * sc[1][i & 3];
            float c1 = xa[i + 1] * sc[1][(i + 1) & 3];
            split2(c0, c1, hA1[i >> 1], lA1[i >> 1]);
            split2(xb[i], xb[i + 1], hB[i >> 1], lB[i >> 1]);
        }
        __syncthreads();
        {
            int b0 = dd * 18 + kg * 4;
            int b1 = (64 + dd) * 18 + kg * 4;
            *(uint2*)(uAh + b0)     = make_uint2(hA0[0], hA0[1]);
            *(uint2*)(uAh + b0 + 2) = make_uint2(hA0[2], hA0[3]);
            *(uint2*)(uAl + b0)     = make_uint2(lA0[0], lA0[1]);
            *(uint2*)(uAl + b0 + 2) = make_uint2(lA0[2], lA0[3]);
            *(uint2*)(uAh + b1)     = make_uint2(hA1[0], hA1[1]);
            *(uint2*)(uAh + b1 + 2) = make_uint2(hA1[2], hA1[3]);
            *(uint2*)(uAl + b1)     = make_uint2(lA1[0], lA1[1]);
            *(uint2*)(uAl + b1 + 2) = make_uint2(lA1[2], lA1[3]);
            *(uint2*)(uBh + b0)     = make_uint2(hB[0], hB[1]);
            *(uint2*)(uBh + b0 + 2) = make_uint2(hB[2], hB[3]);
            *(uint2*)(uBl + b0)     = make_uint2(lB[0], lB[1]);
            *(uint2*)(uBl + b0 + 2) = make_uint2(lB[2], lB[3]);
        }
        __syncthreads();
#pragma unroll
        for (int kq = 0; kq < 2; ++kq) {
            int kuo = kq * 16 + half * 8;
            short8 aH = ldfrag(sAh, arow, kuo);
            short8 aL = ldfrag(sAl, arow, kuo);
            short8 b0H = ldfrag(sBh, ml, kuo);
            short8 b0L = ldfrag(sBl, ml, kuo);
            short8 b1H = ldfrag(sBh, 32 + ml, kuo);
            short8 b1L = ldfrag(sBl, 32 + ml, kuo);
            acc0 = __builtin_amdgcn_mfma_f32_32x32x16_bf16(aH, b0H, acc0, 0, 0, 0);
            acc0 = __builtin_amdgcn_mfma_f32_32x32x16_bf16(aH, b0L, acc0, 0, 0, 0);
            acc0 = __builtin_amdgcn_mfma_f32_32x32x16_bf16(aL, b0H, acc0, 0, 0, 0);
            acc1 = __builtin_amdgcn_mfma_f32_32x32x16_bf16(aH, b1H, acc1, 0, 0, 0);
            acc1 = __builtin_amdgcn_mfma_f32_32x32x16_bf16(aH, b1L, acc1, 0, 0, 0);
            acc1 = __builtin_amdgcn_mfma_f32_32x32x16_bf16(aL, b1H, acc1, 0, 0, 0);
        }
    }

    int col0 = j0 + ml;
    int col1 = j0 + 32 + ml;
#pragma unroll
    for (int reg = 0; reg < 16; ++reg) {
        int m = kg * 32 + (reg & 3) + 8 * (reg >> 2) + 4 * half;
        int g = m >> 6, ddm = m & 63;
        size_t rb = (size_t)((h * 2 + g) * 64 + ddm) * NPOS;
        Pout[rb + col0] = acc0[reg];
        if (col1 < NPOS) Pout[rb + col1] = acc1[reg];
    }
}

// ---------------------------------------------------------------------------
// K2R: reduce part1 chunks + split-bf16 + transpose to B' planes
//   Bhi/Blo[(g*4+h)][j][k], k = part*64+dd.  Rows j in [4900,4928) zeroed.
// ---------------------------------------------------------------------------
__global__ __launch_bounds__(256) void k2_reduce(
    const float* __restrict__ P0, const float* __restrict__ P1,
    unsigned short* __restrict__ Bhi, unsigned short* __restrict__ Blo)
{
    int t = threadIdx.x;
    int j = blockIdx.x * 256 + t;
    if (j >= JBP) return;
    int p = blockIdx.y;               // plane = g*4+h
    int g = p >> 2, h = p & 3;
    int kg = blockIdx.z;              // 16 k-values each
    int k0 = kg * 16;
    int rowb = (h * 2 + g) * 64;

    unsigned short hi[16], lo[16];
    if (j < NPOS) {
        if (k0 < 64) {
#pragma unroll
            for (int i = 0; i < 16; ++i) {
                float v = P0[(size_t)(rowb + k0 + i) * NPOS + j];
                split1(v, hi[i], lo[i]);
            }
        } else {
#pragma unroll
            for (int i = 0; i < 16; ++i) {
                size_t off = (size_t)(rowb + (k0 - 64) + i) * NPOS + j;
                float v = P1[off] + P1[off + PCH] + P1[off + 2 * (size_t)PCH];
                split1(v, hi[i], lo[i]);
            }
        }
    } else {
#pragma unroll
        for (int i = 0; i < 16; ++i) { hi[i] = 0; lo[i] = 0; }
    }
    size_t base = ((size_t)p * JBP + j) * 128 + k0;
    union { unsigned short us[16]; uint4 v[2]; } uh, ul;
#pragma unroll
    for (int i = 0; i < 16; ++i) { uh.us[i] = hi[i]; ul.us[i] = lo[i]; }
    *(uint4*)(Bhi + base)     = uh.v[0];
    *(uint4*)(Bhi + base + 8) = uh.v[1];
    *(uint4*)(Blo + base)     = ul.v[0];
    *(uint4*)(Blo + base + 8) = ul.v[1];
}

// ---------------------------------------------------------------------------
// QSPLIT: Q~ = hQ (head-reshaped) * S, split-bf16, k-contiguous rows.
// Row layout: g0: h*768 + ql (pad 768); g1: 3072 + h*4224 + ql (pad 4224).
// Pad rows (ql >= Lg) zeroed. 19968 rows x 128 k.
// ---------------------------------------------------------------------------
__global__ __launch_bounds__(256) void qsplit(
    const float* __restrict__ hQ, const float* __restrict__ S,
    unsigned short* __restrict__ Qh, unsigned short* __restrict__ Ql)
{
    int t = threadIdx.x;
    int row = blockIdx.x * 2 + (t >> 7);
    int k = t & 127;
    int g, h, ql, Lg, vbase;
    if (row < 3072) { g = 0; h = row / 768; ql = row - h * 768; Lg = NG1; vbase = 0; }
    else {
        int rr = row - 3072;
        g = 1; h = rr / 4224; ql = rr - h * 4224; Lg = NG2; vbase = NG1 * OUTF;
    }
    int d = k & 63, p = k >> 6;
    float v = 0.f;
    if (ql < Lg)
        v = hQ[vbase + (size_t)(h * Lg + ql) * 64 + d] *
            S[(g + p) * 256 + (ql & 3) * 64 + d];
    unsigned short hi, lo;
    split1(v, hi, lo);
    Qh[(size_t)row * 128 + k] = hi;
    Ql[(size_t)row * 128 + k] = lo;
}

// ---------------------------------------------------------------------------
// VTSPLIT: Vt[h][d][j] (hi/lo bf16, j-contiguous, j padded to JBP with zeros)
// from hV head-view hV[(h*4900 + j)*64 + d].
// ---------------------------------------------------------------------------
__global__ __launch_bounds__(256) void vtsplit(
    const float* __restrict__ hV,
    unsigned short* __restrict__ VtH, unsigned short* __restrict__ VtL)
{
    __shared__ float ls[128 * 65];
    int t = threadIdx.x;
    int j0 = blockIdx.x * 128;
    int h  = blockIdx.y;
#pragma unroll
    for (int i = 0; i < 32; ++i) {
        int idx = t + i * 256;
        int j = idx >> 6, d = idx & 63;
        float v = 0.f;
        int jg = j0 + j;
        if (jg < NPOS) v = hV[(size_t)(h * NPOS + jg) * 64 + d];
        ls[j * 65 + d] = v;
    }
    __syncthreads();
    int d = t >> 2, jseg = (t & 3) * 32;
#pragma unroll
    for (int i = 0; i < 32; ++i) {
        int j = jseg + i;
        int jg = j0 + j;
        if (jg < JBP) {
            unsigned short hi, lo;
            split1(ls[j * 65 + d], hi, lo);
            VtH[(size_t)(h * 64 + d) * JBP + jg] = hi;
            VtL[(size_t)(h * 64 + d) * JBP + jg] = lo;
        }
    }
}

// ---------------------------------------------------------------------------
// K3F v3: fused logits -> head-softmax -> PV, head-per-wave.
// Grid (78 pos-tiles of 64, NC j-chunks).  Block 512 thr = 8 waves:
// wave = (head h = w&3, pos-half ph = w>>2) -> 32 pos.
// Q-frags persistent in regs (jt-invariant).  Per jt (32 j):
//   QK: A = B'[h] j-rows (global), B = Qfrag -> qk[j-reg][pos-lane] (16 regs)
//   -> logits to LDS La[w][32j][33] -> barrier
//   -> 4-head softmax by all threads; alpha split-bf16 to Aa[w][pl][pos][36]
//   -> barrier -> PV: A = Vt d-rows (global), B = alpha frag (LDS),
//      pv[2][16] regs accumulate over the chunk's j-range.
// Epilogue: LDS transpose -> coalesced store to per-chunk mpart copy.
// No atomics, no spill (pv 32 + Q 64 + qk 16 regs).
// ---------------------------------------------------------------------------
__global__ __launch_bounds__(512, 2) void k3f_attn(
    const unsigned short* __restrict__ Qh, const unsigned short* __restrict__ Ql,
    const unsigned short* __restrict__ Bhi, const unsigned short* __restrict__ Blo,
    const unsigned short* __restrict__ VtH, const unsigned short* __restrict__ VtL,
    float* __restrict__ mpart)
{
    __shared__ __align__(16) char smem[70656];
    float* La = (float*)smem;                              // [8][32][33] f32
    unsigned short* Aa = (unsigned short*)(smem + 33792);  // [8][2][32][36] us

    int t = threadIdx.x;
    int w = t >> 6, lane = t & 63;
    int half = lane >> 5, ml = lane & 31;
    int h = w & 3, ph = w >> 2;

    int x = blockIdx.x;
    int c = blockIdx.y;
    int g = (x < 12) ? 0 : 1;
    int tile = g ? (x - 12) : x;
    int Lg = g ? NG2 : NG1;
    int posbase = g ? NG1 : 0;
    int qbase = g ? 3072 : 0;
    int hstr = g ? 4224 : 768;
    int q0 = tile * 64 + ph * 32;

    // persistent Q fragments (hi+lo), loaded once
    const unsigned short* qrowH = Qh + (size_t)(qbase + h * hstr + q0 + ml) * 128 + half * 8;
    const unsigned short* qrowL = Ql + (size_t)(qbase + h * hstr + q0 + ml) * 128 + half * 8;
    short8 qfH[8], qfL[8];
#pragma unroll
    for (int kc = 0; kc < 8; ++kc) {
        qfH[kc] = g16(qrowH + kc * 16);
        qfL[kc] = g16(qrowL + kc * 16);
    }

    const unsigned short* bHb = Bhi + ((size_t)(g * 4 + h) * JBP + ml) * 128 + half * 8;
    const unsigned short* bLb = Blo + ((size_t)(g * 4 + h) * JBP + ml) * 128 + half * 8;
    size_t vro = (size_t)(h * 64 + ml) * JBP;
    const unsigned short* vH0 = VtH + vro;
    const unsigned short* vL0 = VtL + vro;
    const unsigned short* vH1 = VtH + vro + (size_t)32 * JBP;
    const unsigned short* vL1 = VtL + vro + (size_t)32 * JBP;

    f32x16 pv[2];
#pragma unroll
    for (int n = 0; n < 2; ++n)
#pragma unroll
        for (int r = 0; r < 16; ++r) pv[n][r] = 0.f;

    // softmax-phase thread mapping
    int ph2 = t >> 8, rr2 = t & 255;
    int spos = rr2 >> 3, sj4 = (rr2 & 7) * 4;

    int jt0 = c * JTT, jt1 = jt0 + JTT;
    if (jt1 > NJT) jt1 = NJT;

    for (int jt = jt0; jt < jt1; ++jt) {
        int j0 = jt * 32;
        // ---- QK^T for own head ----
        f32x16 qk;
#pragma unroll
        for (int r = 0; r < 16; ++r) qk[r] = 0.f;
        const unsigned short* bH = bHb + (size_t)j0 * 128;
        const unsigned short* bL = bLb + (size_t)j0 * 128;
#pragma unroll
        for (int kc = 0; kc < 8; ++kc) {
            short8 aH = g16(bH + kc * 16);
            short8 aL = g16(bL + kc * 16);
            qk = __builtin_amdgcn_mfma_f32_32x32x16_bf16(aH, qfH[kc], qk, 0, 0, 0);
            qk = __builtin_amdgcn_mfma_f32_32x32x16_bf16(aH, qfL[kc], qk, 0, 0, 0);
            qk = __builtin_amdgcn_mfma_f32_32x32x16_bf16(aL, qfH[kc], qk, 0, 0, 0);
        }
        // logits -> LDS (D: col=ml=pos, row=j)
#pragma unroll
        for (int r = 0; r < 16; ++r) {
            int jrow = (r & 3) + 8 * (r >> 2) + 4 * half;
            La[(w * 32 + jrow) * 33 + ml] = qk[r];
        }
        __syncthreads();
        // ---- 4-head softmax + alpha split write ----
        {
            unsigned short hi_[4][4], lo_[4][4];   // [h][jj]
#pragma unroll
            for (int jj = 0; jj < 4; ++jj) {
                int j = sj4 + jj;
                float v0 = La[((ph2 * 4 + 0) * 32 + j) * 33 + spos];
                float v1 = La[((ph2 * 4 + 1) * 32 + j) * 33 + spos];
                float v2 = La[((ph2 * 4 + 2) * 32 + j) * 33 + spos];
                float v3 = La[((ph2 * 4 + 3) * 32 + j) * 33 + spos];
                float mx = fmaxf(fmaxf(v0, v1), fmaxf(v2, v3));
                float e0 = __expf(v0 - mx), e1 = __expf(v1 - mx);
                float e2 = __expf(v2 - mx), e3 = __expf(v3 - mx);
                float inv = 1.0f / (e0 + e1 + e2 + e3);
                split1(e0 * inv, hi_[0][jj], lo_[0][jj]);
                split1(e1 * inv, hi_[1][jj], lo_[1][jj]);
                split1(e2 * inv, hi_[2][jj], lo_[2][jj]);
                split1(e3 * inv, hi_[3][jj], lo_[3][jj]);
            }
#pragma unroll
            for (int hh = 0; hh < 4; ++hh) {
                unsigned long long Hw =
                    (unsigned long long)hi_[hh][0] |
                    ((unsigned long long)hi_[hh][1] << 16) |
                    ((unsigned long long)hi_[hh][2] << 32) |
                    ((unsigned long long)hi_[hh][3] << 48);
                unsigned long long Lw =
                    (unsigned long long)lo_[hh][0] |
                    ((unsigned long long)lo_[hh][1] << 16) |
                    ((unsigned long long)lo_[hh][2] << 32) |
                    ((unsigned long long)lo_[hh][3] << 48);
                *(unsigned long long*)&Aa[(((ph2 * 4 + hh) * 2 + 0) * 32 + spos) * 36 + sj4] = Hw;
                *(unsigned long long*)&Aa[(((ph2 * 4 + hh) * 2 + 1) * 32 + spos) * 36 + sj4] = Lw;
            }
        }
        __syncthreads();
        // ---- PV for own head ----
        const unsigned short* aBH = Aa + (size_t)((w * 2 + 0) * 32 + ml) * 36 + half * 8;
        const unsigned short* aBL = Aa + (size_t)((w * 2 + 1) * 32 + ml) * 36 + half * 8;
#pragma unroll
        for (int ck = 0; ck < 2; ++ck) {
            short8 paH = lds16u(aBH + ck * 16);
            short8 paL = lds16u(aBL + ck * 16);
            int jo = j0 + ck * 16 + half * 8;
            short8 w0H = g16(vH0 + jo);
            short8 w0L = g16(vL0 + jo);
            short8 w1H = g16(vH1 + jo);
            short8 w1L = g16(vL1 + jo);
            pv[0] = __builtin_amdgcn_mfma_f32_32x32x16_bf16(w0H, paH, pv[0], 0, 0, 0);
            pv[0] = __builtin_amdgcn_mfma_f32_32x32x16_bf16(w0H, paL, pv[0], 0, 0, 0);
            pv[0] = __builtin_amdgcn_mfma_f32_32x32x16_bf16(w0L, paH, pv[0], 0, 0, 0);
            pv[1] = __builtin_amdgcn_mfma_f32_32x32x16_bf16(w1H, paH, pv[1], 0, 0, 0);
            pv[1] = __builtin_amdgcn_mfma_f32_32x32x16_bf16(w1H, paL, pv[1], 0, 0, 0);
            pv[1] = __builtin_amdgcn_mfma_f32_32x32x16_bf16(w1L, paH, pv[1], 0, 0, 0);
        }
    }

    // ---- epilogue: LDS transpose -> coalesced store to mpart chunk c ----
    __syncthreads();
    float* scr = (float*)smem + w * 2112;   // [32 pos][66]
#pragma unroll
    for (int nt = 0; nt < 2; ++nt)
#pragma unroll
        for (int r = 0; r < 16; ++r) {
            int drow = (r & 3) + 8 * (r >> 2) + 4 * half;
            scr[ml * 66 + nt * 32 + drow] = pv[nt][r];
        }
    float* mpc = mpart + (size_t)c * NPOS * OUTF;
#pragma unroll 4
    for (int i = 0; i < 32; ++i) {
        int pg = q0 + i;
        if (pg < Lg)
            mpc[(size_t)(posbase + pg) * OUTF + h * 64 + lane] = scr[i * 66 + lane];
    }
}

// ---------------------------------------------------------------------------
// E1: m = sum_c mpart[c]; relu; ln1; write concat buffer [H | ln1(relu(m))]
// ---------------------------------------------------------------------------
__global__ __launch_bounds__(256) void e1_relu_ln(
    const float* __restrict__ mpart, const float* __restrict__ Hb,
    const float* __restrict__ g1, const float* __restrict__ b1,
    float* __restrict__ cc)
{
    int w = threadIdx.x >> 6, lane = threadIdx.x & 63;
    int row = blockIdx.x * 4 + w;
    int c = lane * 4;
    const size_t CST = (size_t)NPOS * OUTF;
    float4 x0 = *(const float4*)(mpart + (size_t)row * OUTF + c);
#pragma unroll
    for (int k = 1; k < NC; ++k) {
        float4 a = *(const float4*)(mpart + k * CST + (size_t)row * OUTF + c);
        x0.x += a.x; x0.y += a.y; x0.z += a.z; x0.w += a.w;
    }
    float x[4] = { fmaxf(x0.x, 0.f), fmaxf(x0.y, 0.f),
                   fmaxf(x0.z, 0.f), fmaxf(x0.w, 0.f) };
    float s = x[0] + x[1] + x[2] + x[3];
#pragma unroll
    for (int m = 32; m > 0; m >>= 1) s += __shfl_xor(s, m, 64);
    float mu = s * (1.0f / 256.0f);
    float vs = 0.f;
#pragma unroll
    for (int i = 0; i < 4; ++i) { float d = x[i] - mu; vs += d * d; }
#pragma unroll
    for (int m = 32; m > 0; m >>= 1) vs += __shfl_xor(vs, m, 64);
    float rs = rsqrtf(vs * (1.0f / 256.0f) + 1e-5f);
    float4 y;
    y.x = (x[0] - mu) * rs * g1[c + 0] + b1[c + 0];
    y.y = (x[1] - mu) * rs * g1[c + 1] + b1[c + 1];
    y.z = (x[2] - mu) * rs * g1[c + 2] + b1[c + 2];
    y.w = (x[3] - mu) * rs * g1[c + 3] + b1[c + 3];
    *(float4*)(cc + (size_t)row * INF + OUTF + c) = y;
    float4 hh = *(const float4*)(Hb + (size_t)row * OUTF + c);
    *(float4*)(cc + (size_t)row * INF + c) = hh;
}

// ---------------------------------------------------------------------------
// E2: beta = sigmoid(cc @ Wbeta + bbeta); out = beta*m1 + (1-beta)*H
// ---------------------------------------------------------------------------
__global__ __launch_bounds__(256) void e2_beta(
    const float* __restrict__ cc, const float* __restrict__ Wb,
    const float* __restrict__ bb, float* __restrict__ outb)
{
    __shared__ float AT[16][68];
    __shared__ float Bs[16][132];
    int t = threadIdx.x;
    int n0 = blockIdx.x * 128;
    int m0 = blockIdx.y * 64;
    float acc[4][8];
#pragma unroll
    for (int i = 0; i < 4; ++i)
#pragma unroll
        for (int j = 0; j < 8; ++j) acc[i][j] = 0.f;
    int mg = (t >> 4) * 4, jg = (t & 15) * 8;
    int am = t & 63, ak = (t >> 6) * 4;
    int bkk = t >> 4, bn = (t & 15) * 8;
    for (int k0 = 0; k0 < INF; k0 += 16) {
        __syncthreads();
        {
            int row = m0 + am;
            float4 v = make_float4(0.f, 0.f, 0.f, 0.f);
            if (row < NPOS) v = *(const float4*)(cc + (size_t)row * INF + k0 + ak);
            AT[ak + 0][am] = v.x; AT[ak + 1][am] = v.y;
            AT[ak + 2][am] = v.z; AT[ak + 3][am] = v.w;
        }
        {
            const float* p = Wb + (size_t)(k0 + bkk) * OUTF + n0 + bn;
            float4 u0 = *(const float4*)p;
            float4 u1 = *(const float4*)(p + 4);
            *(float4*)&Bs[bkk][bn]     = u0;
            *(float4*)&Bs[bkk][bn + 4] = u1;
        }
        __syncthreads();
#pragma unroll
        for (int kk = 0; kk < 16; ++kk) {
            float4 a  = *(const float4*)&AT[kk][mg];
            float4 b0 = *(const float4*)&Bs[kk][jg];
            float4 b1 = *(const float4*)&Bs[kk][jg + 4];
            float av[4] = {a.x, a.y, a.z, a.w};
            float bv_[8] = {b0.x, b0.y, b0.z, b0.w, b1.x, b1.y, b1.z, b1.w};
#pragma unroll
            for (int i = 0; i < 4; ++i)
#pragma unroll
                for (int j = 0; j < 8; ++j) acc[i][j] += av[i] * bv_[j];
        }
    }
#pragma unroll
    for (int i = 0; i < 4; ++i) {
        int row = m0 + mg + i;
        if (row < NPOS) {
#pragma unroll
            for (int j = 0; j < 8; ++j) {
                int n = n0 + jg + j;
                float x = acc[i][j] + bb[n];
                float sg = 1.0f / (1.0f + __expf(-x));
                float m1v = cc[(size_t)row * INF + OUTF + n];
                float Hv  = cc[(size_t)row * INF + n];
                outb[(size_t)row * OUTF + n] = sg * m1v + (1.0f - sg) * Hv;
            }
        }
    }
}

// ---------------------------------------------------------------------------
// E3: t = out @ w1 + b1 ; ln2(eps=1e-6) ; tanh -> h2.
// ---------------------------------------------------------------------------
__global__ __launch_bounds__(256) void e3_w1_ln2(
    const float* __restrict__ outb, const float* __restrict__ w1,
    const float* __restrict__ b1v, const float* __restrict__ g2,
    const float* __restrict__ b2v, float* __restrict__ h2o)
{
    __shared__ float As[16][260];
    __shared__ float Bs[16][260];
    __shared__ float red[16][17];
    int t = threadIdx.x;
    int m0 = blockIdx.x * 16;
    {
        int rr = t >> 4, c4 = (t & 15) * 4;
        int row = m0 + rr;
#pragma unroll
        for (int i = 0; i < 4; ++i) {
            int c = c4 + i * 64;
            float4 x = make_float4(0.f, 0.f, 0.f, 0.f);
            if (row < NPOS) x = *(const float4*)(outb + (size_t)row * OUTF + c);
            *(float4*)&As[rr][c] = x;
        }
    }
    int q = t & 15, dg = (t >> 4) * 16;
    float acc[16];
#pragma unroll
    for (int i = 0; i < 16; ++i) acc[i] = 0.f;
    for (int k0 = 0; k0 < 256; k0 += 16) {
        __syncthreads();
        {
            int kk = t >> 4, n16 = (t & 15) * 16;
#pragma unroll
            for (int i = 0; i < 4; ++i) {
                float4 x = *(const float4*)(w1 + (size_t)(k0 + kk) * OUTF + n16 + i * 4);
                *(float4*)&Bs[kk][n16 + i * 4] = x;
            }
        }
        __syncthreads();
#pragma unroll
        for (int kk = 0; kk < 16; ++kk) {
            float a = As[q][k0 + kk];
#pragma unroll
            for (int i = 0; i < 16; i += 4) {
                float4 b = *(const float4*)&Bs[kk][dg + i];
                acc[i + 0] += a * b.x; acc[i + 1] += a * b.y;
                acc[i + 2] += a * b.z; acc[i + 3] += a * b.w;
            }
        }
    }
    float x[16];
#pragma unroll
    for (int i = 0; i < 16; ++i) x[i] = acc[i] + b1v[dg + i];
    float ps = 0.f;
#pragma unroll
    for (int i = 0; i < 16; ++i) ps += x[i];
    __syncthreads();
    red[t >> 4][q] = ps;
    __syncthreads();
    float s = 0.f;
#pragma unroll
    for (int i = 0; i < 16; ++i) s += red[i][q];
    float mu = s * (1.0f / 256.0f);
    float pvv = 0.f;
#pragma unroll
    for (int i = 0; i < 16; ++i) { float d = x[i] - mu; pvv += d * d; }
    __syncthreads();
    red[t >> 4][q] = pvv;
    __syncthreads();
    float v = 0.f;
#pragma unroll
    for (int i = 0; i < 16; ++i) v += red[i][q];
    float rs = rsqrtf(v * (1.0f / 256.0f) + 1e-6f);
    int row = m0 + q;
    if (row < NPOS) {
#pragma unroll
        for (int i = 0; i < 16; ++i) {
            int n = dg + i;
            h2o[(size_t)row * OUTF + n] = tanhf((x[i] - mu) * rs * g2[n] + b2v[n]);
        }
    }
}

// ---------------------------------------------------------------------------
// E4: final = h2 @ w2  (no bias) -> d_out
// ---------------------------------------------------------------------------
__global__ __launch_bounds__(256) void e4_final(
    const float* __restrict__ h2in, const float* __restrict__ w2,
    float* __restrict__ outp)
{
    __shared__ float AT[16][68];
    __shared__ float Bs[16][132];
    int t = threadIdx.x;
    int n0 = blockIdx.x * 128;
    int m0 = blockIdx.y * 64;
    float acc[4][8];
#pragma unroll
    for (int i = 0; i < 4; ++i)
#pragma unroll
        for (int j = 0; j < 8; ++j) acc[i][j] = 0.f;
    int mg = (t >> 4) * 4, jg = (t & 15) * 8;
    int am = t & 63, ak = (t >> 6) * 4;
    int bkk = t >> 4, bn = (t & 15) * 8;
    for (int k0 = 0; k0 < 256; k0 += 16) {
        __syncthreads();
        {
            int row = m0 + am;
            float4 v = make_float4(0.f, 0.f, 0.f, 0.f);
            if (row < NPOS) v = *(const float4*)(h2in + (size_t)row * OUTF + k0 + ak);
            AT[ak + 0][am] = v.x; AT[ak + 1][am] = v.y;
            AT[ak + 2][am] = v.z; AT[ak + 3][am] = v.w;
        }
        {
            const float* p = w2 + (size_t)(k0 + bkk) * OUTF + n0 + bn;
            float4 u0 = *(const float4*)p;
            float4 u1 = *(const float4*)(p + 4);
            *(float4*)&Bs[bkk][bn]     = u0;
            *(float4*)&Bs[bkk][bn + 4] = u1;
        }
        __syncthreads();
#pragma unroll
        for (int kk = 0; kk < 16; ++kk) {
            float4 a  = *(const float4*)&AT[kk][mg];
            float4 b0 = *(const float4*)&Bs[kk][jg];
            float4 b1 = *(const float4*)&Bs[kk][jg + 4];
            float av[4] = {a.x, a.y, a.z, a.w};
            float bv_[8] = {b0.x, b0.y, b0.z, b0.w, b1.x, b1.y, b1.z, b1.w};
#pragma unroll
            for (int i = 0; i < 4; ++i)
#pragma unroll
                for (int j = 0; j < 8; ++j) acc[i][j] += av[i] * bv_[j];
        }
    }
#pragma unroll
    for (int i = 0; i < 4; ++i) {
        int row = m0 + mg + i;
        if (row < NPOS) {
#pragma unroll
            for (int j = 0; j < 8; ++j) {
                outp[(size_t)row * OUTF + n0 + jg + j] = acc[i][j];
            }
        }
    }
}

// ---------------------------------------------------------------------------
extern "C" void kernel_launch(void* const* d_in, const int* in_sizes, int n_in,
                              void* d_out, int out_size, void* d_ws, size_t ws_size,
                              hipStream_t stream)
{
    const float* feature = (const float*)d_in[0];
    const float* adj   = (const float*)d_in[1];
    const float* r     = (const float*)d_in[2];
    const float* Wq    = (const float*)d_in[3];
    const float* bq    = (const float*)d_in[4];
    const float* Wk    = (const float*)d_in[5];
    const float* bk    = (const float*)d_in[6];
    const float* Wv    = (const float*)d_in[7];
    const float* bv    = (const float*)d_in[8];
    const float* Ww    = (const float*)d_in[9];
    const float* bw    = (const float*)d_in[10];
    const float* Wr    = (const float*)d_in[11];
    const float* br    = (const float*)d_in[12];
    const float* Wbeta = (const float*)d_in[13];
    const float* bbeta = (const float*)d_in[14];
    const float* ln1g  = (const float*)d_in[15];
    const float* ln1b  = (const float*)d_in[16];
    const float* w1    = (const float*)d_in[17];
    const float* b1    = (const float*)d_in[18];
    const float* ln2g  = (const float*)d_in[19];
    const float* ln2b  = (const float*)d_in[20];
    const float* w2    = (const float*)d_in[21];
    const int*   flag  = (const int*)d_in[22];
    float* out = (float*)d_out;

    // --- workspace layout (liveness-aliased, peak ~75.4 MB) ---
    // k2 phase:   P0 [0,10.04M), P1 [10.04M,40.14M); hK aliases Bhi slot.
    // k2_reduce:  P0,P1 -> Bhi,Blo (hK dead).
    // transforms: Qh,Ql,VtH,VtL carved from dead P0/P1 [0,15.27M).
    // k3f:        mpart[NC=4] at [15.27M, 35.34M)  (< P1 end 40.14M).
    // e-chain:    cc [0,10.04M), outb [10.04M,15.05M) (Qh/Ql/Vt dead),
    //             hh2 over mpart c0 (dead after e1).
    char* ws = (char*)d_ws;
    float*          P0    = (float*)(ws + 0);
    float*          P1    = (float*)(ws + 10035200);
    unsigned short* Qh    = (unsigned short*)(ws + 0);         // 5,111,808
    unsigned short* Qlo   = (unsigned short*)(ws + 5111808);   // 5,111,808
    unsigned short* VtH   = (unsigned short*)(ws + 10223616);  // 2,523,136
    unsigned short* VtL   = (unsigned short*)(ws + 12746752);  // 2,523,136
    float*          mpart = (float*)(ws + 15269888);           // 4 x 5,017,600
    float*          cc    = (float*)(ws + 0);                  // 10,035,200
    float*          outb  = (float*)(ws + 10035200);           // 5,017,600
    float*          hh2   = (float*)(ws + 15269888);           // 5,017,600
    unsigned short* Bhi   = (unsigned short*)(ws + 40140800);  // 10,092,544
    unsigned short* Blo   = (unsigned short*)(ws + 50233344);  // 10,092,544
    float*          hK    = (float*)(ws + 40140800);           // aliases Bhi (dead first)
    float*          hQ    = (float*)(ws + 60325888);           // 5,017,600
    float*          hV    = (float*)(ws + 65343488);           // 5,017,600
    float*          Hb    = (float*)(ws + 70361088);           // 5,017,600
    float*          S     = (float*)(ws + 75378688);           // 3,072

    k0_rp<<<1, 256, 0, stream>>>(r, Wr, br, flag, S);
    k1_proj<<<dim3(8, 77), 256, 0, stream>>>(feature, Wq, bq, Wk, bk, Wv, bv, Ww, bw,
                                             hQ, hK, hV, Hb);
    k2_mfma<<<dim3(77, 4, 4), 256, 0, stream>>>(hK, adj, S, P0, P1);
    k2_reduce<<<dim3(20, 8, 8), 256, 0, stream>>>(P0, P1, Bhi, Blo);
    qsplit<<<9984, 256, 0, stream>>>(hQ, S, Qh, Qlo);
    vtsplit<<<dim3(39, 4), 256, 0, stream>>>(hV, VtH, VtL);
    k3f_attn<<<dim3(78, NC), 512, 0, stream>>>(Qh, Qlo, Bhi, Blo, VtH, VtL, mpart);
    e1_relu_ln<<<1225, 256, 0, stream>>>(mpart, Hb, ln1g, ln1b, cc);
    e2_beta<<<dim3(2, 77), 256, 0, stream>>>(cc, Wbeta, bbeta, outb);
    e3_w1_ln2<<<307, 256, 0, stream>>>(outb, w1, b1, ln2g, ln2b, hh2);
    e4_final<<<dim3(2, 77), 256, 0, stream>>>(hh2, w2, out);
}

// Round 5
// 976.382 us; speedup vs baseline: 1.6181x; 1.0900x over previous
//
#include <hip/hip_runtime.h>
#include <hip/hip_bf16.h>
#include <math.h>

#define NPOS 4900
#define NG1  708
#define NG2  4192
#define INF  512
#define OUTF 256
#define JBP  4928       // B'/Vt padded j extent (rows >= 4900 zeroed)
#define NJT  154        // JBP/32 j-tiles
#define NC   6          // j-chunks (mpart copies)
#define JTT  26         // ceil(154/6)
#define LDS_KS 36       // k2: ushort k-stride (32 + 4 pad)
#define PCH   2508800   // k2 partial chunk stride in floats (512*4900)
#define KSPL 2112       // part1 K-split point -- MUST be multiple of 32

typedef __attribute__((ext_vector_type(8))) short short8;
typedef __attribute__((ext_vector_type(16))) float f32x16;

// ---------------------------------------------------------------------------
// K0: rp = r @ Wr + br  (4x256); store S[0]=rp[ridx], S[1]=rp[2], S[2]=rp[3]
// ---------------------------------------------------------------------------
__global__ __launch_bounds__(256) void k0_rp(
    const float* __restrict__ r, const float* __restrict__ Wr,
    const float* __restrict__ br, const int* __restrict__ flagp,
    float* __restrict__ S)
{
    __shared__ float rsh[1024];
    int t = threadIdx.x;
    for (int i = t; i < 1024; i += 256) rsh[i] = r[i];
    __syncthreads();
    float a0 = 0.f, a1 = 0.f, a2 = 0.f, a3 = 0.f;
    for (int c = 0; c < 256; ++c) {
        float w = Wr[c * 256 + t];
        a0 += rsh[c] * w;
        a1 += rsh[256 + c] * w;
        a2 += rsh[512 + c] * w;
        a3 += rsh[768 + c] * w;
    }
    float b = br[t];
    a0 += b; a1 += b; a2 += b; a3 += b;
    int ridx = (flagp[0] != 0) ? 1 : 0;
    S[t]         = ridx ? a1 : a0;
    S[256 + t]   = a2;
    S[512 + t]   = a3;
}

// ---------------------------------------------------------------------------
// K1: fused projections hQ/hK/hV/H = feature @ {Wq,Wk,Wv,Ww} + bias
// ---------------------------------------------------------------------------
__global__ __launch_bounds__(256) void k1_proj(
    const float* __restrict__ feat,
    const float* __restrict__ Wq, const float* __restrict__ bq,
    const float* __restrict__ Wk, const float* __restrict__ bk,
    const float* __restrict__ Wv, const float* __restrict__ bv,
    const float* __restrict__ Ww, const float* __restrict__ bw,
    float* __restrict__ hQ, float* __restrict__ hK,
    float* __restrict__ hV, float* __restrict__ Hb)
{
    __shared__ float AT[16][68];    // [k][m]
    __shared__ float Bs[16][132];   // [k][n]
    int t = threadIdx.x;
    int mat = blockIdx.x >> 1;
    int n0  = (blockIdx.x & 1) * 128;
    int m0  = blockIdx.y * 64;
    const float* W; const float* bias; float* dst;
    switch (mat) {
        case 0:  W = Wq; bias = bq; dst = hQ; break;
        case 1:  W = Wk; bias = bk; dst = hK; break;
        case 2:  W = Wv; bias = bv; dst = hV; break;
        default: W = Ww; bias = bw; dst = Hb; break;
    }
    float acc[4][8];
#pragma unroll
    for (int i = 0; i < 4; ++i)
#pragma unroll
        for (int j = 0; j < 8; ++j) acc[i][j] = 0.f;
    int mg = (t >> 4) * 4, jg = (t & 15) * 8;
    int am = t & 63, ak = (t >> 6) * 4;
    int bkk = t >> 4, bn = (t & 15) * 8;
    for (int k0 = 0; k0 < INF; k0 += 16) {
        __syncthreads();
        {
            int row = m0 + am;
            float4 v = make_float4(0.f, 0.f, 0.f, 0.f);
            if (row < NPOS) v = *(const float4*)(feat + (size_t)row * INF + k0 + ak);
            AT[ak + 0][am] = v.x; AT[ak + 1][am] = v.y;
            AT[ak + 2][am] = v.z; AT[ak + 3][am] = v.w;
        }
        {
            const float* p = W + (size_t)(k0 + bkk) * OUTF + n0 + bn;
            float4 u0 = *(const float4*)p;
            float4 u1 = *(const float4*)(p + 4);
            *(float4*)&Bs[bkk][bn]     = u0;
            *(float4*)&Bs[bkk][bn + 4] = u1;
        }
        __syncthreads();
#pragma unroll
        for (int kk = 0; kk < 16; ++kk) {
            float4 a  = *(const float4*)&AT[kk][mg];
            float4 b0 = *(const float4*)&Bs[kk][jg];
            float4 b1 = *(const float4*)&Bs[kk][jg + 4];
            float av[4] = {a.x, a.y, a.z, a.w};
            float bv_[8] = {b0.x, b0.y, b0.z, b0.w, b1.x, b1.y, b1.z, b1.w};
#pragma unroll
            for (int i = 0; i < 4; ++i)
#pragma unroll
                for (int j = 0; j < 8; ++j) acc[i][j] += av[i] * bv_[j];
        }
    }
#pragma unroll
    for (int i = 0; i < 4; ++i) {
        int row = m0 + mg + i;
        if (row < NPOS) {
#pragma unroll
            for (int j = 0; j < 8; ++j) {
                int n = n0 + jg + j;
                dst[(size_t)row * OUTF + n] = acc[i][j] + bias[n];
            }
        }
    }
}

// ---------------------------------------------------------------------------
// split helpers (truncation split: x = hi(bf16) + lo(bf16), rel err ~2^-16)
// ---------------------------------------------------------------------------
__device__ __forceinline__ void split2(float x0, float x1,
                                       unsigned& hi, unsigned& lo)
{
    unsigned u0 = __float_as_uint(x0), u1 = __float_as_uint(x1);
    unsigned h0 = u0 & 0xFFFF0000u,   h1 = u1 & 0xFFFF0000u;
    float r0 = x0 - __uint_as_float(h0);
    float r1 = x1 - __uint_as_float(h1);
    hi = (h0 >> 16) | h1;
    lo = (__float_as_uint(r0) >> 16) | (__float_as_uint(r1) & 0xFFFF0000u);
}

__device__ __forceinline__ void split1(float x, unsigned short& hi, unsigned short& lo)
{
    unsigned u = __float_as_uint(x);
    unsigned h = u & 0xFFFF0000u;
    float r = x - __uint_as_float(h);
    hi = (unsigned short)(h >> 16);
    lo = (unsigned short)(__float_as_uint(r) >> 16);
}

__device__ __forceinline__ short8 ldfrag(const unsigned short* base, int row, int kuo)
{
    const unsigned long long* p =
        (const unsigned long long*)(base + row * LDS_KS + kuo);
    union { unsigned long long q[2]; short8 s; } u;
    u.q[0] = p[0];
    u.q[1] = p[1];
    return u.s;
}

__device__ __forceinline__ short8 g16(const unsigned short* p)
{
    union { uint4 q; short8 s; } u;
    u.q = *(const uint4*)p;
    return u.s;
}

__device__ __forceinline__ short8 lds16u(const unsigned short* p)
{
    union { unsigned long long q[2]; short8 s; } u;
    u.q[0] = ((const unsigned long long*)p)[0];
    u.q[1] = ((const unsigned long long*)p)[1];
    return u.s;
}

// ---------------------------------------------------------------------------
// K2 (MFMA split-bf16, K-SPLIT): fp32 partials of
//   Bc[part][(h*2+g)*64+dd][j] = sum_k hK~*adj
// chunk 0 -> part0 [0,708); chunks 1..2 -> part1 [0,KSPL),[KSPL,4192).
// KSPL is 32-aligned: the ks loop has no lower-bound mask within a step.
// ---------------------------------------------------------------------------
__global__ __launch_bounds__(256) void k2_mfma(
    const float* __restrict__ hK, const float* __restrict__ adj,
    const float* __restrict__ S,
    float* __restrict__ P0, float* __restrict__ P1)
{
    __shared__ unsigned short sAh[128 * LDS_KS];
    __shared__ unsigned short sAl[128 * LDS_KS];
    __shared__ unsigned short sBh[64 * LDS_KS];
    __shared__ unsigned short sBl[64 * LDS_KS];

    int t = threadIdx.x;
    int j0 = blockIdx.x * 64;
    int h  = blockIdx.y;
    int chunk = blockIdx.z;
    int part = (chunk == 0) ? 0 : 1;
    int kbeg = (chunk <= 1) ? 0 : KSPL;
    int kend = (chunk == 0) ? NG1 : ((chunk == 2) ? NG2 : KSPL);
    int L = part ? NG2 : NG1;
    const float* kflat = hK + (part ? (size_t)NG1 * OUTF : 0);
    int rowoff = part ? NG1 : 0;
    float* Pout = chunk ? (P1 + (size_t)(chunk - 1) * PCH) : P0;

    int dd = t & 63;
    int kg = t >> 6;
    int jcol = j0 + dd;

    float sc[2][4];
#pragma unroll
    for (int g = 0; g < 2; ++g)
#pragma unroll
        for (int c = 0; c < 4; ++c)
            sc[g][c] = 0.5f * S[(g + part) * 256 + c * 64 + dd];

    f32x16 acc0, acc1;
#pragma unroll
    for (int i = 0; i < 16; ++i) { acc0[i] = 0.f; acc1[i] = 0.f; }

    int lane = t & 63;
    int half = lane >> 5;
    int ml = lane & 31;
    int arow = kg * 32 + ml;

    unsigned* uAh = (unsigned*)sAh;
    unsigned* uAl = (unsigned*)sAl;
    unsigned* uBh = (unsigned*)sBh;
    unsigned* uBl = (unsigned*)sBl;

    int ks0 = kbeg >> 5;
    int ks1 = (kend + 31) >> 5;
    for (int ks = ks0; ks < ks1; ++ks) {
        int k0 = ks * 32;
        float xa[8], xb[8];
#pragma unroll
        for (int i = 0; i < 8; ++i) {
            int kv = k0 + kg * 8 + i;
            bool okk = (kv < kend);
            xa[i] = okk ? kflat[(size_t)(h * L + kv) * 64 + dd] : 0.f;
            xb[i] = (okk && jcol < NPOS)
                        ? adj[(size_t)(rowoff + kv) * NPOS + jcol] : 0.f;
        }
        unsigned hA0[4], lA0[4], hA1[4], lA1[4], hB[4], lB[4];
#pragma unroll
        for (int i = 0; i < 8; i += 2) {
            float a0 = xa[i] * sc[0][i & 3];
            float a1 = xa[i + 1] * sc[0][(i + 1) & 3];
            split2(a0, a1, hA0[i >> 1], lA0[i >> 1]);
            float c0 = xa[i] * sc[1][i & 3];
            float c1 = xa[i + 1] * sc[1][(i + 1) & 3];
            split2(c0, c1, hA1[i >> 1], lA1[i >> 1]);
            split2(xb[i], xb[i + 1], hB[i >> 1], lB[i >> 1]);
        }
        __syncthreads();
        {
            int b0 = dd * 18 + kg * 4;
            int b1 = (64 + dd) * 18 + kg * 4;
            *(uint2*)(uAh + b0)     = make_uint2(hA0[0], hA0[1]);
            *(uint2*)(uAh + b0 + 2) = make_uint2(hA0[2], hA0[3]);
            *(uint2*)(uAl + b0)     = make_uint2(lA0[0], lA0[1]);
            *(uint2*)(uAl + b0 + 2) = make_uint2(lA0[2], lA0[3]);
            *(uint2*)(uAh + b1)     = make_uint2(hA1[0], hA1[1]);
            *(uint2*)(uAh + b1 + 2) = make_uint2(hA1[2], hA1[3]);
            *(uint2*)(uAl + b1)     = make_uint2(lA1[0], lA1[1]);
            *(uint2*)(uAl + b1 + 2) = make_uint2(lA1[2], lA1[3]);
            *(uint2*)(uBh + b0)     = make_uint2(hB[0], hB[1]);
            *(uint2*)(uBh + b0 + 2) = make_uint2(hB[2], hB[3]);
            *(uint2*)(uBl + b0)     = make_uint2(lB[0], lB[1]);
            *(uint2*)(uBl + b0 + 2) = make_uint2(lB[2], lB[3]);
        }
        __syncthreads();
#pragma unroll
        for (int kq = 0; kq < 2; ++kq) {
            int kuo = kq * 16 + half * 8;
            short8 aH = ldfrag(sAh, arow, kuo);
            short8 aL = ldfrag(sAl, arow, kuo);
            short8 b0H = ldfrag(sBh, ml, kuo);
            short8 b0L = ldfrag(sBl, ml, kuo);
            short8 b1H = ldfrag(sBh, 32 + ml, kuo);
            short8 b1L = ldfrag(sBl, 32 + ml, kuo);
            acc0 = __builtin_amdgcn_mfma_f32_32x32x16_bf16(aH, b0H, acc0, 0, 0, 0);
            acc0 = __builtin_amdgcn_mfma_f32_32x32x16_bf16(aH, b0L, acc0, 0, 0, 0);
            acc0 = __builtin_amdgcn_mfma_f32_32x32x16_bf16(aL, b0H, acc0, 0, 0, 0);
            acc1 = __builtin_amdgcn_mfma_f32_32x32x16_bf16(aH, b1H, acc1, 0, 0, 0);
            acc1 = __builtin_amdgcn_mfma_f32_32x32x16_bf16(aH, b1L, acc1, 0, 0, 0);
            acc1 = __builtin_amdgcn_mfma_f32_32x32x16_bf16(aL, b1H, acc1, 0, 0, 0);
        }
    }

    int col0 = j0 + ml;
    int col1 = j0 + 32 + ml;
#pragma unroll
    for (int reg = 0; reg < 16; ++reg) {
        int m = kg * 32 + (reg & 3) + 8 * (reg >> 2) + 4 * half;
        int g = m >> 6, ddm = m & 63;
        size_t rb = (size_t)((h * 2 + g) * 64 + ddm) * NPOS;
        Pout[rb + col0] = acc0[reg];
        if (col1 < NPOS) Pout[rb + col1] = acc1[reg];
    }
}

// ---------------------------------------------------------------------------
// K2R: reduce part1 chunks + split-bf16 + transpose to B' planes
//   Bhi/Blo[(g*4+h)][j][k], k = part*64+dd.  Rows j in [4900,4928) zeroed.
// ---------------------------------------------------------------------------
__global__ __launch_bounds__(256) void k2_reduce(
    const float* __restrict__ P0, const float* __restrict__ P1,
    unsigned short* __restrict__ Bhi, unsigned short* __restrict__ Blo)
{
    int t = threadIdx.x;
    int j = blockIdx.x * 256 + t;
    if (j >= JBP) return;
    int p = blockIdx.y;               // plane = g*4+h
    int g = p >> 2, h = p & 3;
    int kg = blockIdx.z;              // 16 k-values each
    int k0 = kg * 16;
    int rowb = (h * 2 + g) * 64;

    unsigned short hi[16], lo[16];
    if (j < NPOS) {
        if (k0 < 64) {
#pragma unroll
            for (int i = 0; i < 16; ++i) {
                float v = P0[(size_t)(rowb + k0 + i) * NPOS + j];
                split1(v, hi[i], lo[i]);
            }
        } else {
#pragma unroll
            for (int i = 0; i < 16; ++i) {
                size_t off = (size_t)(rowb + (k0 - 64) + i) * NPOS + j;
                float v = P1[off] + P1[off + PCH];
                split1(v, hi[i], lo[i]);
            }
        }
    } else {
#pragma unroll
        for (int i = 0; i < 16; ++i) { hi[i] = 0; lo[i] = 0; }
    }
    size_t base = ((size_t)p * JBP + j) * 128 + k0;
    union { unsigned short us[16]; uint4 v[2]; } uh, ul;
#pragma unroll
    for (int i = 0; i < 16; ++i) { uh.us[i] = hi[i]; ul.us[i] = lo[i]; }
    *(uint4*)(Bhi + base)     = uh.v[0];
    *(uint4*)(Bhi + base + 8) = uh.v[1];
    *(uint4*)(Blo + base)     = ul.v[0];
    *(uint4*)(Blo + base + 8) = ul.v[1];
}

// ---------------------------------------------------------------------------
// QSPLIT: Q~ = hQ (head-reshaped) * S, split-bf16, k-contiguous rows.
// Row layout: g0: h*768 + ql (pad 768); g1: 3072 + h*4224 + ql (pad 4224).
// Pad rows (ql >= Lg) zeroed. 19968 rows x 128 k.
// ---------------------------------------------------------------------------
__global__ __launch_bounds__(256) void qsplit(
    const float* __restrict__ hQ, const float* __restrict__ S,
    unsigned short* __restrict__ Qh, unsigned short* __restrict__ Ql)
{
    int t = threadIdx.x;
    int row = blockIdx.x * 2 + (t >> 7);
    int k = t & 127;
    int g, h, ql, Lg, vbase;
    if (row < 3072) { g = 0; h = row / 768; ql = row - h * 768; Lg = NG1; vbase = 0; }
    else {
        int rr = row - 3072;
        g = 1; h = rr / 4224; ql = rr - h * 4224; Lg = NG2; vbase = NG1 * OUTF;
    }
    int d = k & 63, p = k >> 6;
    float v = 0.f;
    if (ql < Lg)
        v = hQ[vbase + (size_t)(h * Lg + ql) * 64 + d] *
            S[(g + p) * 256 + (ql & 3) * 64 + d];
    unsigned short hi, lo;
    split1(v, hi, lo);
    Qh[(size_t)row * 128 + k] = hi;
    Ql[(size_t)row * 128 + k] = lo;
}

// ---------------------------------------------------------------------------
// VTSPLIT: Vt[h][d][j] (hi/lo bf16, j-contiguous, j padded to JBP with zeros)
// from hV head-view hV[(h*4900 + j)*64 + d].
// ---------------------------------------------------------------------------
__global__ __launch_bounds__(256) void vtsplit(
    const float* __restrict__ hV,
    unsigned short* __restrict__ VtH, unsigned short* __restrict__ VtL)
{
    __shared__ float ls[128 * 65];
    int t = threadIdx.x;
    int j0 = blockIdx.x * 128;
    int h  = blockIdx.y;
#pragma unroll
    for (int i = 0; i < 32; ++i) {
        int idx = t + i * 256;
        int j = idx >> 6, d = idx & 63;
        float v = 0.f;
        int jg = j0 + j;
        if (jg < NPOS) v = hV[(size_t)(h * NPOS + jg) * 64 + d];
        ls[j * 65 + d] = v;
    }
    __syncthreads();
    int d = t >> 2, jseg = (t & 3) * 32;
#pragma unroll
    for (int i = 0; i < 32; ++i) {
        int j = jseg + i;
        int jg = j0 + j;
        if (jg < JBP) {
            unsigned short hi, lo;
            split1(ls[j * 65 + d], hi, lo);
            VtH[(size_t)(h * 64 + d) * JBP + jg] = hi;
            VtL[(size_t)(h * 64 + d) * JBP + jg] = lo;
        }
    }
}

// ---------------------------------------------------------------------------
// K3F v4: fused logits -> head-softmax -> PV, head-per-wave, 4 waves/block.
// Grid (154 pos-tiles of 32, NC j-chunks).  Block 256 thr = 4 waves:
// wave w = head h, 32 pos.  Q-frags persistent in regs.  Per jt (32 j):
//   QK: A = B'[h] j-rows (global), B = Qfrag -> qk[j-reg][pos-lane]
//   -> logits to LDS La[4][32][33] -> barrier
//   -> 4-head softmax by all 256 threads; alpha split-bf16 -> Aa[4][2][32][36]
//   -> barrier -> PV: A = Vt d-rows (global), B = alpha frag (LDS),
//      pv[2][16] accumulate over chunk's j-range.
// Epilogue: LDS transpose -> coalesced store to per-chunk mpart copy.
// LDS 35.3 KB -> 4 blocks/CU; grid 924 blocks (~3.6/CU).
// ---------------------------------------------------------------------------
__global__ __launch_bounds__(256, 4) void k3f_attn(
    const unsigned short* __restrict__ Qh, const unsigned short* __restrict__ Ql,
    const unsigned short* __restrict__ Bhi, const unsigned short* __restrict__ Blo,
    const unsigned short* __restrict__ VtH, const unsigned short* __restrict__ VtL,
    float* __restrict__ mpart)
{
    __shared__ __align__(16) char smem[35328];
    float* La = (float*)smem;                              // [4][32][33] f32
    unsigned short* Aa = (unsigned short*)(smem + 16896);  // [4][2][32][36] us

    int t = threadIdx.x;
    int w = t >> 6, lane = t & 63;
    int half = lane >> 5, ml = lane & 31;
    int h = w;

    int x = blockIdx.x;
    int c = blockIdx.y;
    int g = (x < 23) ? 0 : 1;
    int tile = g ? (x - 23) : x;
    int Lg = g ? NG2 : NG1;
    int posbase = g ? NG1 : 0;
    int qbase = g ? 3072 : 0;
    int hstr = g ? 4224 : 768;
    int q0 = tile * 32;

    // persistent Q fragments (hi+lo), loaded once
    const unsigned short* qrowH = Qh + (size_t)(qbase + h * hstr + q0 + ml) * 128 + half * 8;
    const unsigned short* qrowL = Ql + (size_t)(qbase + h * hstr + q0 + ml) * 128 + half * 8;
    short8 qfH[8], qfL[8];
#pragma unroll
    for (int kc = 0; kc < 8; ++kc) {
        qfH[kc] = g16(qrowH + kc * 16);
        qfL[kc] = g16(qrowL + kc * 16);
    }

    const unsigned short* bHb = Bhi + ((size_t)(g * 4 + h) * JBP + ml) * 128 + half * 8;
    const unsigned short* bLb = Blo + ((size_t)(g * 4 + h) * JBP + ml) * 128 + half * 8;
    size_t vro = (size_t)(h * 64 + ml) * JBP;
    const unsigned short* vH0 = VtH + vro;
    const unsigned short* vL0 = VtL + vro;
    const unsigned short* vH1 = VtH + vro + (size_t)32 * JBP;
    const unsigned short* vL1 = VtL + vro + (size_t)32 * JBP;

    f32x16 pv[2];
#pragma unroll
    for (int n = 0; n < 2; ++n)
#pragma unroll
        for (int r = 0; r < 16; ++r) pv[n][r] = 0.f;

    // softmax-phase thread mapping: 32 spos x 8 j-groups of 4
    int spos = t >> 3, sj4 = (t & 7) * 4;

    int jt0 = c * JTT, jt1 = jt0 + JTT;
    if (jt1 > NJT) jt1 = NJT;

    for (int jt = jt0; jt < jt1; ++jt) {
        int j0 = jt * 32;
        // ---- QK^T for own head ----
        f32x16 qk;
#pragma unroll
        for (int r = 0; r < 16; ++r) qk[r] = 0.f;
        const unsigned short* bH = bHb + (size_t)j0 * 128;
        const unsigned short* bL = bLb + (size_t)j0 * 128;
#pragma unroll
        for (int kc = 0; kc < 8; ++kc) {
            short8 aH = g16(bH + kc * 16);
            short8 aL = g16(bL + kc * 16);
            qk = __builtin_amdgcn_mfma_f32_32x32x16_bf16(aH, qfH[kc], qk, 0, 0, 0);
            qk = __builtin_amdgcn_mfma_f32_32x32x16_bf16(aH, qfL[kc], qk, 0, 0, 0);
            qk = __builtin_amdgcn_mfma_f32_32x32x16_bf16(aL, qfH[kc], qk, 0, 0, 0);
        }
        // logits -> LDS (D: col=ml=pos, row=j)
#pragma unroll
        for (int r = 0; r < 16; ++r) {
            int jrow = (r & 3) + 8 * (r >> 2) + 4 * half;
            La[(w * 32 + jrow) * 33 + ml] = qk[r];
        }
        __syncthreads();
        // ---- 4-head softmax + alpha split write ----
        {
            unsigned short hi_[4][4], lo_[4][4];   // [h][jj]
#pragma unroll
            for (int jj = 0; jj < 4; ++jj) {
                int j = sj4 + jj;
                float v0 = La[(0 * 32 + j) * 33 + spos];
                float v1 = La[(1 * 32 + j) * 33 + spos];
                float v2 = La[(2 * 32 + j) * 33 + spos];
                float v3 = La[(3 * 32 + j) * 33 + spos];
                float mx = fmaxf(fmaxf(v0, v1), fmaxf(v2, v3));
                float e0 = __expf(v0 - mx), e1 = __expf(v1 - mx);
                float e2 = __expf(v2 - mx), e3 = __expf(v3 - mx);
                float inv = 1.0f / (e0 + e1 + e2 + e3);
                split1(e0 * inv, hi_[0][jj], lo_[0][jj]);
                split1(e1 * inv, hi_[1][jj], lo_[1][jj]);
                split1(e2 * inv, hi_[2][jj], lo_[2][jj]);
                split1(e3 * inv, hi_[3][jj], lo_[3][jj]);
            }
#pragma unroll
            for (int hh = 0; hh < 4; ++hh) {
                unsigned long long Hw =
                    (unsigned long long)hi_[hh][0] |
                    ((unsigned long long)hi_[hh][1] << 16) |
                    ((unsigned long long)hi_[hh][2] << 32) |
                    ((unsigned long long)hi_[hh][3] << 48);
                unsigned long long Lw =
                    (unsigned long long)lo_[hh][0] |
                    ((unsigned long long)lo_[hh][1] << 16) |
                    ((unsigned long long)lo_[hh][2] << 32) |
                    ((unsigned long long)lo_[hh][3] << 48);
                *(unsigned long long*)&Aa[((hh * 2 + 0) * 32 + spos) * 36 + sj4] = Hw;
                *(unsigned long long*)&Aa[((hh * 2 + 1) * 32 + spos) * 36 + sj4] = Lw;
            }
        }
        __syncthreads();
        // ---- PV for own head ----
        const unsigned short* aBH = Aa + (size_t)((w * 2 + 0) * 32 + ml) * 36 + half * 8;
        const unsigned short* aBL = Aa + (size_t)((w * 2 + 1) * 32 + ml) * 36 + half * 8;
#pragma unroll
        for (int ck = 0; ck < 2; ++ck) {
            short8 paH = lds16u(aBH + ck * 16);
            short8 paL = lds16u(aBL + ck * 16);
            int jo = j0 + ck * 16 + half * 8;
            short8 w0H = g16(vH0 + jo);
            short8 w0L = g16(vL0 + jo);
            short8 w1H = g16(vH1 + jo);
            short8 w1L = g16(vL1 + jo);
            pv[0] = __builtin_amdgcn_mfma_f32_32x32x16_bf16(w0H, paH, pv[0], 0, 0, 0);
            pv[0] = __builtin_amdgcn_mfma_f32_32x32x16_bf16(w0H, paL, pv[0], 0, 0, 0);
            pv[0] = __builtin_amdgcn_mfma_f32_32x32x16_bf16(w0L, paH, pv[0], 0, 0, 0);
            pv[1] = __builtin_amdgcn_mfma_f32_32x32x16_bf16(w1H, paH, pv[1], 0, 0, 0);
            pv[1] = __builtin_amdgcn_mfma_f32_32x32x16_bf16(w1H, paL, pv[1], 0, 0, 0);
            pv[1] = __builtin_amdgcn_mfma_f32_32x32x16_bf16(w1L, paH, pv[1], 0, 0, 0);
        }
    }

    // ---- epilogue: LDS transpose -> coalesced store to mpart chunk c ----
    __syncthreads();
    float* scr = (float*)smem + w * 2112;   // [32 pos][66]
#pragma unroll
    for (int nt = 0; nt < 2; ++nt)
#pragma unroll
        for (int r = 0; r < 16; ++r) {
            int drow = (r & 3) + 8 * (r >> 2) + 4 * half;
            scr[ml * 66 + nt * 32 + drow] = pv[nt][r];
        }
    float* mpc = mpart + (size_t)c * NPOS * OUTF;
#pragma unroll 4
    for (int i = 0; i < 32; ++i) {
        int pg = q0 + i;
        if (pg < Lg)
            mpc[(size_t)(posbase + pg) * OUTF + h * 64 + lane] = scr[i * 66 + lane];
    }
}

// ---------------------------------------------------------------------------
// E1: m = sum_c mpart[c]; relu; ln1; write concat buffer [H | ln1(relu(m))]
// ---------------------------------------------------------------------------
__global__ __launch_bounds__(256) void e1_relu_ln(
    const float* __restrict__ mpart, const float* __restrict__ Hb,
    const float* __restrict__ g1, const float* __restrict__ b1,
    float* __restrict__ cc)
{
    int w = threadIdx.x >> 6, lane = threadIdx.x & 63;
    int row = blockIdx.x * 4 + w;
    int c = lane * 4;
    const size_t CST = (size_t)NPOS * OUTF;
    float4 x0 = *(const float4*)(mpart + (size_t)row * OUTF + c);
#pragma unroll
    for (int k = 1; k < NC; ++k) {
        float4 a = *(const float4*)(mpart + k * CST + (size_t)row * OUTF + c);
        x0.x += a.x; x0.y += a.y; x0.z += a.z; x0.w += a.w;
    }
    float x[4] = { fmaxf(x0.x, 0.f), fmaxf(x0.y, 0.f),
                   fmaxf(x0.z, 0.f), fmaxf(x0.w, 0.f) };
    float s = x[0] + x[1] + x[2] + x[3];
#pragma unroll
    for (int m = 32; m > 0; m >>= 1) s += __shfl_xor(s, m, 64);
    float mu = s * (1.0f / 256.0f);
    float vs = 0.f;
#pragma unroll
    for (int i = 0; i < 4; ++i) { float d = x[i] - mu; vs += d * d; }
#pragma unroll
    for (int m = 32; m > 0; m >>= 1) vs += __shfl_xor(vs, m, 64);
    float rs = rsqrtf(vs * (1.0f / 256.0f) + 1e-5f);
    float4 y;
    y.x = (x[0] - mu) * rs * g1[c + 0] + b1[c + 0];
    y.y = (x[1] - mu) * rs * g1[c + 1] + b1[c + 1];
    y.z = (x[2] - mu) * rs * g1[c + 2] + b1[c + 2];
    y.w = (x[3] - mu) * rs * g1[c + 3] + b1[c + 3];
    *(float4*)(cc + (size_t)row * INF + OUTF + c) = y;
    float4 hh = *(const float4*)(Hb + (size_t)row * OUTF + c);
    *(float4*)(cc + (size_t)row * INF + c) = hh;
}

// ---------------------------------------------------------------------------
// E2: beta = sigmoid(cc @ Wbeta + bbeta); out = beta*m1 + (1-beta)*H
// ---------------------------------------------------------------------------
__global__ __launch_bounds__(256) void e2_beta(
    const float* __restrict__ cc, const float* __restrict__ Wb,
    const float* __restrict__ bb, float* __restrict__ outb)
{
    __shared__ float AT[16][68];
    __shared__ float Bs[16][132];
    int t = threadIdx.x;
    int n0 = blockIdx.x * 128;
    int m0 = blockIdx.y * 64;
    float acc[4][8];
#pragma unroll
    for (int i = 0; i < 4; ++i)
#pragma unroll
        for (int j = 0; j < 8; ++j) acc[i][j] = 0.f;
    int mg = (t >> 4) * 4, jg = (t & 15) * 8;
    int am = t & 63, ak = (t >> 6) * 4;
    int bkk = t >> 4, bn = (t & 15) * 8;
    for (int k0 = 0; k0 < INF; k0 += 16) {
        __syncthreads();
        {
            int row = m0 + am;
            float4 v = make_float4(0.f, 0.f, 0.f, 0.f);
            if (row < NPOS) v = *(const float4*)(cc + (size_t)row * INF + k0 + ak);
            AT[ak + 0][am] = v.x; AT[ak + 1][am] = v.y;
            AT[ak + 2][am] = v.z; AT[ak + 3][am] = v.w;
        }
        {
            const float* p = Wb + (size_t)(k0 + bkk) * OUTF + n0 + bn;
            float4 u0 = *(const float4*)p;
            float4 u1 = *(const float4*)(p + 4);
            *(float4*)&Bs[bkk][bn]     = u0;
            *(float4*)&Bs[bkk][bn + 4] = u1;
        }
        __syncthreads();
#pragma unroll
        for (int kk = 0; kk < 16; ++kk) {
            float4 a  = *(const float4*)&AT[kk][mg];
            float4 b0 = *(const float4*)&Bs[kk][jg];
            float4 b1 = *(const float4*)&Bs[kk][jg + 4];
            float av[4] = {a.x, a.y, a.z, a.w};
            float bv_[8] = {b0.x, b0.y, b0.z, b0.w, b1.x, b1.y, b1.z, b1.w};
#pragma unroll
            for (int i = 0; i < 4; ++i)
#pragma unroll
                for (int j = 0; j < 8; ++j) acc[i][j] += av[i] * bv_[j];
        }
    }
#pragma unroll
    for (int i = 0; i < 4; ++i) {
        int row = m0 + mg + i;
        if (row < NPOS) {
#pragma unroll
            for (int j = 0; j < 8; ++j) {
                int n = n0 + jg + j;
                float x = acc[i][j] + bb[n];
                float sg = 1.0f / (1.0f + __expf(-x));
                float m1v = cc[(size_t)row * INF + OUTF + n];
                float Hv  = cc[(size_t)row * INF + n];
                outb[(size_t)row * OUTF + n] = sg * m1v + (1.0f - sg) * Hv;
            }
        }
    }
}

// ---------------------------------------------------------------------------
// E3: t = out @ w1 + b1 ; ln2(eps=1e-6) ; tanh -> h2.
// ---------------------------------------------------------------------------
__global__ __launch_bounds__(256) void e3_w1_ln2(
    const float* __restrict__ outb, const float* __restrict__ w1,
    const float* __restrict__ b1v, const float* __restrict__ g2,
    const float* __restrict__ b2v, float* __restrict__ h2o)
{
    __shared__ float As[16][260];
    __shared__ float Bs[16][260];
    __shared__ float red[16][17];
    int t = threadIdx.x;
    int m0 = blockIdx.x * 16;
    {
        int rr = t >> 4, c4 = (t & 15) * 4;
        int row = m0 + rr;
#pragma unroll
        for (int i = 0; i < 4; ++i) {
            int c = c4 + i * 64;
            float4 x = make_float4(0.f, 0.f, 0.f, 0.f);
            if (row < NPOS) x = *(const float4*)(outb + (size_t)row * OUTF + c);
            *(float4*)&As[rr][c] = x;
        }
    }
    int q = t & 15, dg = (t >> 4) * 16;
    float acc[16];
#pragma unroll
    for (int i = 0; i < 16; ++i) acc[i] = 0.f;
    for (int k0 = 0; k0 < 256; k0 += 16) {
        __syncthreads();
        {
            int kk = t >> 4, n16 = (t & 15) * 16;
#pragma unroll
            for (int i = 0; i < 4; ++i) {
                float4 x = *(const float4*)(w1 + (size_t)(k0 + kk) * OUTF + n16 + i * 4);
                *(float4*)&Bs[kk][n16 + i * 4] = x;
            }
        }
        __syncthreads();
#pragma unroll
        for (int kk = 0; kk < 16; ++kk) {
            float a = As[q][k0 + kk];
#pragma unroll
            for (int i = 0; i < 16; i += 4) {
                float4 b = *(const float4*)&Bs[kk][dg + i];
                acc[i + 0] += a * b.x; acc[i + 1] += a * b.y;
                acc[i + 2] += a * b.z; acc[i + 3] += a * b.w;
            }
        }
    }
    float x[16];
#pragma unroll
    for (int i = 0; i < 16; ++i) x[i] = acc[i] + b1v[dg + i];
    float ps = 0.f;
#pragma unroll
    for (int i = 0; i < 16; ++i) ps += x[i];
    __syncthreads();
    red[t >> 4][q] = ps;
    __syncthreads();
    float s = 0.f;
#pragma unroll
    for (int i = 0; i < 16; ++i) s += red[i][q];
    float mu = s * (1.0f / 256.0f);
    float pvv = 0.f;
#pragma unroll
    for (int i = 0; i < 16; ++i) { float d = x[i] - mu; pvv += d * d; }
    __syncthreads();
    red[t >> 4][q] = pvv;
    __syncthreads();
    float v = 0.f;
#pragma unroll
    for (int i = 0; i < 16; ++i) v += red[i][q];
    float rs = rsqrtf(v * (1.0f / 256.0f) + 1e-6f);
    int row = m0 + q;
    if (row < NPOS) {
#pragma unroll
        for (int i = 0; i < 16; ++i) {
            int n = dg + i;
            h2o[(size_t)row * OUTF + n] = tanhf((x[i] - mu) * rs * g2[n] + b2v[n]);
        }
    }
}

// ---------------------------------------------------------------------------
// E4: final = h2 @ w2  (no bias) -> d_out
// ---------------------------------------------------------------------------
__global__ __launch_bounds__(256) void e4_final(
    const float* __restrict__ h2in, const float* __restrict__ w2,
    float* __restrict__ outp)
{
    __shared__ float AT[16][68];
    __shared__ float Bs[16][132];
    int t = threadIdx.x;
    int n0 = blockIdx.x * 128;
    int m0 = blockIdx.y * 64;
    float acc[4][8];
#pragma unroll
    for (int i = 0; i < 4; ++i)
#pragma unroll
        for (int j = 0; j < 8; ++j) acc[i][j] = 0.f;
    int mg = (t >> 4) * 4, jg = (t & 15) * 8;
    int am = t & 63, ak = (t >> 6) * 4;
    int bkk = t >> 4, bn = (t & 15) * 8;
    for (int k0 = 0; k0 < 256; k0 += 16) {
        __syncthreads();
        {
            int row = m0 + am;
            float4 v = make_float4(0.f, 0.f, 0.f, 0.f);
            if (row < NPOS) v = *(const float4*)(h2in + (size_t)row * OUTF + k0 + ak);
            AT[ak + 0][am] = v.x; AT[ak + 1][am] = v.y;
            AT[ak + 2][am] = v.z; AT[ak + 3][am] = v.w;
        }
        {
            const float* p = w2 + (size_t)(k0 + bkk) * OUTF + n0 + bn;
            float4 u0 = *(const float4*)p;
            float4 u1 = *(const float4*)(p + 4);
            *(float4*)&Bs[bkk][bn]     = u0;
            *(float4*)&Bs[bkk][bn + 4] = u1;
        }
        __syncthreads();
#pragma unroll
        for (int kk = 0; kk < 16; ++kk) {
            float4 a  = *(const float4*)&AT[kk][mg];
            float4 b0 = *(const float4*)&Bs[kk][jg];
            float4 b1 = *(const float4*)&Bs[kk][jg + 4];
            float av[4] = {a.x, a.y, a.z, a.w};
            float bv_[8] = {b0.x, b0.y, b0.z, b0.w, b1.x, b1.y, b1.z, b1.w};
#pragma unroll
            for (int i = 0; i < 4; ++i)
#pragma unroll
                for (int j = 0; j < 8; ++j) acc[i][j] += av[i] * bv_[j];
        }
    }
#pragma unroll
    for (int i = 0; i < 4; ++i) {
        int row = m0 + mg + i;
        if (row < NPOS) {
#pragma unroll
            for (int j = 0; j < 8; ++j) {
                outp[(size_t)row * OUTF + n0 + jg + j] = acc[i][j];
            }
        }
    }
}

// ---------------------------------------------------------------------------
extern "C" void kernel_launch(void* const* d_in, const int* in_sizes, int n_in,
                              void* d_out, int out_size, void* d_ws, size_t ws_size,
                              hipStream_t stream)
{
    const float* feature = (const float*)d_in[0];
    const float* adj   = (const float*)d_in[1];
    const float* r     = (const float*)d_in[2];
    const float* Wq    = (const float*)d_in[3];
    const float* bq    = (const float*)d_in[4];
    const float* Wk    = (const float*)d_in[5];
    const float* bk    = (const float*)d_in[6];
    const float* Wv    = (const float*)d_in[7];
    const float* bv    = (const float*)d_in[8];
    const float* Ww    = (const float*)d_in[9];
    const float* bw    = (const float*)d_in[10];
    const float* Wr    = (const float*)d_in[11];
    const float* br    = (const float*)d_in[12];
    const float* Wbeta = (const float*)d_in[13];
    const float* bbeta = (const float*)d_in[14];
    const float* ln1g  = (const float*)d_in[15];
    const float* ln1b  = (const float*)d_in[16];
    const float* w1    = (const float*)d_in[17];
    const float* b1    = (const float*)d_in[18];
    const float* ln2g  = (const float*)d_in[19];
    const float* ln2b  = (const float*)d_in[20];
    const float* w2    = (const float*)d_in[21];
    const int*   flag  = (const int*)d_in[22];
    float* out = (float*)d_out;

    // --- workspace layout (liveness-aliased, peak ~70.6 MB) ---
    // order: k0, k1, qsplit, vtsplit, k2_mfma, k2_reduce, k3f, e1..e4
    // [0,10.22M)      Qh,Ql          (qsplit->k3f);  cc after k3f
    // [10.22,15.27M)  VtH,VtL        (vtsplit->k3f); outb after k3f
    // [15.27,20.29M)  Hb             (k1->e1)
    // [20.29,50.39M)  P0+P1 (k2) == mpart[6] (k3f->e1) == hh2 (e3)
    // [50.39,60.49M)  Bhi (k2_reduce->k3f) == hK (k1->k2_mfma)
    // [60.49,70.58M)  Blo (k2_reduce->k3f) == hQ,hV (k1->q/vtsplit)
    // [70.58M]        S
    char* ws = (char*)d_ws;
    unsigned short* Qh    = (unsigned short*)(ws + 0);         // 5,111,808
    unsigned short* Qlo   = (unsigned short*)(ws + 5111808);   // 5,111,808
    unsigned short* VtH   = (unsigned short*)(ws + 10223616);  // 2,523,136
    unsigned short* VtL   = (unsigned short*)(ws + 12746752);  // 2,523,136
    float*          Hb    = (float*)(ws + 15269888);           // 5,017,600
    float*          P0    = (float*)(ws + 20287488);           // 10,035,200
    float*          P1    = (float*)(ws + 30322688);           // 2 x 10,035,200
    float*          mpart = (float*)(ws + 20287488);           // 6 x 5,017,600
    unsigned short* Bhi   = (unsigned short*)(ws + 50393088);  // 10,092,544
    unsigned short* Blo   = (unsigned short*)(ws + 60485632);  // 10,092,544
    float*          hK    = (float*)(ws + 50393088);           // alias Bhi
    float*          hQ    = (float*)(ws + 60485632);           // alias Blo lo
    float*          hV    = (float*)(ws + 65503232);           // alias Blo hi
    float*          cc    = (float*)(ws + 0);                  // 10,035,200
    float*          outb  = (float*)(ws + 10223616);           // 5,017,600
    float*          hh2   = (float*)(ws + 20287488);           // 5,017,600
    float*          S     = (float*)(ws + 70578176);           // 3,072

    k0_rp<<<1, 256, 0, stream>>>(r, Wr, br, flag, S);
    k1_proj<<<dim3(8, 77), 256, 0, stream>>>(feature, Wq, bq, Wk, bk, Wv, bv, Ww, bw,
                                             hQ, hK, hV, Hb);
    qsplit<<<9984, 256, 0, stream>>>(hQ, S, Qh, Qlo);
    vtsplit<<<dim3(39, 4), 256, 0, stream>>>(hV, VtH, VtL);
    k2_mfma<<<dim3(77, 4, 3), 256, 0, stream>>>(hK, adj, S, P0, P1);
    k2_reduce<<<dim3(20, 8, 8), 256, 0, stream>>>(P0, P1, Bhi, Blo);
    k3f_attn<<<dim3(154, NC), 256, 0, stream>>>(Qh, Qlo, Bhi, Blo, VtH, VtL, mpart);
    e1_relu_ln<<<1225, 256, 0, stream>>>(mpart, Hb, ln1g, ln1b, cc);
    e2_beta<<<dim3(2, 77), 256, 0, stream>>>(cc, Wbeta, bbeta, outb);
    e3_w1_ln2<<<307, 256, 0, stream>>>(outb, w1, b1, ln2g, ln2b, hh2);
    e4_final<<<dim3(2, 77), 256, 0, stream>>>(hh2, w2, out);
}

// Round 6
// 859.066 us; speedup vs baseline: 1.8391x; 1.1366x over previous
//
#include <hip/hip_runtime.h>
#include <hip/hip_bf16.h>
#include <math.h>

#define NPOS 4900
#define NG1  708
#define NG2  4192
#define INF  512
#define OUTF 256
#define JBP  4928       // B'/Vt padded j extent (rows >= 4900 zeroed)
#define NJT  154        // JBP/32 j-tiles
#define NC   6          // j-chunks (mpart copies)
#define JTT  26         // ceil(154/6)
#define LDS_KS 36       // k2: ushort k-stride (32 + 4 pad)
#define PCH   2508800   // k2 partial chunk stride in floats (512*4900)
#define KSPL 2112       // part1 K-split point -- MUST be multiple of 32

typedef __attribute__((ext_vector_type(8))) short short8;
typedef __attribute__((ext_vector_type(16))) float f32x16;

// ---------------------------------------------------------------------------
// K0: rp = r @ Wr + br  (4x256); store S[0]=rp[ridx], S[1]=rp[2], S[2]=rp[3]
// ---------------------------------------------------------------------------
__global__ __launch_bounds__(256) void k0_rp(
    const float* __restrict__ r, const float* __restrict__ Wr,
    const float* __restrict__ br, const int* __restrict__ flagp,
    float* __restrict__ S)
{
    __shared__ float rsh[1024];
    int t = threadIdx.x;
    for (int i = t; i < 1024; i += 256) rsh[i] = r[i];
    __syncthreads();
    float a0 = 0.f, a1 = 0.f, a2 = 0.f, a3 = 0.f;
    for (int c = 0; c < 256; ++c) {
        float w = Wr[c * 256 + t];
        a0 += rsh[c] * w;
        a1 += rsh[256 + c] * w;
        a2 += rsh[512 + c] * w;
        a3 += rsh[768 + c] * w;
    }
    float b = br[t];
    a0 += b; a1 += b; a2 += b; a3 += b;
    int ridx = (flagp[0] != 0) ? 1 : 0;
    S[t]         = ridx ? a1 : a0;
    S[256 + t]   = a2;
    S[512 + t]   = a3;
}

// ---------------------------------------------------------------------------
// K1: fused projections hQ/hK/hV/H = feature @ {Wq,Wk,Wv,Ww} + bias
// ---------------------------------------------------------------------------
__global__ __launch_bounds__(256) void k1_proj(
    const float* __restrict__ feat,
    const float* __restrict__ Wq, const float* __restrict__ bq,
    const float* __restrict__ Wk, const float* __restrict__ bk,
    const float* __restrict__ Wv, const float* __restrict__ bv,
    const float* __restrict__ Ww, const float* __restrict__ bw,
    float* __restrict__ hQ, float* __restrict__ hK,
    float* __restrict__ hV, float* __restrict__ Hb)
{
    __shared__ float AT[16][68];    // [k][m]
    __shared__ float Bs[16][132];   // [k][n]
    int t = threadIdx.x;
    int mat = blockIdx.x >> 1;
    int n0  = (blockIdx.x & 1) * 128;
    int m0  = blockIdx.y * 64;
    const float* W; const float* bias; float* dst;
    switch (mat) {
        case 0:  W = Wq; bias = bq; dst = hQ; break;
        case 1:  W = Wk; bias = bk; dst = hK; break;
        case 2:  W = Wv; bias = bv; dst = hV; break;
        default: W = Ww; bias = bw; dst = Hb; break;
    }
    float acc[4][8];
#pragma unroll
    for (int i = 0; i < 4; ++i)
#pragma unroll
        for (int j = 0; j < 8; ++j) acc[i][j] = 0.f;
    int mg = (t >> 4) * 4, jg = (t & 15) * 8;
    int am = t & 63, ak = (t >> 6) * 4;
    int bkk = t >> 4, bn = (t & 15) * 8;
    for (int k0 = 0; k0 < INF; k0 += 16) {
        __syncthreads();
        {
            int row = m0 + am;
            float4 v = make_float4(0.f, 0.f, 0.f, 0.f);
            if (row < NPOS) v = *(const float4*)(feat + (size_t)row * INF + k0 + ak);
            AT[ak + 0][am] = v.x; AT[ak + 1][am] = v.y;
            AT[ak + 2][am] = v.z; AT[ak + 3][am] = v.w;
        }
        {
            const float* p = W + (size_t)(k0 + bkk) * OUTF + n0 + bn;
            float4 u0 = *(const float4*)p;
            float4 u1 = *(const float4*)(p + 4);
            *(float4*)&Bs[bkk][bn]     = u0;
            *(float4*)&Bs[bkk][bn + 4] = u1;
        }
        __syncthreads();
#pragma unroll
        for (int kk = 0; kk < 16; ++kk) {
            float4 a  = *(const float4*)&AT[kk][mg];
            float4 b0 = *(const float4*)&Bs[kk][jg];
            float4 b1 = *(const float4*)&Bs[kk][jg + 4];
            float av[4] = {a.x, a.y, a.z, a.w};
            float bv_[8] = {b0.x, b0.y, b0.z, b0.w, b1.x, b1.y, b1.z, b1.w};
#pragma unroll
            for (int i = 0; i < 4; ++i)
#pragma unroll
                for (int j = 0; j < 8; ++j) acc[i][j] += av[i] * bv_[j];
        }
    }
#pragma unroll
    for (int i = 0; i < 4; ++i) {
        int row = m0 + mg + i;
        if (row < NPOS) {
#pragma unroll
            for (int j = 0; j < 8; ++j) {
                int n = n0 + jg + j;
                dst[(size_t)row * OUTF + n] = acc[i][j] + bias[n];
            }
        }
    }
}

// ---------------------------------------------------------------------------
// split helpers (truncation split: x = hi(bf16) + lo(bf16), rel err ~2^-16)
// ---------------------------------------------------------------------------
__device__ __forceinline__ void split2(float x0, float x1,
                                       unsigned& hi, unsigned& lo)
{
    unsigned u0 = __float_as_uint(x0), u1 = __float_as_uint(x1);
    unsigned h0 = u0 & 0xFFFF0000u,   h1 = u1 & 0xFFFF0000u;
    float r0 = x0 - __uint_as_float(h0);
    float r1 = x1 - __uint_as_float(h1);
    hi = (h0 >> 16) | h1;
    lo = (__float_as_uint(r0) >> 16) | (__float_as_uint(r1) & 0xFFFF0000u);
}

__device__ __forceinline__ void split1(float x, unsigned short& hi, unsigned short& lo)
{
    unsigned u = __float_as_uint(x);
    unsigned h = u & 0xFFFF0000u;
    float r = x - __uint_as_float(h);
    hi = (unsigned short)(h >> 16);
    lo = (unsigned short)(__float_as_uint(r) >> 16);
}

__device__ __forceinline__ short8 ldfrag(const unsigned short* base, int row, int kuo)
{
    const unsigned long long* p =
        (const unsigned long long*)(base + row * LDS_KS + kuo);
    union { unsigned long long q[2]; short8 s; } u;
    u.q[0] = p[0];
    u.q[1] = p[1];
    return u.s;
}

__device__ __forceinline__ short8 g16(const unsigned short* p)
{
    union { uint4 q; short8 s; } u;
    u.q = *(const uint4*)p;
    return u.s;
}

__device__ __forceinline__ short8 lds16u(const unsigned short* p)
{
    union { unsigned long long q[2]; short8 s; } u;
    u.q[0] = ((const unsigned long long*)p)[0];
    u.q[1] = ((const unsigned long long*)p)[1];
    return u.s;
}

// ---------------------------------------------------------------------------
// K2 (MFMA split-bf16, K-SPLIT): fp32 partials of
//   Bc[part][(h*2+g)*64+dd][j] = sum_k hK~*adj
// chunk 0 -> part0 [0,708); chunks 1..2 -> part1 [0,KSPL),[KSPL,4192).
// KSPL is 32-aligned: the ks loop has no lower-bound mask within a step.
// ---------------------------------------------------------------------------
__global__ __launch_bounds__(256) void k2_mfma(
    const float* __restrict__ hK, const float* __restrict__ adj,
    const float* __restrict__ S,
    float* __restrict__ P0, float* __restrict__ P1)
{
    __shared__ unsigned short sAh[128 * LDS_KS];
    __shared__ unsigned short sAl[128 * LDS_KS];
    __shared__ unsigned short sBh[64 * LDS_KS];
    __shared__ unsigned short sBl[64 * LDS_KS];

    int t = threadIdx.x;
    int j0 = blockIdx.x * 64;
    int h  = blockIdx.y;
    int chunk = blockIdx.z;
    int part = (chunk == 0) ? 0 : 1;
    int kbeg = (chunk <= 1) ? 0 : KSPL;
    int kend = (chunk == 0) ? NG1 : ((chunk == 2) ? NG2 : KSPL);
    int L = part ? NG2 : NG1;
    const float* kflat = hK + (part ? (size_t)NG1 * OUTF : 0);
    int rowoff = part ? NG1 : 0;
    float* Pout = chunk ? (P1 + (size_t)(chunk - 1) * PCH) : P0;

    int dd = t & 63;
    int kg = t >> 6;
    int jcol = j0 + dd;

    float sc[2][4];
#pragma unroll
    for (int g = 0; g < 2; ++g)
#pragma unroll
        for (int c = 0; c < 4; ++c)
            sc[g][c] = 0.5f * S[(g + part) * 256 + c * 64 + dd];

    f32x16 acc0, acc1;
#pragma unroll
    for (int i = 0; i < 16; ++i) { acc0[i] = 0.f; acc1[i] = 0.f; }

    int lane = t & 63;
    int half = lane >> 5;
    int ml = lane & 31;
    int arow = kg * 32 + ml;

    unsigned* uAh = (unsigned*)sAh;
    unsigned* uAl = (unsigned*)sAl;
    unsigned* uBh = (unsigned*)sBh;
    unsigned* uBl = (unsigned*)sBl;

    int ks0 = kbeg >> 5;
    int ks1 = (kend + 31) >> 5;
    for (int ks = ks0; ks < ks1; ++ks) {
        int k0 = ks * 32;
        float xa[8], xb[8];
#pragma unroll
        for (int i = 0; i < 8; ++i) {
            int kv = k0 + kg * 8 + i;
            bool okk = (kv < kend);
            xa[i] = okk ? kflat[(size_t)(h * L + kv) * 64 + dd] : 0.f;
            xb[i] = (okk && jcol < NPOS)
                        ? adj[(size_t)(rowoff + kv) * NPOS + jcol] : 0.f;
        }
        unsigned hA0[4], lA0[4], hA1[4], lA1[4], hB[4], lB[4];
#pragma unroll
        for (int i = 0; i < 8; i += 2) {
            float a0 = xa[i] * sc[0][i & 3];
            float a1 = xa[i + 1] * sc[0][(i + 1) & 3];
            split2(a0, a1, hA0[i >> 1], lA0[i >> 1]);
            float c0 = xa[i] * sc[1][i & 3];
            float c1 = xa[i + 1] * sc[1][(i + 1) & 3];
            split2(c0, c1, hA1[i >> 1], lA1[i >> 1]);
            split2(xb[i], xb[i + 1], hB[i >> 1], lB[i >> 1]);
        }
        __syncthreads();
        {
            int b0 = dd * 18 + kg * 4;
            int b1 = (64 + dd) * 18 + kg * 4;
            *(uint2*)(uAh + b0)     = make_uint2(hA0[0], hA0[1]);
            *(uint2*)(uAh + b0 + 2) = make_uint2(hA0[2], hA0[3]);
            *(uint2*)(uAl + b0)     = make_uint2(lA0[0], lA0[1]);
            *(uint2*)(uAl + b0 + 2) = make_uint2(lA0[2], lA0[3]);
            *(uint2*)(uAh + b1)     = make_uint2(hA1[0], hA1[1]);
            *(uint2*)(uAh + b1 + 2) = make_uint2(hA1[2], hA1[3]);
            *(uint2*)(uAl + b1)     = make_uint2(lA1[0], lA1[1]);
            *(uint2*)(uAl + b1 + 2) = make_uint2(lA1[2], lA1[3]);
            *(uint2*)(uBh + b0)     = make_uint2(hB[0], hB[1]);
            *(uint2*)(uBh + b0 + 2) = make_uint2(hB[2], hB[3]);
            *(uint2*)(uBl + b0)     = make_uint2(lB[0], lB[1]);
            *(uint2*)(uBl + b0 + 2) = make_uint2(lB[2], lB[3]);
        }
        __syncthreads();
#pragma unroll
        for (int kq = 0; kq < 2; ++kq) {
            int kuo = kq * 16 + half * 8;
            short8 aH = ldfrag(sAh, arow, kuo);
            short8 aL = ldfrag(sAl, arow, kuo);
            short8 b0H = ldfrag(sBh, ml, kuo);
            short8 b0L = ldfrag(sBl, ml, kuo);
            short8 b1H = ldfrag(sBh, 32 + ml, kuo);
            short8 b1L = ldfrag(sBl, 32 + ml, kuo);
            acc0 = __builtin_amdgcn_mfma_f32_32x32x16_bf16(aH, b0H, acc0, 0, 0, 0);
            acc0 = __builtin_amdgcn_mfma_f32_32x32x16_bf16(aH, b0L, acc0, 0, 0, 0);
            acc0 = __builtin_amdgcn_mfma_f32_32x32x16_bf16(aL, b0H, acc0, 0, 0, 0);
            acc1 = __builtin_amdgcn_mfma_f32_32x32x16_bf16(aH, b1H, acc1, 0, 0, 0);
            acc1 = __builtin_amdgcn_mfma_f32_32x32x16_bf16(aH, b1L, acc1, 0, 0, 0);
            acc1 = __builtin_amdgcn_mfma_f32_32x32x16_bf16(aL, b1H, acc1, 0, 0, 0);
        }
    }

    int col0 = j0 + ml;
    int col1 = j0 + 32 + ml;
#pragma unroll
    for (int reg = 0; reg < 16; ++reg) {
        int m = kg * 32 + (reg & 3) + 8 * (reg >> 2) + 4 * half;
        int g = m >> 6, ddm = m & 63;
        size_t rb = (size_t)((h * 2 + g) * 64 + ddm) * NPOS;
        Pout[rb + col0] = acc0[reg];
        if (col1 < NPOS) Pout[rb + col1] = acc1[reg];
    }
}

// ---------------------------------------------------------------------------
// K2R: reduce part1 chunks + split-bf16 + transpose to B' planes
//   Bhi/Blo[(g*4+h)][j][k], k = part*64+dd.  Rows j in [4900,4928) zeroed.
// ---------------------------------------------------------------------------
__global__ __launch_bounds__(256) void k2_reduce(
    const float* __restrict__ P0, const float* __restrict__ P1,
    unsigned short* __restrict__ Bhi, unsigned short* __restrict__ Blo)
{
    int t = threadIdx.x;
    int j = blockIdx.x * 256 + t;
    if (j >= JBP) return;
    int p = blockIdx.y;               // plane = g*4+h
    int g = p >> 2, h = p & 3;
    int kg = blockIdx.z;              // 16 k-values each
    int k0 = kg * 16;
    int rowb = (h * 2 + g) * 64;

    unsigned short hi[16], lo[16];
    if (j < NPOS) {
        if (k0 < 64) {
#pragma unroll
            for (int i = 0; i < 16; ++i) {
                float v = P0[(size_t)(rowb + k0 + i) * NPOS + j];
                split1(v, hi[i], lo[i]);
            }
        } else {
#pragma unroll
            for (int i = 0; i < 16; ++i) {
                size_t off = (size_t)(rowb + (k0 - 64) + i) * NPOS + j;
                float v = P1[off] + P1[off + PCH];
                split1(v, hi[i], lo[i]);
            }
        }
    } else {
#pragma unroll
        for (int i = 0; i < 16; ++i) { hi[i] = 0; lo[i] = 0; }
    }
    size_t base = ((size_t)p * JBP + j) * 128 + k0;
    union { unsigned short us[16]; uint4 v[2]; } uh, ul;
#pragma unroll
    for (int i = 0; i < 16; ++i) { uh.us[i] = hi[i]; ul.us[i] = lo[i]; }
    *(uint4*)(Bhi + base)     = uh.v[0];
    *(uint4*)(Bhi + base + 8) = uh.v[1];
    *(uint4*)(Blo + base)     = ul.v[0];
    *(uint4*)(Blo + base + 8) = ul.v[1];
}

// ---------------------------------------------------------------------------
// QSPLIT: Q~ = hQ (head-reshaped) * S, split-bf16, k-contiguous rows.
// Row layout: g0: h*768 + ql (pad 768); g1: 3072 + h*4224 + ql (pad 4224).
// Pad rows (ql >= Lg) zeroed. 19968 rows x 128 k.
// ---------------------------------------------------------------------------
__global__ __launch_bounds__(256) void qsplit(
    const float* __restrict__ hQ, const float* __restrict__ S,
    unsigned short* __restrict__ Qh, unsigned short* __restrict__ Ql)
{
    int t = threadIdx.x;
    int row = blockIdx.x * 2 + (t >> 7);
    int k = t & 127;
    int g, h, ql, Lg, vbase;
    if (row < 3072) { g = 0; h = row / 768; ql = row - h * 768; Lg = NG1; vbase = 0; }
    else {
        int rr = row - 3072;
        g = 1; h = rr / 4224; ql = rr - h * 4224; Lg = NG2; vbase = NG1 * OUTF;
    }
    int d = k & 63, p = k >> 6;
    float v = 0.f;
    if (ql < Lg)
        v = hQ[vbase + (size_t)(h * Lg + ql) * 64 + d] *
            S[(g + p) * 256 + (ql & 3) * 64 + d];
    unsigned short hi, lo;
    split1(v, hi, lo);
    Qh[(size_t)row * 128 + k] = hi;
    Ql[(size_t)row * 128 + k] = lo;
}

// ---------------------------------------------------------------------------
// VTSPLIT: Vt[h][d][j] (hi/lo bf16, j-contiguous, j padded to JBP with zeros)
// from hV head-view hV[(h*4900 + j)*64 + d].
// ---------------------------------------------------------------------------
__global__ __launch_bounds__(256) void vtsplit(
    const float* __restrict__ hV,
    unsigned short* __restrict__ VtH, unsigned short* __restrict__ VtL)
{
    __shared__ float ls[128 * 65];
    int t = threadIdx.x;
    int j0 = blockIdx.x * 128;
    int h  = blockIdx.y;
#pragma unroll
    for (int i = 0; i < 32; ++i) {
        int idx = t + i * 256;
        int j = idx >> 6, d = idx & 63;
        float v = 0.f;
        int jg = j0 + j;
        if (jg < NPOS) v = hV[(size_t)(h * NPOS + jg) * 64 + d];
        ls[j * 65 + d] = v;
    }
    __syncthreads();
    int d = t >> 2, jseg = (t & 3) * 32;
#pragma unroll
    for (int i = 0; i < 32; ++i) {
        int j = jseg + i;
        int jg = j0 + j;
        if (jg < JBP) {
            unsigned short hi, lo;
            split1(ls[j * 65 + d], hi, lo);
            VtH[(size_t)(h * 64 + d) * JBP + jg] = hi;
            VtL[(size_t)(h * 64 + d) * JBP + jg] = lo;
        }
    }
}

// ---------------------------------------------------------------------------
// K3F v5: fused logits -> head-softmax -> PV, head-per-wave, 4 waves/block.
// v5 change vs v4: __launch_bounds__(256,2) raises the register ceiling so
// the 16 B' loads per jt are BATCHED (one exposed latency, not ~8):
//   - bb[8] array holds the 8 B'-hi frags; 16 aH MFMAs (qka/qkb dual acc);
//   - bb[] reloaded with B'-lo (loads pipeline under aH MFMAs); 8 aL MFMAs;
//   - Vt-hi frags prefetched at jt top (latency hidden under QK+softmax);
//     Vt-lo loaded at PV start (hidden under first PV MFMAs).
// Occupancy drops to 2 blocks/CU (8 waves) by design: latency count, not
// wave count, was the limiter (v4: VGPR=64 forced serial load-use).
// ---------------------------------------------------------------------------
__global__ __launch_bounds__(256, 2) void k3f_attn(
    const unsigned short* __restrict__ Qh, const unsigned short* __restrict__ Ql,
    const unsigned short* __restrict__ Bhi, const unsigned short* __restrict__ Blo,
    const unsigned short* __restrict__ VtH, const unsigned short* __restrict__ VtL,
    float* __restrict__ mpart)
{
    __shared__ __align__(16) char smem[35328];
    float* La = (float*)smem;                              // [4][32][33] f32
    unsigned short* Aa = (unsigned short*)(smem + 16896);  // [4][2][32][36] us

    int t = threadIdx.x;
    int w = t >> 6, lane = t & 63;
    int half = lane >> 5, ml = lane & 31;
    int h = w;

    int x = blockIdx.x;
    int c = blockIdx.y;
    int g = (x < 23) ? 0 : 1;
    int tile = g ? (x - 23) : x;
    int Lg = g ? NG2 : NG1;
    int posbase = g ? NG1 : 0;
    int qbase = g ? 3072 : 0;
    int hstr = g ? 4224 : 768;
    int q0 = tile * 32;

    // persistent Q fragments (hi+lo), loaded once
    const unsigned short* qrowH = Qh + (size_t)(qbase + h * hstr + q0 + ml) * 128 + half * 8;
    const unsigned short* qrowL = Ql + (size_t)(qbase + h * hstr + q0 + ml) * 128 + half * 8;
    short8 qfH[8], qfL[8];
#pragma unroll
    for (int kc = 0; kc < 8; ++kc) {
        qfH[kc] = g16(qrowH + kc * 16);
        qfL[kc] = g16(qrowL + kc * 16);
    }

    const unsigned short* bHb = Bhi + ((size_t)(g * 4 + h) * JBP + ml) * 128 + half * 8;
    const unsigned short* bLb = Blo + ((size_t)(g * 4 + h) * JBP + ml) * 128 + half * 8;
    size_t vro = (size_t)(h * 64 + ml) * JBP;
    const unsigned short* vH0 = VtH + vro;
    const unsigned short* vL0 = VtL + vro;
    const unsigned short* vH1 = VtH + vro + (size_t)32 * JBP;
    const unsigned short* vL1 = VtL + vro + (size_t)32 * JBP;

    f32x16 pv[2];
#pragma unroll
    for (int n = 0; n < 2; ++n)
#pragma unroll
        for (int r = 0; r < 16; ++r) pv[n][r] = 0.f;

    // softmax-phase thread mapping: 32 spos x 8 j-groups of 4
    int spos = t >> 3, sj4 = (t & 7) * 4;

    int jt0 = c * JTT, jt1 = jt0 + JTT;
    if (jt1 > NJT) jt1 = NJT;

    for (int jt = jt0; jt < jt1; ++jt) {
        int j0 = jt * 32;
        const unsigned short* bH = bHb + (size_t)j0 * 128;
        const unsigned short* bL = bLb + (size_t)j0 * 128;

        // ---- batched B'-hi loads + Vt-hi prefetch ----
        short8 bb[8];
#pragma unroll
        for (int kc = 0; kc < 8; ++kc) bb[kc] = g16(bH + kc * 16);
        int joA = j0 + half * 8;
        int joB = j0 + 16 + half * 8;
        short8 vh0a = g16(vH0 + joA);
        short8 vh1a = g16(vH1 + joA);
        short8 vh0b = g16(vH0 + joB);
        short8 vh1b = g16(vH1 + joB);

        // ---- QK^T: aH terms (dual accumulator) ----
        f32x16 qka, qkb;
#pragma unroll
        for (int r = 0; r < 16; ++r) { qka[r] = 0.f; qkb[r] = 0.f; }
#pragma unroll
        for (int kc = 0; kc < 8; kc += 2) {
            qka = __builtin_amdgcn_mfma_f32_32x32x16_bf16(bb[kc], qfH[kc], qka, 0, 0, 0);
            qka = __builtin_amdgcn_mfma_f32_32x32x16_bf16(bb[kc], qfL[kc], qka, 0, 0, 0);
            qkb = __builtin_amdgcn_mfma_f32_32x32x16_bf16(bb[kc + 1], qfH[kc + 1], qkb, 0, 0, 0);
            qkb = __builtin_amdgcn_mfma_f32_32x32x16_bf16(bb[kc + 1], qfL[kc + 1], qkb, 0, 0, 0);
        }
        // ---- reload bb with B'-lo (pipelines under aH MFMAs), aL terms ----
#pragma unroll
        for (int kc = 0; kc < 8; ++kc) bb[kc] = g16(bL + kc * 16);
#pragma unroll
        for (int kc = 0; kc < 8; kc += 2) {
            qka = __builtin_amdgcn_mfma_f32_32x32x16_bf16(bb[kc], qfH[kc], qka, 0, 0, 0);
            qkb = __builtin_amdgcn_mfma_f32_32x32x16_bf16(bb[kc + 1], qfH[kc + 1], qkb, 0, 0, 0);
        }

        // logits -> LDS (D: col=ml=pos, row=j)
#pragma unroll
        for (int r = 0; r < 16; ++r) {
            int jrow = (r & 3) + 8 * (r >> 2) + 4 * half;
            La[(w * 32 + jrow) * 33 + ml] = qka[r] + qkb[r];
        }
        __syncthreads();
        // ---- 4-head softmax + alpha split write ----
        {
            unsigned short hi_[4][4], lo_[4][4];   // [h][jj]
#pragma unroll
            for (int jj = 0; jj < 4; ++jj) {
                int j = sj4 + jj;
                float v0 = La[(0 * 32 + j) * 33 + spos];
                float v1 = La[(1 * 32 + j) * 33 + spos];
                float v2 = La[(2 * 32 + j) * 33 + spos];
                float v3 = La[(3 * 32 + j) * 33 + spos];
                float mx = fmaxf(fmaxf(v0, v1), fmaxf(v2, v3));
                float e0 = __expf(v0 - mx), e1 = __expf(v1 - mx);
                float e2 = __expf(v2 - mx), e3 = __expf(v3 - mx);
                float inv = 1.0f / (e0 + e1 + e2 + e3);
                split1(e0 * inv, hi_[0][jj], lo_[0][jj]);
                split1(e1 * inv, hi_[1][jj], lo_[1][jj]);
                split1(e2 * inv, hi_[2][jj], lo_[2][jj]);
                split1(e3 * inv, hi_[3][jj], lo_[3][jj]);
            }
#pragma unroll
            for (int hh = 0; hh < 4; ++hh) {
                unsigned long long Hw =
                    (unsigned long long)hi_[hh][0] |
                    ((unsigned long long)hi_[hh][1] << 16) |
                    ((unsigned long long)hi_[hh][2] << 32) |
                    ((unsigned long long)hi_[hh][3] << 48);
                unsigned long long Lw =
                    (unsigned long long)lo_[hh][0] |
                    ((unsigned long long)lo_[hh][1] << 16) |
                    ((unsigned long long)lo_[hh][2] << 32) |
                    ((unsigned long long)lo_[hh][3] << 48);
                *(unsigned long long*)&Aa[((hh * 2 + 0) * 32 + spos) * 36 + sj4] = Hw;
                *(unsigned long long*)&Aa[((hh * 2 + 1) * 32 + spos) * 36 + sj4] = Lw;
            }
        }
        __syncthreads();
        // ---- PV for own head (Vt-hi preloaded; Vt-lo loads hide under MFMAs) ----
        const unsigned short* aBH = Aa + (size_t)((w * 2 + 0) * 32 + ml) * 36 + half * 8;
        const unsigned short* aBL = Aa + (size_t)((w * 2 + 1) * 32 + ml) * 36 + half * 8;
        short8 w0La = g16(vL0 + joA);
        short8 w1La = g16(vL1 + joA);
        short8 w0Lb = g16(vL0 + joB);
        short8 w1Lb = g16(vL1 + joB);
#pragma unroll
        for (int ck = 0; ck < 2; ++ck) {
            short8 paH = lds16u(aBH + ck * 16);
            short8 paL = lds16u(aBL + ck * 16);
            short8 w0H = ck ? vh0b : vh0a;
            short8 w1H = ck ? vh1b : vh1a;
            short8 w0L = ck ? w0Lb : w0La;
            short8 w1L = ck ? w1Lb : w1La;
            pv[0] = __builtin_amdgcn_mfma_f32_32x32x16_bf16(w0H, paH, pv[0], 0, 0, 0);
            pv[0] = __builtin_amdgcn_mfma_f32_32x32x16_bf16(w0H, paL, pv[0], 0, 0, 0);
            pv[0] = __builtin_amdgcn_mfma_f32_32x32x16_bf16(w0L, paH, pv[0], 0, 0, 0);
            pv[1] = __builtin_amdgcn_mfma_f32_32x32x16_bf16(w1H, paH, pv[1], 0, 0, 0);
            pv[1] = __builtin_amdgcn_mfma_f32_32x32x16_bf16(w1H, paL, pv[1], 0, 0, 0);
            pv[1] = __builtin_amdgcn_mfma_f32_32x32x16_bf16(w1L, paH, pv[1], 0, 0, 0);
        }
    }

    // ---- epilogue: LDS transpose -> coalesced store to mpart chunk c ----
    __syncthreads();
    float* scr = (float*)smem + w * 2112;   // [32 pos][66]
#pragma unroll
    for (int nt = 0; nt < 2; ++nt)
#pragma unroll
        for (int r = 0; r < 16; ++r) {
            int drow = (r & 3) + 8 * (r >> 2) + 4 * half;
            scr[ml * 66 + nt * 32 + drow] = pv[nt][r];
        }
    float* mpc = mpart + (size_t)c * NPOS * OUTF;
#pragma unroll 4
    for (int i = 0; i < 32; ++i) {
        int pg = q0 + i;
        if (pg < Lg)
            mpc[(size_t)(posbase + pg) * OUTF + h * 64 + lane] = scr[i * 66 + lane];
    }
}

// ---------------------------------------------------------------------------
// E1: m = sum_c mpart[c]; relu; ln1; write concat buffer [H | ln1(relu(m))]
// ---------------------------------------------------------------------------
__global__ __launch_bounds__(256) void e1_relu_ln(
    const float* __restrict__ mpart, const float* __restrict__ Hb,
    const float* __restrict__ g1, const float* __restrict__ b1,
    float* __restrict__ cc)
{
    int w = threadIdx.x >> 6, lane = threadIdx.x & 63;
    int row = blockIdx.x * 4 + w;
    int c = lane * 4;
    const size_t CST = (size_t)NPOS * OUTF;
    float4 x0 = *(const float4*)(mpart + (size_t)row * OUTF + c);
#pragma unroll
    for (int k = 1; k < NC; ++k) {
        float4 a = *(const float4*)(mpart + k * CST + (size_t)row * OUTF + c);
        x0.x += a.x; x0.y += a.y; x0.z += a.z; x0.w += a.w;
    }
    float x[4] = { fmaxf(x0.x, 0.f), fmaxf(x0.y, 0.f),
                   fmaxf(x0.z, 0.f), fmaxf(x0.w, 0.f) };
    float s = x[0] + x[1] + x[2] + x[3];
#pragma unroll
    for (int m = 32; m > 0; m >>= 1) s += __shfl_xor(s, m, 64);
    float mu = s * (1.0f / 256.0f);
    float vs = 0.f;
#pragma unroll
    for (int i = 0; i < 4; ++i) { float d = x[i] - mu; vs += d * d; }
#pragma unroll
    for (int m = 32; m > 0; m >>= 1) vs += __shfl_xor(vs, m, 64);
    float rs = rsqrtf(vs * (1.0f / 256.0f) + 1e-5f);
    float4 y;
    y.x = (x[0] - mu) * rs * g1[c + 0] + b1[c + 0];
    y.y = (x[1] - mu) * rs * g1[c + 1] + b1[c + 1];
    y.z = (x[2] - mu) * rs * g1[c + 2] + b1[c + 2];
    y.w = (x[3] - mu) * rs * g1[c + 3] + b1[c + 3];
    *(float4*)(cc + (size_t)row * INF + OUTF + c) = y;
    float4 hh = *(const float4*)(Hb + (size_t)row * OUTF + c);
    *(float4*)(cc + (size_t)row * INF + c) = hh;
}

// ---------------------------------------------------------------------------
// E2: beta = sigmoid(cc @ Wbeta + bbeta); out = beta*m1 + (1-beta)*H
// ---------------------------------------------------------------------------
__global__ __launch_bounds__(256) void e2_beta(
    const float* __restrict__ cc, const float* __restrict__ Wb,
    const float* __restrict__ bb, float* __restrict__ outb)
{
    __shared__ float AT[16][68];
    __shared__ float Bs[16][132];
    int t = threadIdx.x;
    int n0 = blockIdx.x * 128;
    int m0 = blockIdx.y * 64;
    float acc[4][8];
#pragma unroll
    for (int i = 0; i < 4; ++i)
#pragma unroll
        for (int j = 0; j < 8; ++j) acc[i][j] = 0.f;
    int mg = (t >> 4) * 4, jg = (t & 15) * 8;
    int am = t & 63, ak = (t >> 6) * 4;
    int bkk = t >> 4, bn = (t & 15) * 8;
    for (int k0 = 0; k0 < INF; k0 += 16) {
        __syncthreads();
        {
            int row = m0 + am;
            float4 v = make_float4(0.f, 0.f, 0.f, 0.f);
            if (row < NPOS) v = *(const float4*)(cc + (size_t)row * INF + k0 + ak);
            AT[ak + 0][am] = v.x; AT[ak + 1][am] = v.y;
            AT[ak + 2][am] = v.z; AT[ak + 3][am] = v.w;
        }
        {
            const float* p = Wb + (size_t)(k0 + bkk) * OUTF + n0 + bn;
            float4 u0 = *(const float4*)p;
            float4 u1 = *(const float4*)(p + 4);
            *(float4*)&Bs[bkk][bn]     = u0;
            *(float4*)&Bs[bkk][bn + 4] = u1;
        }
        __syncthreads();
#pragma unroll
        for (int kk = 0; kk < 16; ++kk) {
            float4 a  = *(const float4*)&AT[kk][mg];
            float4 b0 = *(const float4*)&Bs[kk][jg];
            float4 b1 = *(const float4*)&Bs[kk][jg + 4];
            float av[4] = {a.x, a.y, a.z, a.w};
            float bv_[8] = {b0.x, b0.y, b0.z, b0.w, b1.x, b1.y, b1.z, b1.w};
#pragma unroll
            for (int i = 0; i < 4; ++i)
#pragma unroll
                for (int j = 0; j < 8; ++j) acc[i][j] += av[i] * bv_[j];
        }
    }
#pragma unroll
    for (int i = 0; i < 4; ++i) {
        int row = m0 + mg + i;
        if (row < NPOS) {
#pragma unroll
            for (int j = 0; j < 8; ++j) {
                int n = n0 + jg + j;
                float x = acc[i][j] + bb[n];
                float sg = 1.0f / (1.0f + __expf(-x));
                float m1v = cc[(size_t)row * INF + OUTF + n];
                float Hv  = cc[(size_t)row * INF + n];
                outb[(size_t)row * OUTF + n] = sg * m1v + (1.0f - sg) * Hv;
            }
        }
    }
}

// ---------------------------------------------------------------------------
// E3: t = out @ w1 + b1 ; ln2(eps=1e-6) ; tanh -> h2.
// ---------------------------------------------------------------------------
__global__ __launch_bounds__(256) void e3_w1_ln2(
    const float* __restrict__ outb, const float* __restrict__ w1,
    const float* __restrict__ b1v, const float* __restrict__ g2,
    const float* __restrict__ b2v, float* __restrict__ h2o)
{
    __shared__ float As[16][260];
    __shared__ float Bs[16][260];
    __shared__ float red[16][17];
    int t = threadIdx.x;
    int m0 = blockIdx.x * 16;
    {
        int rr = t >> 4, c4 = (t & 15) * 4;
        int row = m0 + rr;
#pragma unroll
        for (int i = 0; i < 4; ++i) {
            int c = c4 + i * 64;
            float4 x = make_float4(0.f, 0.f, 0.f, 0.f);
            if (row < NPOS) x = *(const float4*)(outb + (size_t)row * OUTF + c);
            *(float4*)&As[rr][c] = x;
        }
    }
    int q = t & 15, dg = (t >> 4) * 16;
    float acc[16];
#pragma unroll
    for (int i = 0; i < 16; ++i) acc[i] = 0.f;
    for (int k0 = 0; k0 < 256; k0 += 16) {
        __syncthreads();
        {
            int kk = t >> 4, n16 = (t & 15) * 16;
#pragma unroll
            for (int i = 0; i < 4; ++i) {
                float4 x = *(const float4*)(w1 + (size_t)(k0 + kk) * OUTF + n16 + i * 4);
                *(float4*)&Bs[kk][n16 + i * 4] = x;
            }
        }
        __syncthreads();
#pragma unroll
        for (int kk = 0; kk < 16; ++kk) {
            float a = As[q][k0 + kk];
#pragma unroll
            for (int i = 0; i < 16; i += 4) {
                float4 b = *(const float4*)&Bs[kk][dg + i];
                acc[i + 0] += a * b.x; acc[i + 1] += a * b.y;
                acc[i + 2] += a * b.z; acc[i + 3] += a * b.w;
            }
        }
    }
    float x[16];
#pragma unroll
    for (int i = 0; i < 16; ++i) x[i] = acc[i] + b1v[dg + i];
    float ps = 0.f;
#pragma unroll
    for (int i = 0; i < 16; ++i) ps += x[i];
    __syncthreads();
    red[t >> 4][q] = ps;
    __syncthreads();
    float s = 0.f;
#pragma unroll
    for (int i = 0; i < 16; ++i) s += red[i][q];
    float mu = s * (1.0f / 256.0f);
    float pvv = 0.f;
#pragma unroll
    for (int i = 0; i < 16; ++i) { float d = x[i] - mu; pvv += d * d; }
    __syncthreads();
    red[t >> 4][q] = pvv;
    __syncthreads();
    float v = 0.f;
#pragma unroll
    for (int i = 0; i < 16; ++i) v += red[i][q];
    float rs = rsqrtf(v * (1.0f / 256.0f) + 1e-6f);
    int row = m0 + q;
    if (row < NPOS) {
#pragma unroll
        for (int i = 0; i < 16; ++i) {
            int n = dg + i;
            h2o[(size_t)row * OUTF + n] = tanhf((x[i] - mu) * rs * g2[n] + b2v[n]);
        }
    }
}

// ---------------------------------------------------------------------------
// E4: final = h2 @ w2  (no bias) -> d_out
// ---------------------------------------------------------------------------
__global__ __launch_bounds__(256) void e4_final(
    const float* __restrict__ h2in, const float* __restrict__ w2,
    float* __restrict__ outp)
{
    __shared__ float AT[16][68];
    __shared__ float Bs[16][132];
    int t = threadIdx.x;
    int n0 = blockIdx.x * 128;
    int m0 = blockIdx.y * 64;
    float acc[4][8];
#pragma unroll
    for (int i = 0; i < 4; ++i)
#pragma unroll
        for (int j = 0; j < 8; ++j) acc[i][j] = 0.f;
    int mg = (t >> 4) * 4, jg = (t & 15) * 8;
    int am = t & 63, ak = (t >> 6) * 4;
    int bkk = t >> 4, bn = (t & 15) * 8;
    for (int k0 = 0; k0 < 256; k0 += 16) {
        __syncthreads();
        {
            int row = m0 + am;
            float4 v = make_float4(0.f, 0.f, 0.f, 0.f);
            if (row < NPOS) v = *(const float4*)(h2in + (size_t)row * OUTF + k0 + ak);
            AT[ak + 0][am] = v.x; AT[ak + 1][am] = v.y;
            AT[ak + 2][am] = v.z; AT[ak + 3][am] = v.w;
        }
        {
            const float* p = w2 + (size_t)(k0 + bkk) * OUTF + n0 + bn;
            float4 u0 = *(const float4*)p;
            float4 u1 = *(const float4*)(p + 4);
            *(float4*)&Bs[bkk][bn]     = u0;
            *(float4*)&Bs[bkk][bn + 4] = u1;
        }
        __syncthreads();
#pragma unroll
        for (int kk = 0; kk < 16; ++kk) {
            float4 a  = *(const float4*)&AT[kk][mg];
            float4 b0 = *(const float4*)&Bs[kk][jg];
            float4 b1 = *(const float4*)&Bs[kk][jg + 4];
            float av[4] = {a.x, a.y, a.z, a.w};
            float bv_[8] = {b0.x, b0.y, b0.z, b0.w, b1.x, b1.y, b1.z, b1.w};
#pragma unroll
            for (int i = 0; i < 4; ++i)
#pragma unroll
                for (int j = 0; j < 8; ++j) acc[i][j] += av[i] * bv_[j];
        }
    }
#pragma unroll
    for (int i = 0; i < 4; ++i) {
        int row = m0 + mg + i;
        if (row < NPOS) {
#pragma unroll
            for (int j = 0; j < 8; ++j) {
                outp[(size_t)row * OUTF + n0 + jg + j] = acc[i][j];
            }
        }
    }
}

// ---------------------------------------------------------------------------
extern "C" void kernel_launch(void* const* d_in, const int* in_sizes, int n_in,
                              void* d_out, int out_size, void* d_ws, size_t ws_size,
                              hipStream_t stream)
{
    const float* feature = (const float*)d_in[0];
    const float* adj   = (const float*)d_in[1];
    const float* r     = (const float*)d_in[2];
    const float* Wq    = (const float*)d_in[3];
    const float* bq    = (const float*)d_in[4];
    const float* Wk    = (const float*)d_in[5];
    const float* bk    = (const float*)d_in[6];
    const float* Wv    = (const float*)d_in[7];
    const float* bv    = (const float*)d_in[8];
    const float* Ww    = (const float*)d_in[9];
    const float* bw    = (const float*)d_in[10];
    const float* Wr    = (const float*)d_in[11];
    const float* br    = (const float*)d_in[12];
    const float* Wbeta = (const float*)d_in[13];
    const float* bbeta = (const float*)d_in[14];
    const float* ln1g  = (const float*)d_in[15];
    const float* ln1b  = (const float*)d_in[16];
    const float* w1    = (const float*)d_in[17];
    const float* b1    = (const float*)d_in[18];
    const float* ln2g  = (const float*)d_in[19];
    const float* ln2b  = (const float*)d_in[20];
    const float* w2    = (const float*)d_in[21];
    const int*   flag  = (const int*)d_in[22];
    float* out = (float*)d_out;

    // --- workspace layout (liveness-aliased, peak ~70.6 MB) ---
    // order: k0, k1, qsplit, vtsplit, k2_mfma, k2_reduce, k3f, e1..e4
    // [0,10.22M)      Qh,Ql          (qsplit->k3f);  cc after k3f
    // [10.22,15.27M)  VtH,VtL        (vtsplit->k3f); outb after k3f
    // [15.27,20.29M)  Hb             (k1->e1)
    // [20.29,50.39M)  P0+P1 (k2) == mpart[6] (k3f->e1) == hh2 (e3)
    // [50.39,60.49M)  Bhi (k2_reduce->k3f) == hK (k1->k2_mfma)
    // [60.49,70.58M)  Blo (k2_reduce->k3f) == hQ,hV (k1->q/vtsplit)
    // [70.58M]        S
    char* ws = (char*)d_ws;
    unsigned short* Qh    = (unsigned short*)(ws + 0);         // 5,111,808
    unsigned short* Qlo   = (unsigned short*)(ws + 5111808);   // 5,111,808
    unsigned short* VtH   = (unsigned short*)(ws + 10223616);  // 2,523,136
    unsigned short* VtL   = (unsigned short*)(ws + 12746752);  // 2,523,136
    float*          Hb    = (float*)(ws + 15269888);           // 5,017,600
    float*          P0    = (float*)(ws + 20287488);           // 10,035,200
    float*          P1    = (float*)(ws + 30322688);           // 2 x 10,035,200
    float*          mpart = (float*)(ws + 20287488);           // 6 x 5,017,600
    unsigned short* Bhi   = (unsigned short*)(ws + 50393088);  // 10,092,544
    unsigned short* Blo   = (unsigned short*)(ws + 60485632);  // 10,092,544
    float*          hK    = (float*)(ws + 50393088);           // alias Bhi
    float*          hQ    = (float*)(ws + 60485632);           // alias Blo lo
    float*          hV    = (float*)(ws + 65503232);           // alias Blo hi
    float*          cc    = (float*)(ws + 0);                  // 10,035,200
    float*          outb  = (float*)(ws + 10223616);           // 5,017,600
    float*          hh2   = (float*)(ws + 20287488);           // 5,017,600
    float*          S     = (float*)(ws + 70578176);           // 3,072

    k0_rp<<<1, 256, 0, stream>>>(r, Wr, br, flag, S);
    k1_proj<<<dim3(8, 77), 256, 0, stream>>>(feature, Wq, bq, Wk, bk, Wv, bv, Ww, bw,
                                             hQ, hK, hV, Hb);
    qsplit<<<9984, 256, 0, stream>>>(hQ, S, Qh, Qlo);
    vtsplit<<<dim3(39, 4), 256, 0, stream>>>(hV, VtH, VtL);
    k2_mfma<<<dim3(77, 4, 3), 256, 0, stream>>>(hK, adj, S, P0, P1);
    k2_reduce<<<dim3(20, 8, 8), 256, 0, stream>>>(P0, P1, Bhi, Blo);
    k3f_attn<<<dim3(154, NC), 256, 0, stream>>>(Qh, Qlo, Bhi, Blo, VtH, VtL, mpart);
    e1_relu_ln<<<1225, 256, 0, stream>>>(mpart, Hb, ln1g, ln1b, cc);
    e2_beta<<<dim3(2, 77), 256, 0, stream>>>(cc, Wbeta, bbeta, outb);
    e3_w1_ln2<<<307, 256, 0, stream>>>(outb, w1, b1, ln2g, ln2b, hh2);
    e4_final<<<dim3(2, 77), 256, 0, stream>>>(hh2, w2, out);
}

// Round 7
// 699.585 us; speedup vs baseline: 2.2583x; 1.2280x over previous
//
#include <hip/hip_runtime.h>
#include <hip/hip_bf16.h>
#include <math.h>

#define NPOS 4900
#define NG1  708
#define NG2  4192
#define INF  512
#define OUTF 256
#define JBP  4928       // B'/Vt padded j extent (rows >= 4900 zeroed)
#define NJT  154        // JBP/32 j-tiles
#define NC   6          // j-chunks (mpart copies)
#define JTT  26         // ceil(154/6)
#define LDS_KS 36       // k2: ushort k-stride (32 + 4 pad)
#define PCH   2508800   // k2 partial chunk stride in floats (512*4900)
#define KSPL 2112       // part1 K-split point -- MUST be multiple of 32

typedef __attribute__((ext_vector_type(8))) short short8;
typedef __attribute__((ext_vector_type(16))) float f32x16;

// ---------------------------------------------------------------------------
// K0: rp = r @ Wr + br  (4x256); store S[0]=rp[ridx], S[1]=rp[2], S[2]=rp[3]
// ---------------------------------------------------------------------------
__global__ __launch_bounds__(256) void k0_rp(
    const float* __restrict__ r, const float* __restrict__ Wr,
    const float* __restrict__ br, const int* __restrict__ flagp,
    float* __restrict__ S)
{
    __shared__ float rsh[1024];
    int t = threadIdx.x;
    for (int i = t; i < 1024; i += 256) rsh[i] = r[i];
    __syncthreads();
    float a0 = 0.f, a1 = 0.f, a2 = 0.f, a3 = 0.f;
    for (int c = 0; c < 256; ++c) {
        float w = Wr[c * 256 + t];
        a0 += rsh[c] * w;
        a1 += rsh[256 + c] * w;
        a2 += rsh[512 + c] * w;
        a3 += rsh[768 + c] * w;
    }
    float b = br[t];
    a0 += b; a1 += b; a2 += b; a3 += b;
    int ridx = (flagp[0] != 0) ? 1 : 0;
    S[t]         = ridx ? a1 : a0;
    S[256 + t]   = a2;
    S[512 + t]   = a3;
}

// ---------------------------------------------------------------------------
// K1: fused projections hQ/hK/hV/H = feature @ {Wq,Wk,Wv,Ww} + bias
// ---------------------------------------------------------------------------
__global__ __launch_bounds__(256) void k1_proj(
    const float* __restrict__ feat,
    const float* __restrict__ Wq, const float* __restrict__ bq,
    const float* __restrict__ Wk, const float* __restrict__ bk,
    const float* __restrict__ Wv, const float* __restrict__ bv,
    const float* __restrict__ Ww, const float* __restrict__ bw,
    float* __restrict__ hQ, float* __restrict__ hK,
    float* __restrict__ hV, float* __restrict__ Hb)
{
    __shared__ float AT[16][68];    // [k][m]
    __shared__ float Bs[16][132];   // [k][n]
    int t = threadIdx.x;
    int mat = blockIdx.x >> 1;
    int n0  = (blockIdx.x & 1) * 128;
    int m0  = blockIdx.y * 64;
    const float* W; const float* bias; float* dst;
    switch (mat) {
        case 0:  W = Wq; bias = bq; dst = hQ; break;
        case 1:  W = Wk; bias = bk; dst = hK; break;
        case 2:  W = Wv; bias = bv; dst = hV; break;
        default: W = Ww; bias = bw; dst = Hb; break;
    }
    float acc[4][8];
#pragma unroll
    for (int i = 0; i < 4; ++i)
#pragma unroll
        for (int j = 0; j < 8; ++j) acc[i][j] = 0.f;
    int mg = (t >> 4) * 4, jg = (t & 15) * 8;
    int am = t & 63, ak = (t >> 6) * 4;
    int bkk = t >> 4, bn = (t & 15) * 8;
    for (int k0 = 0; k0 < INF; k0 += 16) {
        __syncthreads();
        {
            int row = m0 + am;
            float4 v = make_float4(0.f, 0.f, 0.f, 0.f);
            if (row < NPOS) v = *(const float4*)(feat + (size_t)row * INF + k0 + ak);
            AT[ak + 0][am] = v.x; AT[ak + 1][am] = v.y;
            AT[ak + 2][am] = v.z; AT[ak + 3][am] = v.w;
        }
        {
            const float* p = W + (size_t)(k0 + bkk) * OUTF + n0 + bn;
            float4 u0 = *(const float4*)p;
            float4 u1 = *(const float4*)(p + 4);
            *(float4*)&Bs[bkk][bn]     = u0;
            *(float4*)&Bs[bkk][bn + 4] = u1;
        }
        __syncthreads();
#pragma unroll
        for (int kk = 0; kk < 16; ++kk) {
            float4 a  = *(const float4*)&AT[kk][mg];
            float4 b0 = *(const float4*)&Bs[kk][jg];
            float4 b1 = *(const float4*)&Bs[kk][jg + 4];
            float av[4] = {a.x, a.y, a.z, a.w};
            float bv_[8] = {b0.x, b0.y, b0.z, b0.w, b1.x, b1.y, b1.z, b1.w};
#pragma unroll
            for (int i = 0; i < 4; ++i)
#pragma unroll
                for (int j = 0; j < 8; ++j) acc[i][j] += av[i] * bv_[j];
        }
    }
#pragma unroll
    for (int i = 0; i < 4; ++i) {
        int row = m0 + mg + i;
        if (row < NPOS) {
#pragma unroll
            for (int j = 0; j < 8; ++j) {
                int n = n0 + jg + j;
                dst[(size_t)row * OUTF + n] = acc[i][j] + bias[n];
            }
        }
    }
}

// ---------------------------------------------------------------------------
// split helpers (truncation split: x = hi(bf16) + lo(bf16), rel err ~2^-16)
// ---------------------------------------------------------------------------
__device__ __forceinline__ void split2(float x0, float x1,
                                       unsigned& hi, unsigned& lo)
{
    unsigned u0 = __float_as_uint(x0), u1 = __float_as_uint(x1);
    unsigned h0 = u0 & 0xFFFF0000u,   h1 = u1 & 0xFFFF0000u;
    float r0 = x0 - __uint_as_float(h0);
    float r1 = x1 - __uint_as_float(h1);
    hi = (h0 >> 16) | h1;
    lo = (__float_as_uint(r0) >> 16) | (__float_as_uint(r1) & 0xFFFF0000u);
}

__device__ __forceinline__ void split1(float x, unsigned short& hi, unsigned short& lo)
{
    unsigned u = __float_as_uint(x);
    unsigned h = u & 0xFFFF0000u;
    float r = x - __uint_as_float(h);
    hi = (unsigned short)(h >> 16);
    lo = (unsigned short)(__float_as_uint(r) >> 16);
}

__device__ __forceinline__ short8 ldfrag(const unsigned short* base, int row, int kuo)
{
    const unsigned long long* p =
        (const unsigned long long*)(base + row * LDS_KS + kuo);
    union { unsigned long long q[2]; short8 s; } u;
    u.q[0] = p[0];
    u.q[1] = p[1];
    return u.s;
}

__device__ __forceinline__ short8 g16(const unsigned short* p)
{
    union { uint4 q; short8 s; } u;
    u.q = *(const uint4*)p;
    return u.s;
}

__device__ __forceinline__ short8 lds16u(const unsigned short* p)
{
    union { unsigned long long q[2]; short8 s; } u;
    u.q[0] = ((const unsigned long long*)p)[0];
    u.q[1] = ((const unsigned long long*)p)[1];
    return u.s;
}

// ---------------------------------------------------------------------------
// K2 (MFMA split-bf16, K-SPLIT): fp32 partials of
//   Bc[part][(h*2+g)*64+dd][j] = sum_k hK~*adj
// chunk 0 -> part0 [0,708); chunks 1..2 -> part1 [0,KSPL),[KSPL,4192).
// ---------------------------------------------------------------------------
__global__ __launch_bounds__(256) void k2_mfma(
    const float* __restrict__ hK, const float* __restrict__ adj,
    const float* __restrict__ S,
    float* __restrict__ P0, float* __restrict__ P1)
{
    __shared__ unsigned short sAh[128 * LDS_KS];
    __shared__ unsigned short sAl[128 * LDS_KS];
    __shared__ unsigned short sBh[64 * LDS_KS];
    __shared__ unsigned short sBl[64 * LDS_KS];

    int t = threadIdx.x;
    int j0 = blockIdx.x * 64;
    int h  = blockIdx.y;
    int chunk = blockIdx.z;
    int part = (chunk == 0) ? 0 : 1;
    int kbeg = (chunk <= 1) ? 0 : KSPL;
    int kend = (chunk == 0) ? NG1 : ((chunk == 2) ? NG2 : KSPL);
    int L = part ? NG2 : NG1;
    const float* kflat = hK + (part ? (size_t)NG1 * OUTF : 0);
    int rowoff = part ? NG1 : 0;
    float* Pout = chunk ? (P1 + (size_t)(chunk - 1) * PCH) : P0;

    int dd = t & 63;
    int kg = t >> 6;
    int jcol = j0 + dd;

    float sc[2][4];
#pragma unroll
    for (int g = 0; g < 2; ++g)
#pragma unroll
        for (int c = 0; c < 4; ++c)
            sc[g][c] = 0.5f * S[(g + part) * 256 + c * 64 + dd];

    f32x16 acc0, acc1;
#pragma unroll
    for (int i = 0; i < 16; ++i) { acc0[i] = 0.f; acc1[i] = 0.f; }

    int lane = t & 63;
    int half = lane >> 5;
    int ml = lane & 31;
    int arow = kg * 32 + ml;

    unsigned* uAh = (unsigned*)sAh;
    unsigned* uAl = (unsigned*)sAl;
    unsigned* uBh = (unsigned*)sBh;
    unsigned* uBl = (unsigned*)sBl;

    int ks0 = kbeg >> 5;
    int ks1 = (kend + 31) >> 5;
    for (int ks = ks0; ks < ks1; ++ks) {
        int k0 = ks * 32;
        float xa[8], xb[8];
#pragma unroll
        for (int i = 0; i < 8; ++i) {
            int kv = k0 + kg * 8 + i;
            bool okk = (kv < kend);
            xa[i] = okk ? kflat[(size_t)(h * L + kv) * 64 + dd] : 0.f;
            xb[i] = (okk && jcol < NPOS)
                        ? adj[(size_t)(rowoff + kv) * NPOS + jcol] : 0.f;
        }
        unsigned hA0[4], lA0[4], hA1[4], lA1[4], hB[4], lB[4];
#pragma unroll
        for (int i = 0; i < 8; i += 2) {
            float a0 = xa[i] * sc[0][i & 3];
            float a1 = xa[i + 1] * sc[0][(i + 1) & 3];
            split2(a0, a1, hA0[i >> 1], lA0[i >> 1]);
            float c0 = xa[i] * sc[1][i & 3];
            float c1 = xa[i + 1] * sc[1][(i + 1) & 3];
            split2(c0, c1, hA1[i >> 1], lA1[i >> 1]);
            split2(xb[i], xb[i + 1], hB[i >> 1], lB[i >> 1]);
        }
        __syncthreads();
        {
            int b0 = dd * 18 + kg * 4;
            int b1 = (64 + dd) * 18 + kg * 4;
            *(uint2*)(uAh + b0)     = make_uint2(hA0[0], hA0[1]);
            *(uint2*)(uAh + b0 + 2) = make_uint2(hA0[2], hA0[3]);
            *(uint2*)(uAl + b0)     = make_uint2(lA0[0], lA0[1]);
            *(uint2*)(uAl + b0 + 2) = make_uint2(lA0[2], lA0[3]);
            *(uint2*)(uAh + b1)     = make_uint2(hA1[0], hA1[1]);
            *(uint2*)(uAh + b1 + 2) = make_uint2(hA1[2], hA1[3]);
            *(uint2*)(uAl + b1)     = make_uint2(lA1[0], lA1[1]);
            *(uint2*)(uAl + b1 + 2) = make_uint2(lA1[2], lA1[3]);
            *(uint2*)(uBh + b0)     = make_uint2(hB[0], hB[1]);
            *(uint2*)(uBh + b0 + 2) = make_uint2(hB[2], hB[3]);
            *(uint2*)(uBl + b0)     = make_uint2(lB[0], lB[1]);
            *(uint2*)(uBl + b0 + 2) = make_uint2(lB[2], lB[3]);
        }
        __syncthreads();
#pragma unroll
        for (int kq = 0; kq < 2; ++kq) {
            int kuo = kq * 16 + half * 8;
            short8 aH = ldfrag(sAh, arow, kuo);
            short8 aL = ldfrag(sAl, arow, kuo);
            short8 b0H = ldfrag(sBh, ml, kuo);
            short8 b0L = ldfrag(sBl, ml, kuo);
            short8 b1H = ldfrag(sBh, 32 + ml, kuo);
            short8 b1L = ldfrag(sBl, 32 + ml, kuo);
            acc0 = __builtin_amdgcn_mfma_f32_32x32x16_bf16(aH, b0H, acc0, 0, 0, 0);
            acc0 = __builtin_amdgcn_mfma_f32_32x32x16_bf16(aH, b0L, acc0, 0, 0, 0);
            acc0 = __builtin_amdgcn_mfma_f32_32x32x16_bf16(aL, b0H, acc0, 0, 0, 0);
            acc1 = __builtin_amdgcn_mfma_f32_32x32x16_bf16(aH, b1H, acc1, 0, 0, 0);
            acc1 = __builtin_amdgcn_mfma_f32_32x32x16_bf16(aH, b1L, acc1, 0, 0, 0);
            acc1 = __builtin_amdgcn_mfma_f32_32x32x16_bf16(aL, b1H, acc1, 0, 0, 0);
        }
    }

    int col0 = j0 + ml;
    int col1 = j0 + 32 + ml;
#pragma unroll
    for (int reg = 0; reg < 16; ++reg) {
        int m = kg * 32 + (reg & 3) + 8 * (reg >> 2) + 4 * half;
        int g = m >> 6, ddm = m & 63;
        size_t rb = (size_t)((h * 2 + g) * 64 + ddm) * NPOS;
        Pout[rb + col0] = acc0[reg];
        if (col1 < NPOS) Pout[rb + col1] = acc1[reg];
    }
}

// ---------------------------------------------------------------------------
// K2R: reduce part1 chunks + split-bf16 + transpose to FRAGMENT-MAJOR B':
//   BF[plane][jt][kc][lane(=half*32+ml)][8 ushorts]
//   element: B'[plane][jt*32+ml][kc*16+half*8+i]  (k = part*64+dd)
// One k3f QK fragment load = contiguous 1KB (lane-coalesced).
// Rows j in [4900,4928) zeroed.
// ---------------------------------------------------------------------------
__global__ __launch_bounds__(256) void k2_reduce(
    const float* __restrict__ P0, const float* __restrict__ P1,
    unsigned short* __restrict__ Bhi, unsigned short* __restrict__ Blo)
{
    int t = threadIdx.x;
    int j = blockIdx.x * 256 + t;
    if (j >= JBP) return;
    int p = blockIdx.y;               // plane = g*4+h
    int g = p >> 2, h = p & 3;
    int kg = blockIdx.z;              // kc: 16 k-values each
    int k0 = kg * 16;
    int rowb = (h * 2 + g) * 64;

    unsigned short hi[16], lo[16];
    if (j < NPOS) {
        if (k0 < 64) {
#pragma unroll
            for (int i = 0; i < 16; ++i) {
                float v = P0[(size_t)(rowb + k0 + i) * NPOS + j];
                split1(v, hi[i], lo[i]);
            }
        } else {
#pragma unroll
            for (int i = 0; i < 16; ++i) {
                size_t off = (size_t)(rowb + (k0 - 64) + i) * NPOS + j;
                float v = P1[off] + P1[off + PCH];
                split1(v, hi[i], lo[i]);
            }
        }
    } else {
#pragma unroll
        for (int i = 0; i < 16; ++i) { hi[i] = 0; lo[i] = 0; }
    }
    int jt = j >> 5, mlr = j & 31;
    size_t fb = (((size_t)p * NJT + jt) * 8 + kg) * 512;
    union { unsigned short us[16]; uint4 v[2]; } uh, ul;
#pragma unroll
    for (int i = 0; i < 16; ++i) { uh.us[i] = hi[i]; ul.us[i] = lo[i]; }
    *(uint4*)(Bhi + fb + (size_t)mlr * 8)       = uh.v[0];   // half=0
    *(uint4*)(Bhi + fb + 256 + (size_t)mlr * 8) = uh.v[1];   // half=1
    *(uint4*)(Blo + fb + (size_t)mlr * 8)       = ul.v[0];
    *(uint4*)(Blo + fb + 256 + (size_t)mlr * 8) = ul.v[1];
}

// ---------------------------------------------------------------------------
// QSPLIT: Q~ = hQ (head-reshaped) * S, split-bf16, k-contiguous rows.
// Row layout: g0: h*768 + ql (pad 768); g1: 3072 + h*4224 + ql (pad 4224).
// Pad rows (ql >= Lg) zeroed. 19968 rows x 128 k.  (Loaded once per k3f
// block -- scattered access amortized; not relayouted.)
// ---------------------------------------------------------------------------
__global__ __launch_bounds__(256) void qsplit(
    const float* __restrict__ hQ, const float* __restrict__ S,
    unsigned short* __restrict__ Qh, unsigned short* __restrict__ Ql)
{
    int t = threadIdx.x;
    int row = blockIdx.x * 2 + (t >> 7);
    int k = t & 127;
    int g, h, ql, Lg, vbase;
    if (row < 3072) { g = 0; h = row / 768; ql = row - h * 768; Lg = NG1; vbase = 0; }
    else {
        int rr = row - 3072;
        g = 1; h = rr / 4224; ql = rr - h * 4224; Lg = NG2; vbase = NG1 * OUTF;
    }
    int d = k & 63, p = k >> 6;
    float v = 0.f;
    if (ql < Lg)
        v = hQ[vbase + (size_t)(h * Lg + ql) * 64 + d] *
            S[(g + p) * 256 + (ql & 3) * 64 + d];
    unsigned short hi, lo;
    split1(v, hi, lo);
    Qh[(size_t)row * 128 + k] = hi;
    Ql[(size_t)row * 128 + k] = lo;
}

// ---------------------------------------------------------------------------
// VTSPLIT: FRAGMENT-MAJOR Vt: VF[h][jt][ck][nt][lane][8 ushorts]
//   element: V[h][d = nt*32+(l&31)][j = jt*32+ck*16+(l>>5)*8+i]
// One k3f PV fragment load = contiguous 1KB (lane-coalesced).
// j padded to JBP with zeros.
// ---------------------------------------------------------------------------
__global__ __launch_bounds__(256) void vtsplit(
    const float* __restrict__ hV,
    unsigned short* __restrict__ VtH, unsigned short* __restrict__ VtL)
{
    __shared__ float ls[128 * 65];
    int t = threadIdx.x;
    int j0 = blockIdx.x * 128;
    int h  = blockIdx.y;
#pragma unroll
    for (int i = 0; i < 32; ++i) {
        int idx = t + i * 256;
        int j = idx >> 6, d = idx & 63;
        float v = 0.f;
        int jg = j0 + j;
        if (jg < NPOS) v = hV[(size_t)(h * NPOS + jg) * 64 + d];
        ls[j * 65 + d] = v;
    }
    __syncthreads();
    int jtbase = j0 >> 5;
#pragma unroll
    for (int it = 0; it < 4; ++it) {
        int chunk = t + it * 256;
        int jtl = chunk >> 8;
        int r = chunk & 255;
        int ck = r >> 7;
        int r2 = r & 127;
        int nt = r2 >> 6;
        int l = r2 & 63;
        int jt = jtbase + jtl;
        if (jt < NJT) {
            int d = nt * 32 + (l & 31);
            int jloc = jtl * 32 + ck * 16 + (l >> 5) * 8;
            union { unsigned short us[8]; uint4 v; } uh, ul;
#pragma unroll
            for (int i = 0; i < 8; ++i)
                split1(ls[(jloc + i) * 65 + d], uh.us[i], ul.us[i]);
            size_t fb = ((((size_t)h * NJT + jt) * 2 + ck) * 2 + nt) * 512 + (size_t)l * 8;
            *(uint4*)(VtH + fb) = uh.v;
            *(uint4*)(VtL + fb) = ul.v;
        }
    }
}

// ---------------------------------------------------------------------------
// K3F v6: fused logits -> head-softmax -> PV, head-per-wave, 4 waves/block.
// v6 vs v5: B'/Vt in FRAGMENT-MAJOR layout -- every global load is a
// lane-coalesced 1KB read (16 fully-used lines vs 32 half-used scattered
// lines).  Cross-jt schedule: B'lo issued before aH MFMAs; NEXT jt's B'hi
// prefetched right after aH (hides under softmax+PV); Vt issued before the
// softmax barrier (hides under softmax).
// ---------------------------------------------------------------------------
__global__ __launch_bounds__(256, 2) void k3f_attn(
    const unsigned short* __restrict__ Qh, const unsigned short* __restrict__ Ql,
    const unsigned short* __restrict__ Bhi, const unsigned short* __restrict__ Blo,
    const unsigned short* __restrict__ VtH, const unsigned short* __restrict__ VtL,
    float* __restrict__ mpart)
{
    __shared__ __align__(16) char smem[35328];
    float* La = (float*)smem;                              // [4][32][33] f32
    unsigned short* Aa = (unsigned short*)(smem + 16896);  // [4][2][32][36] us

    int t = threadIdx.x;
    int w = t >> 6, lane = t & 63;
    int half = lane >> 5, ml = lane & 31;
    int h = w;

    int x = blockIdx.x;
    int c = blockIdx.y;
    int g = (x < 23) ? 0 : 1;
    int tile = g ? (x - 23) : x;
    int Lg = g ? NG2 : NG1;
    int posbase = g ? NG1 : 0;
    int qbase = g ? 3072 : 0;
    int hstr = g ? 4224 : 768;
    int q0 = tile * 32;

    // persistent Q fragments (hi+lo), loaded once
    const unsigned short* qrowH = Qh + (size_t)(qbase + h * hstr + q0 + ml) * 128 + half * 8;
    const unsigned short* qrowL = Ql + (size_t)(qbase + h * hstr + q0 + ml) * 128 + half * 8;
    short8 qfH[8], qfL[8];
#pragma unroll
    for (int kc = 0; kc < 8; ++kc) {
        qfH[kc] = g16(qrowH + kc * 16);
        qfL[kc] = g16(qrowL + kc * 16);
    }

    // fragment-major bases (per-lane offset folded in)
    const unsigned short* bfH = Bhi + (size_t)(g * 4 + h) * NJT * 4096 + (size_t)lane * 8;
    const unsigned short* bfL = Blo + (size_t)(g * 4 + h) * NJT * 4096 + (size_t)lane * 8;
    const unsigned short* vfH = VtH + (size_t)h * NJT * 2048 + (size_t)lane * 8;
    const unsigned short* vfL = VtL + (size_t)h * NJT * 2048 + (size_t)lane * 8;

    f32x16 pv[2];
#pragma unroll
    for (int n = 0; n < 2; ++n)
#pragma unroll
        for (int r = 0; r < 16; ++r) pv[n][r] = 0.f;

    // softmax-phase thread mapping: 32 spos x 8 j-groups of 4
    int spos = t >> 3, sj4 = (t & 7) * 4;

    int jt0 = c * JTT, jt1 = jt0 + JTT;
    if (jt1 > NJT) jt1 = NJT;

    // prologue: B'hi for jt0
    short8 bbH[8];
#pragma unroll
    for (int kc = 0; kc < 8; ++kc)
        bbH[kc] = g16(bfH + (size_t)jt0 * 4096 + kc * 512);

    for (int jt = jt0; jt < jt1; ++jt) {
        size_t jo = (size_t)jt * 4096;
        int jn = (jt + 1 < jt1) ? jt + 1 : jt;
        size_t jno = (size_t)jn * 4096;

        // issue B'lo loads early (latency covered by aH MFMAs)
        short8 bbL[8];
#pragma unroll
        for (int kc = 0; kc < 8; ++kc) bbL[kc] = g16(bfL + jo + kc * 512);

        // ---- QK^T: aH terms (dual accumulator) ----
        f32x16 qka, qkb;
#pragma unroll
        for (int r = 0; r < 16; ++r) { qka[r] = 0.f; qkb[r] = 0.f; }
#pragma unroll
        for (int kc = 0; kc < 8; kc += 2) {
            qka = __builtin_amdgcn_mfma_f32_32x32x16_bf16(bbH[kc], qfH[kc], qka, 0, 0, 0);
            qka = __builtin_amdgcn_mfma_f32_32x32x16_bf16(bbH[kc], qfL[kc], qka, 0, 0, 0);
            qkb = __builtin_amdgcn_mfma_f32_32x32x16_bf16(bbH[kc + 1], qfH[kc + 1], qkb, 0, 0, 0);
            qkb = __builtin_amdgcn_mfma_f32_32x32x16_bf16(bbH[kc + 1], qfL[kc + 1], qkb, 0, 0, 0);
        }
        // prefetch NEXT jt's B'hi (bbH free after aH; hides under softmax+PV)
#pragma unroll
        for (int kc = 0; kc < 8; ++kc) bbH[kc] = g16(bfH + jno + kc * 512);

        // ---- aL terms ----
#pragma unroll
        for (int kc = 0; kc < 8; kc += 2) {
            qka = __builtin_amdgcn_mfma_f32_32x32x16_bf16(bbL[kc], qfH[kc], qka, 0, 0, 0);
            qkb = __builtin_amdgcn_mfma_f32_32x32x16_bf16(bbL[kc + 1], qfH[kc + 1], qkb, 0, 0, 0);
        }

        // issue Vt loads (latency covered by softmax phase)
        short8 vt[8];
        size_t vo = (size_t)jt * 2048;
#pragma unroll
        for (int q2 = 0; q2 < 4; ++q2) {
            vt[q2]     = g16(vfH + vo + q2 * 512);
            vt[4 + q2] = g16(vfL + vo + q2 * 512);
        }

        // logits -> LDS (D: col=ml=pos, row=j)
#pragma unroll
        for (int r = 0; r < 16; ++r) {
            int jrow = (r & 3) + 8 * (r >> 2) + 4 * half;
            La[(w * 32 + jrow) * 33 + ml] = qka[r] + qkb[r];
        }
        __syncthreads();
        // ---- 4-head softmax + alpha split write ----
        {
            unsigned short hi_[4][4], lo_[4][4];   // [h][jj]
#pragma unroll
            for (int jj = 0; jj < 4; ++jj) {
                int j = sj4 + jj;
                float v0 = La[(0 * 32 + j) * 33 + spos];
                float v1 = La[(1 * 32 + j) * 33 + spos];
                float v2 = La[(2 * 32 + j) * 33 + spos];
                float v3 = La[(3 * 32 + j) * 33 + spos];
                float mx = fmaxf(fmaxf(v0, v1), fmaxf(v2, v3));
                float e0 = __expf(v0 - mx), e1 = __expf(v1 - mx);
                float e2 = __expf(v2 - mx), e3 = __expf(v3 - mx);
                float inv = 1.0f / (e0 + e1 + e2 + e3);
                split1(e0 * inv, hi_[0][jj], lo_[0][jj]);
                split1(e1 * inv, hi_[1][jj], lo_[1][jj]);
                split1(e2 * inv, hi_[2][jj], lo_[2][jj]);
                split1(e3 * inv, hi_[3][jj], lo_[3][jj]);
            }
#pragma unroll
            for (int hh = 0; hh < 4; ++hh) {
                unsigned long long Hw =
                    (unsigned long long)hi_[hh][0] |
                    ((unsigned long long)hi_[hh][1] << 16) |
                    ((unsigned long long)hi_[hh][2] << 32) |
                    ((unsigned long long)hi_[hh][3] << 48);
                unsigned long long Lw =
                    (unsigned long long)lo_[hh][0] |
                    ((unsigned long long)lo_[hh][1] << 16) |
                    ((unsigned long long)lo_[hh][2] << 32) |
                    ((unsigned long long)lo_[hh][3] << 48);
                *(unsigned long long*)&Aa[((hh * 2 + 0) * 32 + spos) * 36 + sj4] = Hw;
                *(unsigned long long*)&Aa[((hh * 2 + 1) * 32 + spos) * 36 + sj4] = Lw;
            }
        }
        __syncthreads();
        // ---- PV for own head (vt preloaded) ----
        const unsigned short* aBH = Aa + (size_t)((w * 2 + 0) * 32 + ml) * 36 + half * 8;
        const unsigned short* aBL = Aa + (size_t)((w * 2 + 1) * 32 + ml) * 36 + half * 8;
#pragma unroll
        for (int ck = 0; ck < 2; ++ck) {
            short8 paH = lds16u(aBH + ck * 16);
            short8 paL = lds16u(aBL + ck * 16);
            short8 w0H = vt[ck * 2 + 0];
            short8 w1H = vt[ck * 2 + 1];
            short8 w0L = vt[4 + ck * 2 + 0];
            short8 w1L = vt[4 + ck * 2 + 1];
            pv[0] = __builtin_amdgcn_mfma_f32_32x32x16_bf16(w0H, paH, pv[0], 0, 0, 0);
            pv[0] = __builtin_amdgcn_mfma_f32_32x32x16_bf16(w0H, paL, pv[0], 0, 0, 0);
            pv[0] = __builtin_amdgcn_mfma_f32_32x32x16_bf16(w0L, paH, pv[0], 0, 0, 0);
            pv[1] = __builtin_amdgcn_mfma_f32_32x32x16_bf16(w1H, paH, pv[1], 0, 0, 0);
            pv[1] = __builtin_amdgcn_mfma_f32_32x32x16_bf16(w1H, paL, pv[1], 0, 0, 0);
            pv[1] = __builtin_amdgcn_mfma_f32_32x32x16_bf16(w1L, paH, pv[1], 0, 0, 0);
        }
    }

    // ---- epilogue: LDS transpose -> coalesced store to mpart chunk c ----
    __syncthreads();
    float* scr = (float*)smem + w * 2112;   // [32 pos][66]
#pragma unroll
    for (int nt = 0; nt < 2; ++nt)
#pragma unroll
        for (int r = 0; r < 16; ++r) {
            int drow = (r & 3) + 8 * (r >> 2) + 4 * half;
            scr[ml * 66 + nt * 32 + drow] = pv[nt][r];
        }
    float* mpc = mpart + (size_t)c * NPOS * OUTF;
#pragma unroll 4
    for (int i = 0; i < 32; ++i) {
        int pg = q0 + i;
        if (pg < Lg)
            mpc[(size_t)(posbase + pg) * OUTF + h * 64 + lane] = scr[i * 66 + lane];
    }
}

// ---------------------------------------------------------------------------
// E1: m = sum_c mpart[c]; relu; ln1; write concat buffer [H | ln1(relu(m))]
// ---------------------------------------------------------------------------
__global__ __launch_bounds__(256) void e1_relu_ln(
    const float* __restrict__ mpart, const float* __restrict__ Hb,
    const float* __restrict__ g1, const float* __restrict__ b1,
    float* __restrict__ cc)
{
    int w = threadIdx.x >> 6, lane = threadIdx.x & 63;
    int row = blockIdx.x * 4 + w;
    int c = lane * 4;
    const size_t CST = (size_t)NPOS * OUTF;
    float4 x0 = *(const float4*)(mpart + (size_t)row * OUTF + c);
#pragma unroll
    for (int k = 1; k < NC; ++k) {
        float4 a = *(const float4*)(mpart + k * CST + (size_t)row * OUTF + c);
        x0.x += a.x; x0.y += a.y; x0.z += a.z; x0.w += a.w;
    }
    float x[4] = { fmaxf(x0.x, 0.f), fmaxf(x0.y, 0.f),
                   fmaxf(x0.z, 0.f), fmaxf(x0.w, 0.f) };
    float s = x[0] + x[1] + x[2] + x[3];
#pragma unroll
    for (int m = 32; m > 0; m >>= 1) s += __shfl_xor(s, m, 64);
    float mu = s * (1.0f / 256.0f);
    float vs = 0.f;
#pragma unroll
    for (int i = 0; i < 4; ++i) { float d = x[i] - mu; vs += d * d; }
#pragma unroll
    for (int m = 32; m > 0; m >>= 1) vs += __shfl_xor(vs, m, 64);
    float rs = rsqrtf(vs * (1.0f / 256.0f) + 1e-5f);
    float4 y;
    y.x = (x[0] - mu) * rs * g1[c + 0] + b1[c + 0];
    y.y = (x[1] - mu) * rs * g1[c + 1] + b1[c + 1];
    y.z = (x[2] - mu) * rs * g1[c + 2] + b1[c + 2];
    y.w = (x[3] - mu) * rs * g1[c + 3] + b1[c + 3];
    *(float4*)(cc + (size_t)row * INF + OUTF + c) = y;
    float4 hh = *(const float4*)(Hb + (size_t)row * OUTF + c);
    *(float4*)(cc + (size_t)row * INF + c) = hh;
}

// ---------------------------------------------------------------------------
// E2: beta = sigmoid(cc @ Wbeta + bbeta); out = beta*m1 + (1-beta)*H
// ---------------------------------------------------------------------------
__global__ __launch_bounds__(256) void e2_beta(
    const float* __restrict__ cc, const float* __restrict__ Wb,
    const float* __restrict__ bb, float* __restrict__ outb)
{
    __shared__ float AT[16][68];
    __shared__ float Bs[16][132];
    int t = threadIdx.x;
    int n0 = blockIdx.x * 128;
    int m0 = blockIdx.y * 64;
    float acc[4][8];
#pragma unroll
    for (int i = 0; i < 4; ++i)
#pragma unroll
        for (int j = 0; j < 8; ++j) acc[i][j] = 0.f;
    int mg = (t >> 4) * 4, jg = (t & 15) * 8;
    int am = t & 63, ak = (t >> 6) * 4;
    int bkk = t >> 4, bn = (t & 15) * 8;
    for (int k0 = 0; k0 < INF; k0 += 16) {
        __syncthreads();
        {
            int row = m0 + am;
            float4 v = make_float4(0.f, 0.f, 0.f, 0.f);
            if (row < NPOS) v = *(const float4*)(cc + (size_t)row * INF + k0 + ak);
            AT[ak + 0][am] = v.x; AT[ak + 1][am] = v.y;
            AT[ak + 2][am] = v.z; AT[ak + 3][am] = v.w;
        }
        {
            const float* p = Wb + (size_t)(k0 + bkk) * OUTF + n0 + bn;
            float4 u0 = *(const float4*)p;
            float4 u1 = *(const float4*)(p + 4);
            *(float4*)&Bs[bkk][bn]     = u0;
            *(float4*)&Bs[bkk][bn + 4] = u1;
        }
        __syncthreads();
#pragma unroll
        for (int kk = 0; kk < 16; ++kk) {
            float4 a  = *(const float4*)&AT[kk][mg];
            float4 b0 = *(const float4*)&Bs[kk][jg];
            float4 b1 = *(const float4*)&Bs[kk][jg + 4];
            float av[4] = {a.x, a.y, a.z, a.w};
            float bv_[8] = {b0.x, b0.y, b0.z, b0.w, b1.x, b1.y, b1.z, b1.w};
#pragma unroll
            for (int i = 0; i < 4; ++i)
#pragma unroll
                for (int j = 0; j < 8; ++j) acc[i][j] += av[i] * bv_[j];
        }
    }
#pragma unroll
    for (int i = 0; i < 4; ++i) {
        int row = m0 + mg + i;
        if (row < NPOS) {
#pragma unroll
            for (int j = 0; j < 8; ++j) {
                int n = n0 + jg + j;
                float x = acc[i][j] + bb[n];
                float sg = 1.0f / (1.0f + __expf(-x));
                float m1v = cc[(size_t)row * INF + OUTF + n];
                float Hv  = cc[(size_t)row * INF + n];
                outb[(size_t)row * OUTF + n] = sg * m1v + (1.0f - sg) * Hv;
            }
        }
    }
}

// ---------------------------------------------------------------------------
// E3: t = out @ w1 + b1 ; ln2(eps=1e-6) ; tanh -> h2.
// ---------------------------------------------------------------------------
__global__ __launch_bounds__(256) void e3_w1_ln2(
    const float* __restrict__ outb, const float* __restrict__ w1,
    const float* __restrict__ b1v, const float* __restrict__ g2,
    const float* __restrict__ b2v, float* __restrict__ h2o)
{
    __shared__ float As[16][260];
    __shared__ float Bs[16][260];
    __shared__ float red[16][17];
    int t = threadIdx.x;
    int m0 = blockIdx.x * 16;
    {
        int rr = t >> 4, c4 = (t & 15) * 4;
        int row = m0 + rr;
#pragma unroll
        for (int i = 0; i < 4; ++i) {
            int c = c4 + i * 64;
            float4 x = make_float4(0.f, 0.f, 0.f, 0.f);
            if (row < NPOS) x = *(const float4*)(outb + (size_t)row * OUTF + c);
            *(float4*)&As[rr][c] = x;
        }
    }
    int q = t & 15, dg = (t >> 4) * 16;
    float acc[16];
#pragma unroll
    for (int i = 0; i < 16; ++i) acc[i] = 0.f;
    for (int k0 = 0; k0 < 256; k0 += 16) {
        __syncthreads();
        {
            int kk = t >> 4, n16 = (t & 15) * 16;
#pragma unroll
            for (int i = 0; i < 4; ++i) {
                float4 x = *(const float4*)(w1 + (size_t)(k0 + kk) * OUTF + n16 + i * 4);
                *(float4*)&Bs[kk][n16 + i * 4] = x;
            }
        }
        __syncthreads();
#pragma unroll
        for (int kk = 0; kk < 16; ++kk) {
            float a = As[q][k0 + kk];
#pragma unroll
            for (int i = 0; i < 16; i += 4) {
                float4 b = *(const float4*)&Bs[kk][dg + i];
                acc[i + 0] += a * b.x; acc[i + 1] += a * b.y;
                acc[i + 2] += a * b.z; acc[i + 3] += a * b.w;
            }
        }
    }
    float x[16];
#pragma unroll
    for (int i = 0; i < 16; ++i) x[i] = acc[i] + b1v[dg + i];
    float ps = 0.f;
#pragma unroll
    for (int i = 0; i < 16; ++i) ps += x[i];
    __syncthreads();
    red[t >> 4][q] = ps;
    __syncthreads();
    float s = 0.f;
#pragma unroll
    for (int i = 0; i < 16; ++i) s += red[i][q];
    float mu = s * (1.0f / 256.0f);
    float pvv = 0.f;
#pragma unroll
    for (int i = 0; i < 16; ++i) { float d = x[i] - mu; pvv += d * d; }
    __syncthreads();
    red[t >> 4][q] = pvv;
    __syncthreads();
    float v = 0.f;
#pragma unroll
    for (int i = 0; i < 16; ++i) v += red[i][q];
    float rs = rsqrtf(v * (1.0f / 256.0f) + 1e-6f);
    int row = m0 + q;
    if (row < NPOS) {
#pragma unroll
        for (int i = 0; i < 16; ++i) {
            int n = dg + i;
            h2o[(size_t)row * OUTF + n] = tanhf((x[i] - mu) * rs * g2[n] + b2v[n]);
        }
    }
}

// ---------------------------------------------------------------------------
// E4: final = h2 @ w2  (no bias) -> d_out
// ---------------------------------------------------------------------------
__global__ __launch_bounds__(256) void e4_final(
    const float* __restrict__ h2in, const float* __restrict__ w2,
    float* __restrict__ outp)
{
    __shared__ float AT[16][68];
    __shared__ float Bs[16][132];
    int t = threadIdx.x;
    int n0 = blockIdx.x * 128;
    int m0 = blockIdx.y * 64;
    float acc[4][8];
#pragma unroll
    for (int i = 0; i < 4; ++i)
#pragma unroll
        for (int j = 0; j < 8; ++j) acc[i][j] = 0.f;
    int mg = (t >> 4) * 4, jg = (t & 15) * 8;
    int am = t & 63, ak = (t >> 6) * 4;
    int bkk = t >> 4, bn = (t & 15) * 8;
    for (int k0 = 0; k0 < 256; k0 += 16) {
        __syncthreads();
        {
            int row = m0 + am;
            float4 v = make_float4(0.f, 0.f, 0.f, 0.f);
            if (row < NPOS) v = *(const float4*)(h2in + (size_t)row * OUTF + k0 + ak);
            AT[ak + 0][am] = v.x; AT[ak + 1][am] = v.y;
            AT[ak + 2][am] = v.z; AT[ak + 3][am] = v.w;
        }
        {
            const float* p = w2 + (size_t)(k0 + bkk) * OUTF + n0 + bn;
            float4 u0 = *(const float4*)p;
            float4 u1 = *(const float4*)(p + 4);
            *(float4*)&Bs[bkk][bn]     = u0;
            *(float4*)&Bs[bkk][bn + 4] = u1;
        }
        __syncthreads();
#pragma unroll
        for (int kk = 0; kk < 16; ++kk) {
            float4 a  = *(const float4*)&AT[kk][mg];
            float4 b0 = *(const float4*)&Bs[kk][jg];
            float4 b1 = *(const float4*)&Bs[kk][jg + 4];
            float av[4] = {a.x, a.y, a.z, a.w};
            float bv_[8] = {b0.x, b0.y, b0.z, b0.w, b1.x, b1.y, b1.z, b1.w};
#pragma unroll
            for (int i = 0; i < 4; ++i)
#pragma unroll
                for (int j = 0; j < 8; ++j) acc[i][j] += av[i] * bv_[j];
        }
    }
#pragma unroll
    for (int i = 0; i < 4; ++i) {
        int row = m0 + mg + i;
        if (row < NPOS) {
#pragma unroll
            for (int j = 0; j < 8; ++j) {
                outp[(size_t)row * OUTF + n0 + jg + j] = acc[i][j];
            }
        }
    }
}

// ---------------------------------------------------------------------------
extern "C" void kernel_launch(void* const* d_in, const int* in_sizes, int n_in,
                              void* d_out, int out_size, void* d_ws, size_t ws_size,
                              hipStream_t stream)
{
    const float* feature = (const float*)d_in[0];
    const float* adj   = (const float*)d_in[1];
    const float* r     = (const float*)d_in[2];
    const float* Wq    = (const float*)d_in[3];
    const float* bq    = (const float*)d_in[4];
    const float* Wk    = (const float*)d_in[5];
    const float* bk    = (const float*)d_in[6];
    const float* Wv    = (const float*)d_in[7];
    const float* bv    = (const float*)d_in[8];
    const float* Ww    = (const float*)d_in[9];
    const float* bw    = (const float*)d_in[10];
    const float* Wr    = (const float*)d_in[11];
    const float* br    = (const float*)d_in[12];
    const float* Wbeta = (const float*)d_in[13];
    const float* bbeta = (const float*)d_in[14];
    const float* ln1g  = (const float*)d_in[15];
    const float* ln1b  = (const float*)d_in[16];
    const float* w1    = (const float*)d_in[17];
    const float* b1    = (const float*)d_in[18];
    const float* ln2g  = (const float*)d_in[19];
    const float* ln2b  = (const float*)d_in[20];
    const float* w2    = (const float*)d_in[21];
    const int*   flag  = (const int*)d_in[22];
    float* out = (float*)d_out;

    // --- workspace layout (liveness-aliased, peak ~70.6 MB) ---
    // order: k0, k1, qsplit, vtsplit, k2_mfma, k2_reduce, k3f, e1..e4
    // [0,10.22M)      Qh,Ql          (qsplit->k3f);  cc after k3f
    // [10.22,15.27M)  VtH,VtL frag   (vtsplit->k3f); outb after k3f
    // [15.27,20.29M)  Hb             (k1->e1)
    // [20.29,50.39M)  P0+P1 (k2) == mpart[6] (k3f->e1) == hh2 (e3)
    // [50.39,60.49M)  Bhi frag (k2_reduce->k3f) == hK (k1->k2_mfma)
    // [60.49,70.58M)  Blo frag (k2_reduce->k3f) == hQ,hV (k1->q/vtsplit)
    // [70.58M]        S
    char* ws = (char*)d_ws;
    unsigned short* Qh    = (unsigned short*)(ws + 0);         // 5,111,808
    unsigned short* Qlo   = (unsigned short*)(ws + 5111808);   // 5,111,808
    unsigned short* VtH   = (unsigned short*)(ws + 10223616);  // 2,523,136
    unsigned short* VtL   = (unsigned short*)(ws + 12746752);  // 2,523,136
    float*          Hb    = (float*)(ws + 15269888);           // 5,017,600
    float*          P0    = (float*)(ws + 20287488);           // 10,035,200
    float*          P1    = (float*)(ws + 30322688);           // 2 x 10,035,200
    float*          mpart = (float*)(ws + 20287488);           // 6 x 5,017,600
    unsigned short* Bhi   = (unsigned short*)(ws + 50393088);  // 10,092,544
    unsigned short* Blo   = (unsigned short*)(ws + 60485632);  // 10,092,544
    float*          hK    = (float*)(ws + 50393088);           // alias Bhi
    float*          hQ    = (float*)(ws + 60485632);           // alias Blo lo
    float*          hV    = (float*)(ws + 65503232);           // alias Blo hi
    float*          cc    = (float*)(ws + 0);                  // 10,035,200
    float*          outb  = (float*)(ws + 10223616);           // 5,017,600
    float*          hh2   = (float*)(ws + 20287488);           // 5,017,600
    float*          S     = (float*)(ws + 70578176);           // 3,072

    k0_rp<<<1, 256, 0, stream>>>(r, Wr, br, flag, S);
    k1_proj<<<dim3(8, 77), 256, 0, stream>>>(feature, Wq, bq, Wk, bk, Wv, bv, Ww, bw,
                                             hQ, hK, hV, Hb);
    qsplit<<<9984, 256, 0, stream>>>(hQ, S, Qh, Qlo);
    vtsplit<<<dim3(39, 4), 256, 0, stream>>>(hV, VtH, VtL);
    k2_mfma<<<dim3(77, 4, 3), 256, 0, stream>>>(hK, adj, S, P0, P1);
    k2_reduce<<<dim3(20, 8, 8), 256, 0, stream>>>(P0, P1, Bhi, Blo);
    k3f_attn<<<dim3(154, NC), 256, 0, stream>>>(Qh, Qlo, Bhi, Blo, VtH, VtL, mpart);
    e1_relu_ln<<<1225, 256, 0, stream>>>(mpart, Hb, ln1g, ln1b, cc);
    e2_beta<<<dim3(2, 77), 256, 0, stream>>>(cc, Wbeta, bbeta, outb);
    e3_w1_ln2<<<307, 256, 0, stream>>>(outb, w1, b1, ln2g, ln2b, hh2);
    e4_final<<<dim3(2, 77), 256, 0, stream>>>(hh2, w2, out);
}